// Round 1
// baseline (2181.076 us; speedup 1.0000x reference)
//
#include <hip/hip_runtime.h>
#include <hip/hip_bf16.h>
#include <cstddef>
#include <cstdint>

typedef __hip_bfloat16 bf16;

#define NPT 4096   // points per cloud
#define BB  4      // batch
#define NBR 16     // neighbors (nsample)
#define WD  16     // weightnet output width
#define CDIM 64    // input feature channels
#define MIDD 128   // lin1/lin2 output channels

// ---------------------------------------------------------------------------
// Transpose [B][C][N] -> [B][N][C]
// ---------------------------------------------------------------------------
__global__ __launch_bounds__(256)
void transpose_kernel(const float* __restrict__ in, float* __restrict__ out, int C)
{
    __shared__ float t[32][33];
    const int b = blockIdx.z;
    const int n0 = blockIdx.x * 32, c0 = blockIdx.y * 32;
    const int tx = threadIdx.x, ty = threadIdx.y;
    #pragma unroll
    for (int r = ty; r < 32; r += 8)
        t[r][tx] = in[((size_t)b * C + c0 + r) * NPT + n0 + tx];
    __syncthreads();
    #pragma unroll
    for (int r = ty; r < 32; r += 8)
        out[((size_t)b * NPT + n0 + r) * C + c0 + tx] = t[tx][r];
}

// ---------------------------------------------------------------------------
// KNN: for each query point, 16 nearest neighbors in the other cloud.
// blockIdx.z == 0: queries pcA vs candidates pcB -> idxAB ; z==1: swapped.
// Distance formula mirrors the reference: |q|^2 + |p|^2 - 2 q.p
// Strict '<' insertion => stable tie-breaking like jax.lax.top_k.
// ---------------------------------------------------------------------------
__global__ __launch_bounds__(256)
void knn_kernel(const float* __restrict__ pcA, const float* __restrict__ pcB,
                int* __restrict__ idxAB, int* __restrict__ idxBA)
{
    const float *qxyz, *cxyz; int* idx_out;
    if (blockIdx.z == 0) { qxyz = pcA; cxyz = pcB; idx_out = idxAB; }
    else                 { qxyz = pcB; cxyz = pcA; idx_out = idxBA; }

    __shared__ float4 cf[NPT];   // x, y, z, |p|^2  (64 KB)
    const int b = blockIdx.y;
    const float* c = cxyz + (size_t)b * 3 * NPT;
    for (int j = threadIdx.x; j < NPT; j += 256) {
        const float x = c[j], y = c[NPT + j], z = c[2 * NPT + j];
        cf[j] = make_float4(x, y, z, fmaf(x, x, fmaf(y, y, z * z)));
    }
    __syncthreads();

    const int n = blockIdx.x * 256 + threadIdx.x;
    const float* q = qxyz + (size_t)b * 3 * NPT;
    const float qx = q[n], qy = q[NPT + n], qz = q[2 * NPT + n];
    const float q2 = fmaf(qx, qx, fmaf(qy, qy, qz * qz));

    float bd[NBR]; int bi[NBR];
    #pragma unroll
    for (int s = 0; s < NBR; ++s) { bd[s] = 3.4e38f; bi[s] = 0; }

    for (int j = 0; j < NPT; ++j) {
        const float4 pv = cf[j];
        const float dot = fmaf(qx, pv.x, fmaf(qy, pv.y, qz * pv.z));
        const float d = q2 + pv.w - 2.f * dot;
        if (d < bd[NBR - 1]) {
            bd[NBR - 1] = d; bi[NBR - 1] = j;
            #pragma unroll
            for (int s = NBR - 1; s > 0; --s) {
                if (bd[s] < bd[s - 1]) {
                    const float td = bd[s]; bd[s] = bd[s - 1]; bd[s - 1] = td;
                    const int   ti = bi[s]; bi[s] = bi[s - 1]; bi[s - 1] = ti;
                }
            }
        }
    }
    #pragma unroll
    for (int s = 0; s < NBR; ++s)
        idx_out[((size_t)b * NPT + n) * NBR + s] = bi[s];
}

// ---------------------------------------------------------------------------
// Per-point weightnet + aggregation. Produces agg rows [cm][2*D2*WD] in bf16.
//   agg[p][d][w] = sum_k pts[p][k][d] * wgt[p][k][w]
//   pts[., 0:D2]    = own point features (constant over k)
//   pts[., D2:2*D2] = gathered neighbor features
// ---------------------------------------------------------------------------
template<int D2, int PTS>
__global__ __launch_bounds__(256)
void agg_kernel(const float* __restrict__ qxyz, const float* __restrict__ cxyz,
                const float* __restrict__ own_pm, const float* __restrict__ nbr_pm,
                const int* __restrict__ idx,
                const float* __restrict__ w0, const float* __restrict__ b0,
                const float* __restrict__ w1, const float* __restrict__ b1,
                const float* __restrict__ w2, const float* __restrict__ b2,
                bf16* __restrict__ agg, int m0)
{
    constexpr int DT   = 2 * D2;
    constexpr int TPP  = 256 / PTS;         // threads per point (16 or 32)
    constexpr int WSTR = NBR * WD + 12;     // 268: p-stride chosen for bank spread
    constexpr int OSTR = D2 + 2;
    constexpr int FSTR = NBR * D2 + 2;

    __shared__ float wp[248];               // weightnet params
    __shared__ int   nb[PTS * NBR];
    __shared__ float wgt[PTS * WSTR];
    __shared__ float ownrow[PTS * OSTR];
    __shared__ bf16  feats[PTS * FSTR];

    const int tid = threadIdx.x;
    const int mbase = m0 + (int)blockIdx.x * PTS;     // global row (b*N + n)
    const int b = mbase >> 12;
    const int nbase = mbase & (NPT - 1);

    if (tid < 248) {
        float v;
        if      (tid <  24) v = w0[tid];
        else if (tid <  32) v = b0[tid - 24];
        else if (tid <  96) v = w1[tid - 32];
        else if (tid < 104) v = b1[tid - 96];
        else if (tid < 232) v = w2[tid - 104];
        else                v = b2[tid - 232];
        wp[tid] = v;
    }
    for (int e = tid; e < PTS * NBR; e += 256)
        nb[e] = idx[(size_t)mbase * NBR + e];
    __syncthreads();

    // ---- weightnet: one thread per (point, neighbor) ----
    if (tid < PTS * NBR) {
        const int p = tid / NBR, k = tid % NBR;
        const int n = nbase + p;
        const int j = nb[p * NBR + k];
        const float* q = qxyz + (size_t)b * 3 * NPT;
        const float* c = cxyz + (size_t)b * 3 * NPT;
        const float dx = c[j]           - q[n];
        const float dy = c[NPT + j]     - q[NPT + n];
        const float dz = c[2 * NPT + j] - q[2 * NPT + n];
        float h1[8], h2[8];
        #pragma unroll
        for (int o = 0; o < 8; ++o) {
            float v = wp[24 + o];
            v = fmaf(dx, wp[o], v);
            v = fmaf(dy, wp[8 + o], v);
            v = fmaf(dz, wp[16 + o], v);
            h1[o] = fmaxf(v, 0.f);
        }
        #pragma unroll
        for (int o = 0; o < 8; ++o) {
            float v = wp[96 + o];
            #pragma unroll
            for (int i = 0; i < 8; ++i) v = fmaf(h1[i], wp[32 + i * 8 + o], v);
            h2[o] = fmaxf(v, 0.f);
        }
        #pragma unroll
        for (int o = 0; o < WD; ++o) {
            float v = wp[232 + o];
            #pragma unroll
            for (int i = 0; i < 8; ++i) v = fmaf(h2[i], wp[104 + i * WD + o], v);
            wgt[p * WSTR + k * WD + o] = fmaxf(v, 0.f);
        }
    }

    // ---- own rows (fp32, constant over k) ----
    for (int e = tid; e < PTS * (D2 / 4); e += 256) {
        const int p = e / (D2 / 4), c4 = (e % (D2 / 4)) * 4;
        const float4 v = *(const float4*)(own_pm + ((size_t)mbase + p) * D2 + c4);
        float* dst = ownrow + p * OSTR + c4;
        dst[0] = v.x; dst[1] = v.y; dst[2] = v.z; dst[3] = v.w;
    }
    // ---- gathered neighbor rows (bf16) ----
    for (int e = tid; e < PTS * NBR * (D2 / 4); e += 256) {
        const int p  = e / (NBR * (D2 / 4));
        const int r  = e % (NBR * (D2 / 4));
        const int k  = r / (D2 / 4), c4 = (r % (D2 / 4)) * 4;
        const int j  = nb[p * NBR + k];
        const float4 v = *(const float4*)(nbr_pm + ((size_t)b * NPT + j) * D2 + c4);
        bf16* dst = feats + p * FSTR + k * D2 + c4;
        dst[0] = __float2bfloat16(v.x); dst[1] = __float2bfloat16(v.y);
        dst[2] = __float2bfloat16(v.z); dst[3] = __float2bfloat16(v.w);
    }
    __syncthreads();

    // ---- aggregation: thread -> (p = tid%PTS, dg = tid/PTS), 8 d-values each.
    // Wave-uniform split: low dg (own half, constant over k) vs high dg (gather).
    const int p  = tid % PTS;
    const int dg = tid / PTS;                 // 0..TPP-1
    const float* wg = wgt + p * WSTR;
    bf16* aout = agg + ((size_t)blockIdx.x * PTS + p) * (DT * WD) + (size_t)dg * 8 * WD;

    if (dg * 8 < D2) {
        float sw[WD];
        #pragma unroll
        for (int w = 0; w < WD; ++w) {
            float s = 0.f;
            #pragma unroll
            for (int k = 0; k < NBR; ++k) s += wg[k * WD + w];
            sw[w] = s;
        }
        #pragma unroll
        for (int di = 0; di < 8; ++di) {
            const float f = ownrow[p * OSTR + dg * 8 + di];
            union { bf16 h[16]; uint4 q[2]; } pk;
            #pragma unroll
            for (int w = 0; w < WD; ++w) pk.h[w] = __float2bfloat16(f * sw[w]);
            *(uint4*)(aout + di * WD)     = pk.q[0];
            *(uint4*)(aout + di * WD + 8) = pk.q[1];
        }
    } else {
        const bf16* fb = feats + p * FSTR + (dg * 8 - D2);
        #pragma unroll
        for (int di = 0; di < 8; ++di) {
            float F[NBR];
            #pragma unroll
            for (int k = 0; k < NBR; ++k) F[k] = __bfloat162float(fb[k * D2 + di]);
            union { bf16 h[16]; uint4 q[2]; } pk;
            #pragma unroll
            for (int w = 0; w < WD; ++w) {
                float s = 0.f;
                #pragma unroll
                for (int k = 0; k < NBR; ++k) s = fmaf(F[k], wg[k * WD + w], s);
                pk.h[w] = __float2bfloat16(s);
            }
            *(uint4*)(aout + di * WD)     = pk.q[0];
            *(uint4*)(aout + di * WD + 8) = pk.q[1];
        }
    }
}

// ---------------------------------------------------------------------------
// GEMM: out[m, o] = leaky( sum_K A[m,K]*Bw[K,o] + bias[o] ), A bf16, Bw fp32.
// 64x128 block tile, 256 threads, 4x8 per-thread tile, K-step 32.
// Epilogue stages the tile in LDS so both output layouts store coalesced:
//   out_t  : [B][128][N]  (d_out layout)
//   out_pm : [B*N][128]   (point-major, consumed by cross 3; may be null)
// ---------------------------------------------------------------------------
__global__ __launch_bounds__(256)
void gemm_kernel(const bf16* __restrict__ A, const float* __restrict__ Bw,
                 const float* __restrict__ bias,
                 float* __restrict__ out_t, float* __restrict__ out_pm,
                 int m0, int K)
{
    __shared__ __align__(16) char smem[64 * 133 * 4];
    bf16  (*AsT)[72]  = (bf16 (*)[72])smem;                  // [32][72] bf16 (A^T tile)
    float (*Bs)[132]  = (float (*)[132])(smem + 4608);       // [32][132]
    float (*tile)[133] = (float (*)[133])smem;               // reused in epilogue

    const int tid = threadIdx.x;
    const int ty = tid >> 4, tx = tid & 15;
    const int mb = (int)blockIdx.x * 64;

    float acc[4][8];
    #pragma unroll
    for (int i = 0; i < 4; ++i)
        #pragma unroll
        for (int j = 0; j < 8; ++j) acc[i][j] = 0.f;

    for (int k0 = 0; k0 < K; k0 += 32) {
        {   // A tile 64x32, stored transposed
            const int r = tid >> 2, ccol = (tid & 3) * 8;
            union { uint4 q; bf16 h[8]; } u;
            u.q = *(const uint4*)(A + (size_t)(mb + r) * K + k0 + ccol);
            #pragma unroll
            for (int jj = 0; jj < 8; ++jj) AsT[ccol + jj][r] = u.h[jj];
        }
        {   // B tile 32x128
            const int br = tid >> 5, bc = (tid & 31) * 4;
            #pragma unroll
            for (int rep = 0; rep < 4; ++rep) {
                const int r = br + rep * 8;
                *(float4*)&Bs[r][bc] = *(const float4*)(Bw + (size_t)(k0 + r) * MIDD + bc);
            }
        }
        __syncthreads();
        #pragma unroll
        for (int kk = 0; kk < 32; ++kk) {
            float a[4], bb[8];
            union { uint2 d; bf16 h[4]; } ua;
            ua.d = *(const uint2*)&AsT[kk][ty * 4];
            #pragma unroll
            for (int i = 0; i < 4; ++i) a[i] = __bfloat162float(ua.h[i]);
            const float4 bq0 = *(const float4*)&Bs[kk][tx * 8];
            const float4 bq1 = *(const float4*)&Bs[kk][tx * 8 + 4];
            bb[0] = bq0.x; bb[1] = bq0.y; bb[2] = bq0.z; bb[3] = bq0.w;
            bb[4] = bq1.x; bb[5] = bq1.y; bb[6] = bq1.z; bb[7] = bq1.w;
            #pragma unroll
            for (int i = 0; i < 4; ++i)
                #pragma unroll
                for (int j = 0; j < 8; ++j) acc[i][j] = fmaf(a[i], bb[j], acc[i][j]);
        }
        __syncthreads();
    }

    // epilogue: bias + leaky into LDS tile, then coalesced stores
    #pragma unroll
    for (int i = 0; i < 4; ++i)
        #pragma unroll
        for (int j = 0; j < 8; ++j) {
            const float v = acc[i][j] + bias[tx * 8 + j];
            tile[ty * 4 + i][tx * 8 + j] = v > 0.f ? v : 0.1f * v;
        }
    __syncthreads();

    const int mrow = m0 + mb;
    const int b = mrow >> 12, n0 = mrow & (NPT - 1);
    for (int e = tid; e < 64 * MIDD; e += 256) {
        const int o = e >> 6, i = e & 63;
        out_t[((size_t)b * MIDD + o) * NPT + n0 + i] = tile[i][o];
    }
    if (out_pm) {
        for (int e = tid; e < 64 * MIDD; e += 256) {
            const int i = e >> 7, o = e & 127;
            out_pm[((size_t)(mrow + i)) * MIDD + o] = tile[i][o];
        }
    }
}

// ---------------------------------------------------------------------------
extern "C" void kernel_launch(void* const* d_in, const int* in_sizes, int n_in,
                              void* d_out, int out_size, void* d_ws, size_t ws_size,
                              hipStream_t stream)
{
    (void)in_sizes; (void)n_in; (void)out_size;
    const float* pc1    = (const float*)d_in[0];
    const float* pc2    = (const float*)d_in[1];
    const float* feat1  = (const float*)d_in[2];
    const float* feat2  = (const float*)d_in[3];
    const float* wn1_w0 = (const float*)d_in[4];
    const float* wn1_b0 = (const float*)d_in[5];
    const float* wn1_w1 = (const float*)d_in[6];
    const float* wn1_b1 = (const float*)d_in[7];
    const float* wn1_w2 = (const float*)d_in[8];
    const float* wn1_b2 = (const float*)d_in[9];
    const float* lin1_w = (const float*)d_in[10];
    const float* lin1_b = (const float*)d_in[11];
    const float* wn2_w0 = (const float*)d_in[12];
    const float* wn2_b0 = (const float*)d_in[13];
    const float* wn2_w1 = (const float*)d_in[14];
    const float* wn2_b1 = (const float*)d_in[15];
    const float* wn2_w2 = (const float*)d_in[16];
    const float* wn2_b2 = (const float*)d_in[17];
    const float* lin2_w = (const float*)d_in[18];
    const float* lin2_b = (const float*)d_in[19];
    float* out = (float*)d_out;

    const int M = BB * NPT;                       // 16384 rows per cross
    char* ws = (char*)d_ws;
    float* p1pm = (float*)ws;                     // [M][64]
    float* p2pm = p1pm + (size_t)M * CDIM;        // [M][64]
    float* f1pm = p2pm + (size_t)M * CDIM;        // [M][128]
    float* f2pm = f1pm + (size_t)M * MIDD;        // [M][128]
    int* idx12  = (int*)(f2pm + (size_t)M * MIDD);
    int* idx21  = idx12 + (size_t)M * NBR;
    bf16* aggbuf = (bf16*)(idx21 + (size_t)M * NBR);
    const size_t used = (size_t)((char*)aggbuf - ws);
    const size_t avail = ws_size > used ? ws_size - used : 0;

    float* f1t = out;
    float* f2t = out + (size_t)BB * MIDD * NPT;
    float* fft = out + 2 * (size_t)BB * MIDD * NPT;

    transpose_kernel<<<dim3(NPT / 32, CDIM / 32, BB), dim3(32, 8), 0, stream>>>(feat1, p1pm, CDIM);
    transpose_kernel<<<dim3(NPT / 32, CDIM / 32, BB), dim3(32, 8), 0, stream>>>(feat2, p2pm, CDIM);
    knn_kernel<<<dim3(NPT / 256, BB, 2), 256, 0, stream>>>(pc1, pc2, idx12, idx21);

    // chunk rows so the agg scratch fits in whatever ws remains
    auto chunk_rows = [&](int K) -> int {
        long rows = (long)(avail / ((size_t)K * sizeof(bf16)));
        if (rows > M) rows = M;
        int cm = (int)rows & ~63;
        if (cm < 64) cm = 64;   // requires ws >= ~27 MB; standard harness scratch is larger
        return cm;
    };

    {   // cross 1 and cross 2 (K = 2048)
        const int K = 2 * CDIM * WD;
        const int CMr = chunk_rows(K);
        for (int m0 = 0; m0 < M; m0 += CMr) {
            const int cm = (M - m0 < CMr) ? (M - m0) : CMr;
            agg_kernel<CDIM, 16><<<cm / 16, 256, 0, stream>>>(
                pc1, pc2, p1pm, p2pm, idx12,
                wn1_w0, wn1_b0, wn1_w1, wn1_b1, wn1_w2, wn1_b2, aggbuf, m0);
            gemm_kernel<<<cm / 64, 256, 0, stream>>>(aggbuf, lin1_w, lin1_b, f1t, f1pm, m0, K);
        }
        for (int m0 = 0; m0 < M; m0 += CMr) {
            const int cm = (M - m0 < CMr) ? (M - m0) : CMr;
            agg_kernel<CDIM, 16><<<cm / 16, 256, 0, stream>>>(
                pc2, pc1, p2pm, p1pm, idx21,
                wn1_w0, wn1_b0, wn1_w1, wn1_b1, wn1_w2, wn1_b2, aggbuf, m0);
            gemm_kernel<<<cm / 64, 256, 0, stream>>>(aggbuf, lin1_w, lin1_b, f2t, f2pm, m0, K);
        }
    }
    {   // cross 3 (K = 4096) — reuses idx12; features are f1n/f2n point-major
        const int K = 2 * MIDD * WD;
        const int CMr = chunk_rows(K);
        for (int m0 = 0; m0 < M; m0 += CMr) {
            const int cm = (M - m0 < CMr) ? (M - m0) : CMr;
            agg_kernel<MIDD, 8><<<cm / 8, 256, 0, stream>>>(
                pc1, pc2, f1pm, f2pm, idx12,
                wn2_w0, wn2_b0, wn2_w1, wn2_b1, wn2_w2, wn2_b2, aggbuf, m0);
            gemm_kernel<<<cm / 64, 256, 0, stream>>>(aggbuf, lin2_w, lin2_b, fft, nullptr, m0, K);
        }
    }
}

// Round 2
// 1249.437 us; speedup vs baseline: 1.7456x; 1.7456x over previous
//
#include <hip/hip_runtime.h>
#include <hip/hip_bf16.h>
#include <cstddef>
#include <cstdint>

typedef __hip_bfloat16 bf16;

#define NPT 4096   // points per cloud
#define BB  4      // batch
#define NBR 16     // neighbors (nsample)
#define WD  16     // weightnet output width
#define CDIM 64    // input feature channels
#define MIDD 128   // lin1/lin2 output channels

// ---------------------------------------------------------------------------
// Transpose [B][C][N] -> [B][N][C]
// ---------------------------------------------------------------------------
__global__ __launch_bounds__(256)
void transpose_kernel(const float* __restrict__ in, float* __restrict__ out, int C)
{
    __shared__ float t[32][33];
    const int b = blockIdx.z;
    const int n0 = blockIdx.x * 32, c0 = blockIdx.y * 32;
    const int tx = threadIdx.x, ty = threadIdx.y;
    #pragma unroll
    for (int r = ty; r < 32; r += 8)
        t[r][tx] = in[((size_t)b * C + c0 + r) * NPT + n0 + tx];
    __syncthreads();
    #pragma unroll
    for (int r = ty; r < 32; r += 8)
        out[((size_t)b * NPT + n0 + r) * C + c0 + tx] = t[tx][r];
}

// ---------------------------------------------------------------------------
// KNN v2: segment-parallel top-16 + in-block merge.
// Block = 256 threads = 32 queries x 8 segments. Each thread scans 512
// candidates (its segment, staged through LDS in 1024-candidate chunks),
// keeping a sorted top-16 in registers (strict '<' insertion => within a
// thread, ties keep the earlier/lower index, list is (d asc, idx asc)).
// Merge: per query, 8 sorted lists merged with (d, idx) lexicographic
// compare => exact jax.lax.top_k tie semantics. Distance arithmetic is
// bit-identical to the round-1 kernel, so neighbor sets are unchanged.
// ---------------------------------------------------------------------------
#define KNN_QB    32    // queries per block
#define KNN_SEG   8     // segments (threads) per query
#define KNN_STAGE 1024  // candidates staged per chunk
#define KNN_SPAN  (KNN_STAGE / KNN_SEG)   // 128 candidates per thread per chunk

__global__ __launch_bounds__(256)
void knn_kernel(const float* __restrict__ pcA, const float* __restrict__ pcB,
                int* __restrict__ idxAB, int* __restrict__ idxBA)
{
    const float *qxyz, *cxyz; int* idx_out;
    if (blockIdx.z == 0) { qxyz = pcA; cxyz = pcB; idx_out = idxAB; }
    else                 { qxyz = pcB; cxyz = pcA; idx_out = idxBA; }

    __shared__ float4 cf[KNN_STAGE];        // 16 KB: x,y,z,|p|^2
    __shared__ float  ld[KNN_QB][129];      // merge lists, padded (stride 129)
    __shared__ int    li[KNN_QB][129];

    const int tid = threadIdx.x;
    const int q   = tid & (KNN_QB - 1);
    const int s   = tid >> 5;               // segment 0..7
    const int b   = blockIdx.y;
    const int n   = blockIdx.x * KNN_QB + q;

    const float* qp = qxyz + (size_t)b * 3 * NPT;
    const float qx = qp[n], qy = qp[NPT + n], qz = qp[2 * NPT + n];
    const float q2 = fmaf(qx, qx, fmaf(qy, qy, qz * qz));

    float bd[NBR]; int bi[NBR];
    #pragma unroll
    for (int t = 0; t < NBR; ++t) { bd[t] = 3.4e38f; bi[t] = 0; }

    const float* c = cxyz + (size_t)b * 3 * NPT;
    for (int st = 0; st < NPT; st += KNN_STAGE) {
        __syncthreads();
        for (int j = tid; j < KNN_STAGE; j += 256) {
            const int g = st + j;
            const float x = c[g], y = c[NPT + g], z = c[2 * NPT + g];
            cf[j] = make_float4(x, y, z, fmaf(x, x, fmaf(y, y, z * z)));
        }
        __syncthreads();

        const int base = s * KNN_SPAN;
        #pragma unroll 4
        for (int j = 0; j < KNN_SPAN; ++j) {
            const float4 pv = cf[base + j];
            const float dot = fmaf(qx, pv.x, fmaf(qy, pv.y, qz * pv.z));
            const float d = q2 + pv.w - 2.f * dot;
            if (d < bd[NBR - 1]) {
                bd[NBR - 1] = d; bi[NBR - 1] = st + base + j;
                #pragma unroll
                for (int t = NBR - 1; t > 0; --t) {
                    if (bd[t] < bd[t - 1]) {
                        const float td = bd[t]; bd[t] = bd[t - 1]; bd[t - 1] = td;
                        const int   ti = bi[t]; bi[t] = bi[t - 1]; bi[t - 1] = ti;
                    }
                }
            }
        }
    }

    // publish per-segment lists
    __syncthreads();
    #pragma unroll
    for (int t = 0; t < NBR; ++t) {
        ld[q][s * NBR + t] = bd[t];
        li[q][s * NBR + t] = bi[t];
    }
    __syncthreads();

    // per-query 8-way merge of sorted lists (thread tid < 32 handles query tid)
    if (tid < KNN_QB) {
        int h0 = 0, h1 = 0, h2 = 0, h3 = 0, h4 = 0, h5 = 0, h6 = 0, h7 = 0;
        int* op = idx_out + ((size_t)b * NPT + blockIdx.x * KNN_QB + tid) * NBR;
        #pragma unroll 1
        for (int pick = 0; pick < NBR; ++pick) {
            float best = 3.5e38f; int bidx = 0x7fffffff;
            #define KNN_PROP(hh, ss)                                              \
                if (hh < NBR) {                                                   \
                    const float d = ld[tid][(ss) * NBR + hh];                     \
                    const int   i = li[tid][(ss) * NBR + hh];                     \
                    if (d < best || (d == best && i < bidx)) { best = d; bidx = i; } \
                }
            KNN_PROP(h0, 0) KNN_PROP(h1, 1) KNN_PROP(h2, 2) KNN_PROP(h3, 3)
            KNN_PROP(h4, 4) KNN_PROP(h5, 5) KNN_PROP(h6, 6) KNN_PROP(h7, 7)
            #undef KNN_PROP
            // advance the (unique) list whose head was picked: candidate
            // indices are disjoint across segments, so match on index.
            #define KNN_ADV(hh, ss)                                               \
                if (hh < NBR && li[tid][(ss) * NBR + hh] == bidx) hh++;
            KNN_ADV(h0, 0) KNN_ADV(h1, 1) KNN_ADV(h2, 2) KNN_ADV(h3, 3)
            KNN_ADV(h4, 4) KNN_ADV(h5, 5) KNN_ADV(h6, 6) KNN_ADV(h7, 7)
            #undef KNN_ADV
            op[pick] = bidx;
        }
    }
}

// ---------------------------------------------------------------------------
// Per-point weightnet + aggregation. Produces agg rows [cm][2*D2*WD] in bf16.
//   agg[p][d][w] = sum_k pts[p][k][d] * wgt[p][k][w]
//   pts[., 0:D2]    = own point features (constant over k)
//   pts[., D2:2*D2] = gathered neighbor features
// ---------------------------------------------------------------------------
template<int D2, int PTS>
__global__ __launch_bounds__(256)
void agg_kernel(const float* __restrict__ qxyz, const float* __restrict__ cxyz,
                const float* __restrict__ own_pm, const float* __restrict__ nbr_pm,
                const int* __restrict__ idx,
                const float* __restrict__ w0, const float* __restrict__ b0,
                const float* __restrict__ w1, const float* __restrict__ b1,
                const float* __restrict__ w2, const float* __restrict__ b2,
                bf16* __restrict__ agg, int m0)
{
    constexpr int DT   = 2 * D2;
    constexpr int TPP  = 256 / PTS;         // threads per point (16 or 32)
    constexpr int WSTR = NBR * WD + 12;     // 268: p-stride chosen for bank spread
    constexpr int OSTR = D2 + 2;
    constexpr int FSTR = NBR * D2 + 2;

    __shared__ float wp[248];               // weightnet params
    __shared__ int   nb[PTS * NBR];
    __shared__ float wgt[PTS * WSTR];
    __shared__ float ownrow[PTS * OSTR];
    __shared__ bf16  feats[PTS * FSTR];

    const int tid = threadIdx.x;
    const int mbase = m0 + (int)blockIdx.x * PTS;     // global row (b*N + n)
    const int b = mbase >> 12;
    const int nbase = mbase & (NPT - 1);

    if (tid < 248) {
        float v;
        if      (tid <  24) v = w0[tid];
        else if (tid <  32) v = b0[tid - 24];
        else if (tid <  96) v = w1[tid - 32];
        else if (tid < 104) v = b1[tid - 96];
        else if (tid < 232) v = w2[tid - 104];
        else                v = b2[tid - 232];
        wp[tid] = v;
    }
    for (int e = tid; e < PTS * NBR; e += 256)
        nb[e] = idx[(size_t)mbase * NBR + e];
    __syncthreads();

    // ---- weightnet: one thread per (point, neighbor) ----
    if (tid < PTS * NBR) {
        const int p = tid / NBR, k = tid % NBR;
        const int n = nbase + p;
        const int j = nb[p * NBR + k];
        const float* q = qxyz + (size_t)b * 3 * NPT;
        const float* c = cxyz + (size_t)b * 3 * NPT;
        const float dx = c[j]           - q[n];
        const float dy = c[NPT + j]     - q[NPT + n];
        const float dz = c[2 * NPT + j] - q[2 * NPT + n];
        float h1[8], h2[8];
        #pragma unroll
        for (int o = 0; o < 8; ++o) {
            float v = wp[24 + o];
            v = fmaf(dx, wp[o], v);
            v = fmaf(dy, wp[8 + o], v);
            v = fmaf(dz, wp[16 + o], v);
            h1[o] = fmaxf(v, 0.f);
        }
        #pragma unroll
        for (int o = 0; o < 8; ++o) {
            float v = wp[96 + o];
            #pragma unroll
            for (int i = 0; i < 8; ++i) v = fmaf(h1[i], wp[32 + i * 8 + o], v);
            h2[o] = fmaxf(v, 0.f);
        }
        #pragma unroll
        for (int o = 0; o < WD; ++o) {
            float v = wp[232 + o];
            #pragma unroll
            for (int i = 0; i < 8; ++i) v = fmaf(h2[i], wp[104 + i * WD + o], v);
            wgt[p * WSTR + k * WD + o] = fmaxf(v, 0.f);
        }
    }

    // ---- own rows (fp32, constant over k) ----
    for (int e = tid; e < PTS * (D2 / 4); e += 256) {
        const int p = e / (D2 / 4), c4 = (e % (D2 / 4)) * 4;
        const float4 v = *(const float4*)(own_pm + ((size_t)mbase + p) * D2 + c4);
        float* dst = ownrow + p * OSTR + c4;
        dst[0] = v.x; dst[1] = v.y; dst[2] = v.z; dst[3] = v.w;
    }
    // ---- gathered neighbor rows (bf16) ----
    for (int e = tid; e < PTS * NBR * (D2 / 4); e += 256) {
        const int p  = e / (NBR * (D2 / 4));
        const int r  = e % (NBR * (D2 / 4));
        const int k  = r / (D2 / 4), c4 = (r % (D2 / 4)) * 4;
        const int j  = nb[p * NBR + k];
        const float4 v = *(const float4*)(nbr_pm + ((size_t)b * NPT + j) * D2 + c4);
        bf16* dst = feats + p * FSTR + k * D2 + c4;
        dst[0] = __float2bfloat16(v.x); dst[1] = __float2bfloat16(v.y);
        dst[2] = __float2bfloat16(v.z); dst[3] = __float2bfloat16(v.w);
    }
    __syncthreads();

    // ---- aggregation: thread -> (p = tid%PTS, dg = tid/PTS), 8 d-values each.
    // Wave-uniform split: low dg (own half, constant over k) vs high dg (gather).
    const int p  = tid % PTS;
    const int dg = tid / PTS;                 // 0..TPP-1
    const float* wg = wgt + p * WSTR;
    bf16* aout = agg + ((size_t)blockIdx.x * PTS + p) * (DT * WD) + (size_t)dg * 8 * WD;

    if (dg * 8 < D2) {
        float sw[WD];
        #pragma unroll
        for (int w = 0; w < WD; ++w) {
            float s = 0.f;
            #pragma unroll
            for (int k = 0; k < NBR; ++k) s += wg[k * WD + w];
            sw[w] = s;
        }
        #pragma unroll
        for (int di = 0; di < 8; ++di) {
            const float f = ownrow[p * OSTR + dg * 8 + di];
            union { bf16 h[16]; uint4 q[2]; } pk;
            #pragma unroll
            for (int w = 0; w < WD; ++w) pk.h[w] = __float2bfloat16(f * sw[w]);
            *(uint4*)(aout + di * WD)     = pk.q[0];
            *(uint4*)(aout + di * WD + 8) = pk.q[1];
        }
    } else {
        const bf16* fb = feats + p * FSTR + (dg * 8 - D2);
        #pragma unroll
        for (int di = 0; di < 8; ++di) {
            float F[NBR];
            #pragma unroll
            for (int k = 0; k < NBR; ++k) F[k] = __bfloat162float(fb[k * D2 + di]);
            union { bf16 h[16]; uint4 q[2]; } pk;
            #pragma unroll
            for (int w = 0; w < WD; ++w) {
                float s = 0.f;
                #pragma unroll
                for (int k = 0; k < NBR; ++k) s = fmaf(F[k], wg[k * WD + w], s);
                pk.h[w] = __float2bfloat16(s);
            }
            *(uint4*)(aout + di * WD)     = pk.q[0];
            *(uint4*)(aout + di * WD + 8) = pk.q[1];
        }
    }
}

// ---------------------------------------------------------------------------
// GEMM: out[m, o] = leaky( sum_K A[m,K]*Bw[K,o] + bias[o] ), A bf16, Bw fp32.
// 64x128 block tile, 256 threads, 4x8 per-thread tile, K-step 32.
// Epilogue stages the tile in LDS so both output layouts store coalesced:
//   out_t  : [B][128][N]  (d_out layout)
//   out_pm : [B*N][128]   (point-major, consumed by cross 3; may be null)
// ---------------------------------------------------------------------------
__global__ __launch_bounds__(256)
void gemm_kernel(const bf16* __restrict__ A, const float* __restrict__ Bw,
                 const float* __restrict__ bias,
                 float* __restrict__ out_t, float* __restrict__ out_pm,
                 int m0, int K)
{
    __shared__ __align__(16) char smem[64 * 133 * 4];
    bf16  (*AsT)[72]  = (bf16 (*)[72])smem;                  // [32][72] bf16 (A^T tile)
    float (*Bs)[132]  = (float (*)[132])(smem + 4608);       // [32][132]
    float (*tile)[133] = (float (*)[133])smem;               // reused in epilogue

    const int tid = threadIdx.x;
    const int ty = tid >> 4, tx = tid & 15;
    const int mb = (int)blockIdx.x * 64;

    float acc[4][8];
    #pragma unroll
    for (int i = 0; i < 4; ++i)
        #pragma unroll
        for (int j = 0; j < 8; ++j) acc[i][j] = 0.f;

    for (int k0 = 0; k0 < K; k0 += 32) {
        {   // A tile 64x32, stored transposed
            const int r = tid >> 2, ccol = (tid & 3) * 8;
            union { uint4 q; bf16 h[8]; } u;
            u.q = *(const uint4*)(A + (size_t)(mb + r) * K + k0 + ccol);
            #pragma unroll
            for (int jj = 0; jj < 8; ++jj) AsT[ccol + jj][r] = u.h[jj];
        }
        {   // B tile 32x128
            const int br = tid >> 5, bc = (tid & 31) * 4;
            #pragma unroll
            for (int rep = 0; rep < 4; ++rep) {
                const int r = br + rep * 8;
                *(float4*)&Bs[r][bc] = *(const float4*)(Bw + (size_t)(k0 + r) * MIDD + bc);
            }
        }
        __syncthreads();
        #pragma unroll
        for (int kk = 0; kk < 32; ++kk) {
            float a[4], bb[8];
            union { uint2 d; bf16 h[4]; } ua;
            ua.d = *(const uint2*)&AsT[kk][ty * 4];
            #pragma unroll
            for (int i = 0; i < 4; ++i) a[i] = __bfloat162float(ua.h[i]);
            const float4 bq0 = *(const float4*)&Bs[kk][tx * 8];
            const float4 bq1 = *(const float4*)&Bs[kk][tx * 8 + 4];
            bb[0] = bq0.x; bb[1] = bq0.y; bb[2] = bq0.z; bb[3] = bq0.w;
            bb[4] = bq1.x; bb[5] = bq1.y; bb[6] = bq1.z; bb[7] = bq1.w;
            #pragma unroll
            for (int i = 0; i < 4; ++i)
                #pragma unroll
                for (int j = 0; j < 8; ++j) acc[i][j] = fmaf(a[i], bb[j], acc[i][j]);
        }
        __syncthreads();
    }

    // epilogue: bias + leaky into LDS tile, then coalesced stores
    #pragma unroll
    for (int i = 0; i < 4; ++i)
        #pragma unroll
        for (int j = 0; j < 8; ++j) {
            const float v = acc[i][j] + bias[tx * 8 + j];
            tile[ty * 4 + i][tx * 8 + j] = v > 0.f ? v : 0.1f * v;
        }
    __syncthreads();

    const int mrow = m0 + mb;
    const int b = mrow >> 12, n0 = mrow & (NPT - 1);
    for (int e = tid; e < 64 * MIDD; e += 256) {
        const int o = e >> 6, i = e & 63;
        out_t[((size_t)b * MIDD + o) * NPT + n0 + i] = tile[i][o];
    }
    if (out_pm) {
        for (int e = tid; e < 64 * MIDD; e += 256) {
            const int i = e >> 7, o = e & 127;
            out_pm[((size_t)(mrow + i)) * MIDD + o] = tile[i][o];
        }
    }
}

// ---------------------------------------------------------------------------
extern "C" void kernel_launch(void* const* d_in, const int* in_sizes, int n_in,
                              void* d_out, int out_size, void* d_ws, size_t ws_size,
                              hipStream_t stream)
{
    (void)in_sizes; (void)n_in; (void)out_size;
    const float* pc1    = (const float*)d_in[0];
    const float* pc2    = (const float*)d_in[1];
    const float* feat1  = (const float*)d_in[2];
    const float* feat2  = (const float*)d_in[3];
    const float* wn1_w0 = (const float*)d_in[4];
    const float* wn1_b0 = (const float*)d_in[5];
    const float* wn1_w1 = (const float*)d_in[6];
    const float* wn1_b1 = (const float*)d_in[7];
    const float* wn1_w2 = (const float*)d_in[8];
    const float* wn1_b2 = (const float*)d_in[9];
    const float* lin1_w = (const float*)d_in[10];
    const float* lin1_b = (const float*)d_in[11];
    const float* wn2_w0 = (const float*)d_in[12];
    const float* wn2_b0 = (const float*)d_in[13];
    const float* wn2_w1 = (const float*)d_in[14];
    const float* wn2_b1 = (const float*)d_in[15];
    const float* wn2_w2 = (const float*)d_in[16];
    const float* wn2_b2 = (const float*)d_in[17];
    const float* lin2_w = (const float*)d_in[18];
    const float* lin2_b = (const float*)d_in[19];
    float* out = (float*)d_out;

    const int M = BB * NPT;                       // 16384 rows per cross
    char* ws = (char*)d_ws;
    float* p1pm = (float*)ws;                     // [M][64]
    float* p2pm = p1pm + (size_t)M * CDIM;        // [M][64]
    float* f1pm = p2pm + (size_t)M * CDIM;        // [M][128]
    float* f2pm = f1pm + (size_t)M * MIDD;        // [M][128]
    int* idx12  = (int*)(f2pm + (size_t)M * MIDD);
    int* idx21  = idx12 + (size_t)M * NBR;
    bf16* aggbuf = (bf16*)(idx21 + (size_t)M * NBR);
    const size_t used = (size_t)((char*)aggbuf - ws);
    const size_t avail = ws_size > used ? ws_size - used : 0;

    float* f1t = out;
    float* f2t = out + (size_t)BB * MIDD * NPT;
    float* fft = out + 2 * (size_t)BB * MIDD * NPT;

    transpose_kernel<<<dim3(NPT / 32, CDIM / 32, BB), dim3(32, 8), 0, stream>>>(feat1, p1pm, CDIM);
    transpose_kernel<<<dim3(NPT / 32, CDIM / 32, BB), dim3(32, 8), 0, stream>>>(feat2, p2pm, CDIM);
    knn_kernel<<<dim3(NPT / KNN_QB, BB, 2), 256, 0, stream>>>(pc1, pc2, idx12, idx21);

    // chunk rows so the agg scratch fits in whatever ws remains
    auto chunk_rows = [&](int K) -> int {
        long rows = (long)(avail / ((size_t)K * sizeof(bf16)));
        if (rows > M) rows = M;
        int cm = (int)rows & ~63;
        if (cm < 64) cm = 64;   // requires ws >= ~27 MB; standard harness scratch is larger
        return cm;
    };

    {   // cross 1 and cross 2 (K = 2048)
        const int K = 2 * CDIM * WD;
        const int CMr = chunk_rows(K);
        for (int m0 = 0; m0 < M; m0 += CMr) {
            const int cm = (M - m0 < CMr) ? (M - m0) : CMr;
            agg_kernel<CDIM, 16><<<cm / 16, 256, 0, stream>>>(
                pc1, pc2, p1pm, p2pm, idx12,
                wn1_w0, wn1_b0, wn1_w1, wn1_b1, wn1_w2, wn1_b2, aggbuf, m0);
            gemm_kernel<<<cm / 64, 256, 0, stream>>>(aggbuf, lin1_w, lin1_b, f1t, f1pm, m0, K);
        }
        for (int m0 = 0; m0 < M; m0 += CMr) {
            const int cm = (M - m0 < CMr) ? (M - m0) : CMr;
            agg_kernel<CDIM, 16><<<cm / 16, 256, 0, stream>>>(
                pc2, pc1, p2pm, p1pm, idx21,
                wn1_w0, wn1_b0, wn1_w1, wn1_b1, wn1_w2, wn1_b2, aggbuf, m0);
            gemm_kernel<<<cm / 64, 256, 0, stream>>>(aggbuf, lin1_w, lin1_b, f2t, f2pm, m0, K);
        }
    }
    {   // cross 3 (K = 4096) — reuses idx12; features are f1n/f2n point-major
        const int K = 2 * MIDD * WD;
        const int CMr = chunk_rows(K);
        for (int m0 = 0; m0 < M; m0 += CMr) {
            const int cm = (M - m0 < CMr) ? (M - m0) : CMr;
            agg_kernel<MIDD, 8><<<cm / 8, 256, 0, stream>>>(
                pc1, pc2, f1pm, f2pm, idx12,
                wn2_w0, wn2_b0, wn2_w1, wn2_b1, wn2_w2, wn2_b2, aggbuf, m0);
            gemm_kernel<<<cm / 64, 256, 0, stream>>>(aggbuf, lin2_w, lin2_b, fft, nullptr, m0, K);
        }
    }
}

// Round 3
// 817.126 us; speedup vs baseline: 2.6692x; 1.5291x over previous
//
#include <hip/hip_runtime.h>
#include <hip/hip_bf16.h>
#include <cstddef>
#include <cstdint>

typedef __hip_bfloat16 bf16;
typedef __attribute__((ext_vector_type(8))) short bf16x8;   // 8 bf16 = 4 VGPRs
typedef __attribute__((ext_vector_type(4))) float f32x4;

#define NPT 4096   // points per cloud
#define BB  4      // batch
#define NBR 16     // neighbors (nsample)
#define WD  16     // weightnet output width
#define CDIM 64    // input feature channels
#define MIDD 128   // lin1/lin2 output channels

// async global->LDS, 16B per lane; LDS dest is wave-uniform base + lane*16
#define GLD16(g, l) __builtin_amdgcn_global_load_lds( \
    (const __attribute__((address_space(1))) unsigned int*)(const void*)(g), \
    (__attribute__((address_space(3))) unsigned int*)(void*)(l), 16, 0, 0)

// ---------------------------------------------------------------------------
// Transpose [B][C][N] -> [B][N][C]
// ---------------------------------------------------------------------------
__global__ __launch_bounds__(256)
void transpose_kernel(const float* __restrict__ in, float* __restrict__ out, int C)
{
    __shared__ float t[32][33];
    const int b = blockIdx.z;
    const int n0 = blockIdx.x * 32, c0 = blockIdx.y * 32;
    const int tx = threadIdx.x, ty = threadIdx.y;
    #pragma unroll
    for (int r = ty; r < 32; r += 8)
        t[r][tx] = in[((size_t)b * C + c0 + r) * NPT + n0 + tx];
    __syncthreads();
    #pragma unroll
    for (int r = ty; r < 32; r += 8)
        out[((size_t)b * NPT + n0 + r) * C + c0 + tx] = t[tx][r];
}

// ---------------------------------------------------------------------------
// Split lin weights [K][128] f32 into transposed bf16 hi/lo: [128][K] each.
// B ~= hi + lo with |err| ~ 2^-17 |B|  => GEMM precision stays ~fp32 on B side.
// ---------------------------------------------------------------------------
__global__ __launch_bounds__(256)
void split_w_kernel(const float* __restrict__ w, bf16* __restrict__ hi,
                    bf16* __restrict__ lo, int K)
{
    __shared__ float t[32][33];
    const int k0 = blockIdx.x * 32, o0 = blockIdx.y * 32;
    const int tx = threadIdx.x, ty = threadIdx.y;
    #pragma unroll
    for (int r = ty; r < 32; r += 8)
        t[r][tx] = w[(size_t)(k0 + r) * MIDD + o0 + tx];
    __syncthreads();
    #pragma unroll
    for (int r = ty; r < 32; r += 8) {
        const float v = t[tx][r];
        const bf16 h = __float2bfloat16(v);
        const bf16 l2 = __float2bfloat16(v - __bfloat162float(h));
        hi[(size_t)(o0 + r) * K + k0 + tx] = h;
        lo[(size_t)(o0 + r) * K + k0 + tx] = l2;
    }
}

// ---------------------------------------------------------------------------
// KNN v2: segment-parallel top-16 + in-block merge (unchanged from round 2).
// ---------------------------------------------------------------------------
#define KNN_QB    32
#define KNN_SEG   8
#define KNN_STAGE 1024
#define KNN_SPAN  (KNN_STAGE / KNN_SEG)

__global__ __launch_bounds__(256)
void knn_kernel(const float* __restrict__ pcA, const float* __restrict__ pcB,
                int* __restrict__ idxAB, int* __restrict__ idxBA)
{
    const float *qxyz, *cxyz; int* idx_out;
    if (blockIdx.z == 0) { qxyz = pcA; cxyz = pcB; idx_out = idxAB; }
    else                 { qxyz = pcB; cxyz = pcA; idx_out = idxBA; }

    __shared__ float4 cf[KNN_STAGE];
    __shared__ float  ld[KNN_QB][129];
    __shared__ int    li[KNN_QB][129];

    const int tid = threadIdx.x;
    const int q   = tid & (KNN_QB - 1);
    const int s   = tid >> 5;
    const int b   = blockIdx.y;
    const int n   = blockIdx.x * KNN_QB + q;

    const float* qp = qxyz + (size_t)b * 3 * NPT;
    const float qx = qp[n], qy = qp[NPT + n], qz = qp[2 * NPT + n];
    const float q2 = fmaf(qx, qx, fmaf(qy, qy, qz * qz));

    float bd[NBR]; int bi[NBR];
    #pragma unroll
    for (int t = 0; t < NBR; ++t) { bd[t] = 3.4e38f; bi[t] = 0; }

    const float* c = cxyz + (size_t)b * 3 * NPT;
    for (int st = 0; st < NPT; st += KNN_STAGE) {
        __syncthreads();
        for (int j = tid; j < KNN_STAGE; j += 256) {
            const int g = st + j;
            const float x = c[g], y = c[NPT + g], z = c[2 * NPT + g];
            cf[j] = make_float4(x, y, z, fmaf(x, x, fmaf(y, y, z * z)));
        }
        __syncthreads();

        const int base = s * KNN_SPAN;
        #pragma unroll 4
        for (int j = 0; j < KNN_SPAN; ++j) {
            const float4 pv = cf[base + j];
            const float dot = fmaf(qx, pv.x, fmaf(qy, pv.y, qz * pv.z));
            const float d = q2 + pv.w - 2.f * dot;
            if (d < bd[NBR - 1]) {
                bd[NBR - 1] = d; bi[NBR - 1] = st + base + j;
                #pragma unroll
                for (int t = NBR - 1; t > 0; --t) {
                    if (bd[t] < bd[t - 1]) {
                        const float td = bd[t]; bd[t] = bd[t - 1]; bd[t - 1] = td;
                        const int   ti = bi[t]; bi[t] = bi[t - 1]; bi[t - 1] = ti;
                    }
                }
            }
        }
    }

    __syncthreads();
    #pragma unroll
    for (int t = 0; t < NBR; ++t) {
        ld[q][s * NBR + t] = bd[t];
        li[q][s * NBR + t] = bi[t];
    }
    __syncthreads();

    if (tid < KNN_QB) {
        int h0 = 0, h1 = 0, h2 = 0, h3 = 0, h4 = 0, h5 = 0, h6 = 0, h7 = 0;
        int* op = idx_out + ((size_t)b * NPT + blockIdx.x * KNN_QB + tid) * NBR;
        #pragma unroll 1
        for (int pick = 0; pick < NBR; ++pick) {
            float best = 3.5e38f; int bidx = 0x7fffffff;
            #define KNN_PROP(hh, ss)                                              \
                if (hh < NBR) {                                                   \
                    const float d = ld[tid][(ss) * NBR + hh];                     \
                    const int   i = li[tid][(ss) * NBR + hh];                     \
                    if (d < best || (d == best && i < bidx)) { best = d; bidx = i; } \
                }
            KNN_PROP(h0, 0) KNN_PROP(h1, 1) KNN_PROP(h2, 2) KNN_PROP(h3, 3)
            KNN_PROP(h4, 4) KNN_PROP(h5, 5) KNN_PROP(h6, 6) KNN_PROP(h7, 7)
            #undef KNN_PROP
            #define KNN_ADV(hh, ss)                                               \
                if (hh < NBR && li[tid][(ss) * NBR + hh] == bidx) hh++;
            KNN_ADV(h0, 0) KNN_ADV(h1, 1) KNN_ADV(h2, 2) KNN_ADV(h3, 3)
            KNN_ADV(h4, 4) KNN_ADV(h5, 5) KNN_ADV(h6, 6) KNN_ADV(h7, 7)
            #undef KNN_ADV
            op[pick] = bidx;
        }
    }
}

// ---------------------------------------------------------------------------
// Per-point weightnet + aggregation (unchanged from round 2).
// ---------------------------------------------------------------------------
template<int D2, int PTS>
__global__ __launch_bounds__(256)
void agg_kernel(const float* __restrict__ qxyz, const float* __restrict__ cxyz,
                const float* __restrict__ own_pm, const float* __restrict__ nbr_pm,
                const int* __restrict__ idx,
                const float* __restrict__ w0, const float* __restrict__ b0,
                const float* __restrict__ w1, const float* __restrict__ b1,
                const float* __restrict__ w2, const float* __restrict__ b2,
                bf16* __restrict__ agg, int m0)
{
    constexpr int DT   = 2 * D2;
    constexpr int WSTR = NBR * WD + 12;
    constexpr int OSTR = D2 + 2;
    constexpr int FSTR = NBR * D2 + 2;

    __shared__ float wp[248];
    __shared__ int   nb[PTS * NBR];
    __shared__ float wgt[PTS * WSTR];
    __shared__ float ownrow[PTS * OSTR];
    __shared__ bf16  feats[PTS * FSTR];

    const int tid = threadIdx.x;
    const int mbase = m0 + (int)blockIdx.x * PTS;
    const int b = mbase >> 12;
    const int nbase = mbase & (NPT - 1);

    if (tid < 248) {
        float v;
        if      (tid <  24) v = w0[tid];
        else if (tid <  32) v = b0[tid - 24];
        else if (tid <  96) v = w1[tid - 32];
        else if (tid < 104) v = b1[tid - 96];
        else if (tid < 232) v = w2[tid - 104];
        else                v = b2[tid - 232];
        wp[tid] = v;
    }
    for (int e = tid; e < PTS * NBR; e += 256)
        nb[e] = idx[(size_t)mbase * NBR + e];
    __syncthreads();

    if (tid < PTS * NBR) {
        const int p = tid / NBR, k = tid % NBR;
        const int n = nbase + p;
        const int j = nb[p * NBR + k];
        const float* q = qxyz + (size_t)b * 3 * NPT;
        const float* c = cxyz + (size_t)b * 3 * NPT;
        const float dx = c[j]           - q[n];
        const float dy = c[NPT + j]     - q[NPT + n];
        const float dz = c[2 * NPT + j] - q[2 * NPT + n];
        float h1[8], h2[8];
        #pragma unroll
        for (int o = 0; o < 8; ++o) {
            float v = wp[24 + o];
            v = fmaf(dx, wp[o], v);
            v = fmaf(dy, wp[8 + o], v);
            v = fmaf(dz, wp[16 + o], v);
            h1[o] = fmaxf(v, 0.f);
        }
        #pragma unroll
        for (int o = 0; o < 8; ++o) {
            float v = wp[96 + o];
            #pragma unroll
            for (int i = 0; i < 8; ++i) v = fmaf(h1[i], wp[32 + i * 8 + o], v);
            h2[o] = fmaxf(v, 0.f);
        }
        #pragma unroll
        for (int o = 0; o < WD; ++o) {
            float v = wp[232 + o];
            #pragma unroll
            for (int i = 0; i < 8; ++i) v = fmaf(h2[i], wp[104 + i * WD + o], v);
            wgt[p * WSTR + k * WD + o] = fmaxf(v, 0.f);
        }
    }

    for (int e = tid; e < PTS * (D2 / 4); e += 256) {
        const int p = e / (D2 / 4), c4 = (e % (D2 / 4)) * 4;
        const float4 v = *(const float4*)(own_pm + ((size_t)mbase + p) * D2 + c4);
        float* dst = ownrow + p * OSTR + c4;
        dst[0] = v.x; dst[1] = v.y; dst[2] = v.z; dst[3] = v.w;
    }
    for (int e = tid; e < PTS * NBR * (D2 / 4); e += 256) {
        const int p  = e / (NBR * (D2 / 4));
        const int r  = e % (NBR * (D2 / 4));
        const int k  = r / (D2 / 4), c4 = (r % (D2 / 4)) * 4;
        const int j  = nb[p * NBR + k];
        const float4 v = *(const float4*)(nbr_pm + ((size_t)b * NPT + j) * D2 + c4);
        bf16* dst = feats + p * FSTR + k * D2 + c4;
        dst[0] = __float2bfloat16(v.x); dst[1] = __float2bfloat16(v.y);
        dst[2] = __float2bfloat16(v.z); dst[3] = __float2bfloat16(v.w);
    }
    __syncthreads();

    const int p  = tid % PTS;
    const int dg = tid / PTS;
    const float* wg = wgt + p * WSTR;
    bf16* aout = agg + ((size_t)blockIdx.x * PTS + p) * (DT * WD) + (size_t)dg * 8 * WD;

    if (dg * 8 < D2) {
        float sw[WD];
        #pragma unroll
        for (int w = 0; w < WD; ++w) {
            float s = 0.f;
            #pragma unroll
            for (int k = 0; k < NBR; ++k) s += wg[k * WD + w];
            sw[w] = s;
        }
        #pragma unroll
        for (int di = 0; di < 8; ++di) {
            const float f = ownrow[p * OSTR + dg * 8 + di];
            union { bf16 h[16]; uint4 q[2]; } pk;
            #pragma unroll
            for (int w = 0; w < WD; ++w) pk.h[w] = __float2bfloat16(f * sw[w]);
            *(uint4*)(aout + di * WD)     = pk.q[0];
            *(uint4*)(aout + di * WD + 8) = pk.q[1];
        }
    } else {
        const bf16* fb = feats + p * FSTR + (dg * 8 - D2);
        #pragma unroll
        for (int di = 0; di < 8; ++di) {
            float F[NBR];
            #pragma unroll
            for (int k = 0; k < NBR; ++k) F[k] = __bfloat162float(fb[k * D2 + di]);
            union { bf16 h[16]; uint4 q[2]; } pk;
            #pragma unroll
            for (int w = 0; w < WD; ++w) {
                float s = 0.f;
                #pragma unroll
                for (int k = 0; k < NBR; ++k) s = fmaf(F[k], wg[k * WD + w], s);
                pk.h[w] = __float2bfloat16(s);
            }
            *(uint4*)(aout + di * WD)     = pk.q[0];
            *(uint4*)(aout + di * WD + 8) = pk.q[1];
        }
    }
}

// ---------------------------------------------------------------------------
// MFMA GEMM: out[m,o] = leaky( A[m,:] @ (Bhi+Blo)[:,o] + bias[o] )
//   A    : [rows][K] bf16 (chunk-local, rows = grid*128)
//   Bhi/Blo : [128][K] bf16 (transposed weights, hi/lo split)
// Block 128x128, BK=32, 4 waves (2x2), mfma_f32_16x16x32_bf16, fp32 acc.
// Double-buffered LDS staging via global_load_lds with XOR chunk swizzle
// (pre-swizzled global source + swizzled ds_read — matched involution).
// Outputs: out_t [b'][128][4096] with b' = mrow>>12 ; out_pm [m][128] (opt).
// ---------------------------------------------------------------------------
__global__ __launch_bounds__(256)
void gemm_mfma(const bf16* __restrict__ A, const bf16* __restrict__ Bhi,
               const bf16* __restrict__ Blo, const float* __restrict__ bias,
               float* __restrict__ out_t, float* __restrict__ out_pm,
               int m0, int K)
{
    __shared__ __align__(16) char smem[49152];   // 2 x (A 8KB + Bhi 8KB + Blo 8KB)
    bf16* lds = (bf16*)smem;

    const int tid  = threadIdx.x;
    const int w    = tid >> 6;        // wave 0..3
    const int lane = tid & 63;
    const int wr   = w >> 1, wc = w & 1;
    const int mb   = (int)blockIdx.x * 128;
    const int gK   = lane >> 4;       // k-group 0..3 (8 k each)
    const int rL   = lane & 15;

    f32x4 acc[4][4];
    #pragma unroll
    for (int i = 0; i < 4; ++i)
        #pragma unroll
        for (int j = 0; j < 4; ++j) acc[i][j] = (f32x4)0.f;

    // stage one 24KB k-tile (A + Bhi + Blo) into buffer `buf`
    auto stage = [&](int buf, int kt) {
        const int kb = kt * 32;
        const int bufo = buf * 12288;
        #pragma unroll
        for (int i = 0; i < 2; ++i) {
            const int s = i * 256 + tid;          // slot = row*4 + chunk
            const int row = s >> 2, ch = s & 3;
            const int sch = ch ^ (row & 3);       // pre-swizzled source chunk
            const int wavebase = (i * 256 + w * 64) << 3;   // elements
            GLD16(A   + (size_t)(mb + row) * K + kb + (sch << 3), lds + bufo +        wavebase);
            GLD16(Bhi + (size_t)row        * K + kb + (sch << 3), lds + bufo + 4096 + wavebase);
            GLD16(Blo + (size_t)row        * K + kb + (sch << 3), lds + bufo + 8192 + wavebase);
        }
    };

    stage(0, 0);
    __syncthreads();

    const int nk = K / 32;
    for (int kt = 0; kt < nk; ++kt) {
        const int cur = kt & 1;
        if (kt + 1 < nk) stage(cur ^ 1, kt + 1);

        const bf16* la  = lds + cur * 12288;
        const bf16* lbh = la + 4096;
        const bf16* lbl = la + 8192;

        bf16x8 af[4], bh[4], bl[4];
        #pragma unroll
        for (int mf = 0; mf < 4; ++mf) {
            const int row = wr * 64 + mf * 16 + rL;
            af[mf] = *(const bf16x8*)(la + row * 32 + ((gK ^ (row & 3)) << 3));
        }
        #pragma unroll
        for (int nf = 0; nf < 4; ++nf) {
            const int col = wc * 64 + nf * 16 + rL;
            const int off = col * 32 + ((gK ^ (col & 3)) << 3);
            bh[nf] = *(const bf16x8*)(lbh + off);
            bl[nf] = *(const bf16x8*)(lbl + off);
        }
        #pragma unroll
        for (int mf = 0; mf < 4; ++mf)
            #pragma unroll
            for (int nf = 0; nf < 4; ++nf) {
                acc[mf][nf] = __builtin_amdgcn_mfma_f32_16x16x32_bf16(af[mf], bh[nf], acc[mf][nf], 0, 0, 0);
                acc[mf][nf] = __builtin_amdgcn_mfma_f32_16x16x32_bf16(af[mf], bl[nf], acc[mf][nf], 0, 0, 0);
            }
        __syncthreads();
    }

    // epilogue: bias + leaky, stage half-tiles (64x128) in LDS, coalesced stores
    float (*tile)[133] = (float(*)[133])smem;
    for (int half = 0; half < 2; ++half) {
        __syncthreads();
        if (wr == half) {
            #pragma unroll
            for (int mf = 0; mf < 4; ++mf)
                #pragma unroll
                for (int nf = 0; nf < 4; ++nf) {
                    const int col = wc * 64 + nf * 16 + rL;
                    const float bs = bias[col];
                    #pragma unroll
                    for (int q = 0; q < 4; ++q) {
                        const int rrow = mf * 16 + gK * 4 + q;   // C/D: col=lane&15, row=(lane>>4)*4+reg
                        const float v = acc[mf][nf][q] + bs;
                        tile[rrow][col] = v > 0.f ? v : 0.1f * v;
                    }
                }
        }
        __syncthreads();
        const int mrow = m0 + mb + half * 64;
        const int b = mrow >> 12, n0 = mrow & (NPT - 1);
        for (int e = tid; e < 64 * MIDD; e += 256) {
            const int o = e >> 6, i = e & 63;
            out_t[((size_t)b * MIDD + o) * NPT + n0 + i] = tile[i][o];
        }
        if (out_pm) {
            for (int e = tid; e < 64 * MIDD; e += 256) {
                const int i = e >> 7, o = e & 127;
                out_pm[(size_t)(mrow + i) * MIDD + o] = tile[i][o];
            }
        }
    }
}

// ---------------------------------------------------------------------------
extern "C" void kernel_launch(void* const* d_in, const int* in_sizes, int n_in,
                              void* d_out, int out_size, void* d_ws, size_t ws_size,
                              hipStream_t stream)
{
    (void)in_sizes; (void)n_in; (void)out_size;
    const float* pc1    = (const float*)d_in[0];
    const float* pc2    = (const float*)d_in[1];
    const float* feat1  = (const float*)d_in[2];
    const float* feat2  = (const float*)d_in[3];
    const float* wn1_w0 = (const float*)d_in[4];
    const float* wn1_b0 = (const float*)d_in[5];
    const float* wn1_w1 = (const float*)d_in[6];
    const float* wn1_b1 = (const float*)d_in[7];
    const float* wn1_w2 = (const float*)d_in[8];
    const float* wn1_b2 = (const float*)d_in[9];
    const float* lin1_w = (const float*)d_in[10];
    const float* lin1_b = (const float*)d_in[11];
    const float* wn2_w0 = (const float*)d_in[12];
    const float* wn2_b0 = (const float*)d_in[13];
    const float* wn2_w1 = (const float*)d_in[14];
    const float* wn2_b1 = (const float*)d_in[15];
    const float* wn2_w2 = (const float*)d_in[16];
    const float* wn2_b2 = (const float*)d_in[17];
    const float* lin2_w = (const float*)d_in[18];
    const float* lin2_b = (const float*)d_in[19];
    float* out = (float*)d_out;

    const int M  = BB * NPT;          // 16384 rows per cross
    const int M2 = 2 * M;             // merged cross1+cross2 rows
    const int K1 = 2 * CDIM * WD;     // 2048
    const int K2 = 2 * MIDD * WD;     // 4096

    char* ws = (char*)d_ws;
    float* p1pm = (float*)ws;                         // [M][64]
    float* p2pm = p1pm + (size_t)M * CDIM;            // [M][64]
    float* f1pm = p2pm + (size_t)M * CDIM;            // [M][128] (merged pm base)
    float* f2pm = f1pm + (size_t)M * MIDD;            // [M][128] (contiguous after f1pm)
    int* idx12  = (int*)(f2pm + (size_t)M * MIDD);
    int* idx21  = idx12 + (size_t)M * NBR;
    bf16* b1hi  = (bf16*)(idx21 + (size_t)M * NBR);   // [128][2048]
    bf16* b1lo  = b1hi + (size_t)MIDD * K1;
    bf16* b2hi  = b1lo + (size_t)MIDD * K1;           // [128][4096]
    bf16* b2lo  = b2hi + (size_t)MIDD * K2;
    bf16* aggbuf = b2lo + (size_t)MIDD * K2;
    const size_t used = (size_t)((char*)aggbuf - ws);
    const size_t avail = ws_size > used ? ws_size - used : 0;

    float* f1t = out;                                  // merged out_t base (b' = m>>12)
    float* fft = out + 2 * (size_t)BB * MIDD * NPT;

    transpose_kernel<<<dim3(NPT / 32, CDIM / 32, BB), dim3(32, 8), 0, stream>>>(feat1, p1pm, CDIM);
    transpose_kernel<<<dim3(NPT / 32, CDIM / 32, BB), dim3(32, 8), 0, stream>>>(feat2, p2pm, CDIM);
    split_w_kernel<<<dim3(K1 / 32, MIDD / 32), dim3(32, 8), 0, stream>>>(lin1_w, b1hi, b1lo, K1);
    split_w_kernel<<<dim3(K2 / 32, MIDD / 32), dim3(32, 8), 0, stream>>>(lin2_w, b2hi, b2lo, K2);
    knn_kernel<<<dim3(NPT / KNN_QB, BB, 2), 256, 0, stream>>>(pc1, pc2, idx12, idx21);

    auto chunk_rows = [&](int K) -> int {
        long rows = (long)(avail / ((size_t)K * sizeof(bf16)));
        int cm = (int)(rows > M2 ? M2 : rows) & ~127;
        if (cm < 128) cm = 128;    // needs ~30 MB ws; harness scratch is larger
        return cm;
    };

    {   // cross 1 + cross 2 merged (K = 2048): rows [0,M) -> f1, [M,2M) -> f2
        const int CMr = chunk_rows(K1);
        for (int m0 = 0; m0 < M2; m0 += CMr) {
            const int cm = (M2 - m0 < CMr) ? (M2 - m0) : CMr;
            int done = 0;
            if (m0 < M) {
                const int c1 = (cm < M - m0) ? cm : (M - m0);
                agg_kernel<CDIM, 16><<<c1 / 16, 256, 0, stream>>>(
                    pc1, pc2, p1pm, p2pm, idx12,
                    wn1_w0, wn1_b0, wn1_w1, wn1_b1, wn1_w2, wn1_b2, aggbuf, m0);
                done = c1;
            }
            if (m0 + cm > M) {
                const int start2 = (m0 > M) ? m0 : M;
                const int c2 = m0 + cm - start2;
                agg_kernel<CDIM, 16><<<c2 / 16, 256, 0, stream>>>(
                    pc2, pc1, p2pm, p1pm, idx21,
                    wn1_w0, wn1_b0, wn1_w1, wn1_b1, wn1_w2, wn1_b2,
                    aggbuf + (size_t)done * K1, start2 - M);
            }
            gemm_mfma<<<cm / 128, 256, 0, stream>>>(aggbuf, b1hi, b1lo, lin1_b, f1t, f1pm, m0, K1);
        }
    }
    {   // cross 3 (K = 4096): reuses idx12; features f1n/f2n point-major
        const int CMr = chunk_rows(K2);
        for (int m0 = 0; m0 < M; m0 += CMr) {
            const int cm = (M - m0 < CMr) ? (M - m0) : CMr;
            agg_kernel<MIDD, 8><<<cm / 8, 256, 0, stream>>>(
                pc1, pc2, f1pm, f2pm, idx12,
                wn2_w0, wn2_b0, wn2_w1, wn2_b1, wn2_w2, wn2_b2, aggbuf, m0);
            gemm_mfma<<<cm / 128, 256, 0, stream>>>(aggbuf, b2hi, b2lo, lin2_b, fft, nullptr, m0, K2);
        }
    }
}

// Round 4
// 617.508 us; speedup vs baseline: 3.5321x; 1.3233x over previous
//
#include <hip/hip_runtime.h>
#include <hip/hip_bf16.h>
#include <cstddef>
#include <cstdint>

typedef __hip_bfloat16 bf16;
typedef __attribute__((ext_vector_type(8))) short bf16x8;   // 8 bf16 = 4 VGPRs
typedef __attribute__((ext_vector_type(4))) float f32x4;

#define NPT 4096   // points per cloud
#define BB  4      // batch
#define NBR 16     // neighbors (nsample)
#define WD  16     // weightnet output width
#define CDIM 64    // input feature channels
#define MIDD 128   // lin1/lin2 output channels

// async global->LDS, 16B per lane; LDS dest is wave-uniform base + lane*16
#define GLD16(g, l) __builtin_amdgcn_global_load_lds( \
    (const __attribute__((address_space(1))) unsigned int*)(const void*)(g), \
    (__attribute__((address_space(3))) unsigned int*)(void*)(l), 16, 0, 0)

// ---------------------------------------------------------------------------
// Transpose [B][C][N] -> [B][N][C]
// ---------------------------------------------------------------------------
__global__ __launch_bounds__(256)
void transpose_kernel(const float* __restrict__ in, float* __restrict__ out, int C)
{
    __shared__ float t[32][33];
    const int b = blockIdx.z;
    const int n0 = blockIdx.x * 32, c0 = blockIdx.y * 32;
    const int tx = threadIdx.x, ty = threadIdx.y;
    #pragma unroll
    for (int r = ty; r < 32; r += 8)
        t[r][tx] = in[((size_t)b * C + c0 + r) * NPT + n0 + tx];
    __syncthreads();
    #pragma unroll
    for (int r = ty; r < 32; r += 8)
        out[((size_t)b * NPT + n0 + r) * C + c0 + tx] = t[tx][r];
}

// ---------------------------------------------------------------------------
// Split lin weights [K][128] f32 into transposed bf16 hi/lo: [128][K] each.
// ---------------------------------------------------------------------------
__global__ __launch_bounds__(256)
void split_w_kernel(const float* __restrict__ w, bf16* __restrict__ hi,
                    bf16* __restrict__ lo, int K)
{
    __shared__ float t[32][33];
    const int k0 = blockIdx.x * 32, o0 = blockIdx.y * 32;
    const int tx = threadIdx.x, ty = threadIdx.y;
    #pragma unroll
    for (int r = ty; r < 32; r += 8)
        t[r][tx] = w[(size_t)(k0 + r) * MIDD + o0 + tx];
    __syncthreads();
    #pragma unroll
    for (int r = ty; r < 32; r += 8) {
        const float v = t[tx][r];
        const bf16 h = __float2bfloat16(v);
        const bf16 l2 = __float2bfloat16(v - __bfloat162float(h));
        hi[(size_t)(o0 + r) * K + k0 + tx] = h;
        lo[(size_t)(o0 + r) * K + k0 + tx] = l2;
    }
}

// ---------------------------------------------------------------------------
// KNN v3: two-pass threshold selection (no per-candidate insertion network).
// Block = 256 threads = 16 queries x 16 segments; segment s covers candidate
// ranges [chunk*1024 + s*64, +64) per staged chunk.
//  P1: per (q,s) track 2 smallest distance VALUES (branchless min/max/min).
//  u16: 16th smallest of the 32 published values per query (rank-count).
//      Validity: the 32 values are 32 distinct candidates, so >=16 candidates
//      have d <= u16 >= true d16 -> gating by d <= u16 drops no top-16 member.
//  P2: rescan (bit-identical fmaf distance expr), append d<=u16 survivors
//      (~20/query) to per-query LDS ring via shared atomics.
//  Final: rank-count select by (d, idx) lexicographic == jax.lax.top_k tie
//      semantics; order-independent of atomic arrival => deterministic.
// ---------------------------------------------------------------------------
#define KQ     16     // queries per block
#define KSEG   16     // segments per query
#define KCH    64     // candidates per segment per staged chunk
#define KSTAGE 1024   // candidates staged per chunk
#define KRING  96     // ring capacity per query (expected ~20 used)

__global__ __launch_bounds__(256)
void knn_kernel(const float* __restrict__ pcA, const float* __restrict__ pcB,
                int* __restrict__ idxAB, int* __restrict__ idxBA)
{
    const float *qxyz, *cxyz; int* idx_out;
    if (blockIdx.z == 0) { qxyz = pcA; cxyz = pcB; idx_out = idxAB; }
    else                 { qxyz = pcB; cxyz = pcA; idx_out = idxBA; }

    __shared__ float4 cf[KSTAGE];            // 16 KB: x,y,z,|p|^2
    __shared__ float  pubd[2][KSEG][KQ];     // 2 KB
    __shared__ float  u16s[KQ];
    __shared__ int    rcnt[KQ];
    __shared__ float  ringd[KQ][KRING + 1];  // +1 pad: stride 97 -> conflict-free
    __shared__ int    ringi[KQ][KRING + 1];

    const int tid = threadIdx.x;
    const int q   = tid & (KQ - 1);
    const int s   = tid >> 4;
    const int b   = blockIdx.y;
    const int n   = blockIdx.x * KQ + q;

    const float* qp = qxyz + (size_t)b * 3 * NPT;
    const float qx = qp[n], qy = qp[NPT + n], qz = qp[2 * NPT + n];
    const float q2 = fmaf(qx, qx, fmaf(qy, qy, qz * qz));
    const float* c = cxyz + (size_t)b * 3 * NPT;

    if (tid < KQ) rcnt[tid] = 0;

    // ---- pass 1: two smallest distance values per (q,s) ----
    float b0 = 3.4e38f, b1 = 3.4e38f;
    for (int st = 0; st < NPT; st += KSTAGE) {
        __syncthreads();
        for (int j = tid; j < KSTAGE; j += 256) {
            const int g = st + j;
            const float x = c[g], y = c[NPT + g], z = c[2 * NPT + g];
            cf[j] = make_float4(x, y, z, fmaf(x, x, fmaf(y, y, z * z)));
        }
        __syncthreads();
        const int base = s * KCH;
        #pragma unroll 4
        for (int jj = 0; jj < KCH; ++jj) {
            const float4 pv = cf[base + jj];
            const float dot = fmaf(qx, pv.x, fmaf(qy, pv.y, qz * pv.z));
            const float d = q2 + pv.w - 2.f * dot;
            const float t = fmaxf(b0, d);
            b0 = fminf(b0, d);
            b1 = fminf(b1, t);
        }
    }
    pubd[0][s][q] = b0;
    pubd[1][s][q] = b1;
    __syncthreads();

    // ---- u16: 16th smallest of 32 published values (rank == 15) ----
    {
        float tv[32];
        #pragma unroll
        for (int j = 0; j < 32; ++j) tv[j] = pubd[j >> 4][j & 15][q];
        #pragma unroll
        for (int rep = 0; rep < 2; ++rep) {
            const int j = rep * 16 + s;                  // this thread's value index
            const float vj = pubd[rep][s][q];            // LDS re-read (avoid runtime reg index)
            int rank = 0;
            #pragma unroll
            for (int k = 0; k < 32; ++k)
                rank += (tv[k] < vj || (tv[k] == vj && k < j)) ? 1 : 0;
            if (rank == 15) u16s[q] = vj;                // exactly one writer per query
        }
    }
    __syncthreads();
    const float ugate = u16s[q];

    // ---- pass 2: collect all candidates with d <= ugate ----
    for (int st = 0; st < NPT; st += KSTAGE) {
        __syncthreads();
        for (int j = tid; j < KSTAGE; j += 256) {
            const int g = st + j;
            const float x = c[g], y = c[NPT + g], z = c[2 * NPT + g];
            cf[j] = make_float4(x, y, z, fmaf(x, x, fmaf(y, y, z * z)));
        }
        __syncthreads();
        const int base = s * KCH;
        #pragma unroll 4
        for (int jj = 0; jj < KCH; ++jj) {
            const float4 pv = cf[base + jj];
            const float dot = fmaf(qx, pv.x, fmaf(qy, pv.y, qz * pv.z));
            const float d = q2 + pv.w - 2.f * dot;
            if (d <= ugate) {
                const int slot = atomicAdd(&rcnt[q], 1);
                if (slot < KRING) { ringd[q][slot] = d; ringi[q][slot] = st + base + jj; }
            }
        }
    }
    __syncthreads();

    // ---- final: exact (d, idx) rank-select of top-16 from the ring ----
    {
        const int cnt = min(rcnt[q], KRING);             // cnt >= 16 guaranteed
        int* op = idx_out + ((size_t)b * NPT + n) * NBR;
        for (int e = s; e < cnt; e += KSEG) {
            const float de = ringd[q][e];
            const int   ie = ringi[q][e];
            int rank = 0;
            for (int k = 0; k < cnt; ++k) {
                const float dk = ringd[q][k];
                const int   ik = ringi[q][k];
                rank += (dk < de || (dk == de && ik < ie)) ? 1 : 0;
            }
            if (rank < NBR) op[rank] = ie;               // ranks distinct -> each written once
        }
    }
}

// ---------------------------------------------------------------------------
// Per-point weightnet + aggregation (unchanged).
// ---------------------------------------------------------------------------
template<int D2, int PTS>
__global__ __launch_bounds__(256)
void agg_kernel(const float* __restrict__ qxyz, const float* __restrict__ cxyz,
                const float* __restrict__ own_pm, const float* __restrict__ nbr_pm,
                const int* __restrict__ idx,
                const float* __restrict__ w0, const float* __restrict__ b0,
                const float* __restrict__ w1, const float* __restrict__ b1,
                const float* __restrict__ w2, const float* __restrict__ b2,
                bf16* __restrict__ agg, int m0)
{
    constexpr int DT   = 2 * D2;
    constexpr int WSTR = NBR * WD + 12;
    constexpr int OSTR = D2 + 2;
    constexpr int FSTR = NBR * D2 + 2;

    __shared__ float wp[248];
    __shared__ int   nb[PTS * NBR];
    __shared__ float wgt[PTS * WSTR];
    __shared__ float ownrow[PTS * OSTR];
    __shared__ bf16  feats[PTS * FSTR];

    const int tid = threadIdx.x;
    const int mbase = m0 + (int)blockIdx.x * PTS;
    const int b = mbase >> 12;
    const int nbase = mbase & (NPT - 1);

    if (tid < 248) {
        float v;
        if      (tid <  24) v = w0[tid];
        else if (tid <  32) v = b0[tid - 24];
        else if (tid <  96) v = w1[tid - 32];
        else if (tid < 104) v = b1[tid - 96];
        else if (tid < 232) v = w2[tid - 104];
        else                v = b2[tid - 232];
        wp[tid] = v;
    }
    for (int e = tid; e < PTS * NBR; e += 256)
        nb[e] = idx[(size_t)mbase * NBR + e];
    __syncthreads();

    if (tid < PTS * NBR) {
        const int p = tid / NBR, k = tid % NBR;
        const int n = nbase + p;
        const int j = nb[p * NBR + k];
        const float* q = qxyz + (size_t)b * 3 * NPT;
        const float* c = cxyz + (size_t)b * 3 * NPT;
        const float dx = c[j]           - q[n];
        const float dy = c[NPT + j]     - q[NPT + n];
        const float dz = c[2 * NPT + j] - q[2 * NPT + n];
        float h1[8], h2[8];
        #pragma unroll
        for (int o = 0; o < 8; ++o) {
            float v = wp[24 + o];
            v = fmaf(dx, wp[o], v);
            v = fmaf(dy, wp[8 + o], v);
            v = fmaf(dz, wp[16 + o], v);
            h1[o] = fmaxf(v, 0.f);
        }
        #pragma unroll
        for (int o = 0; o < 8; ++o) {
            float v = wp[96 + o];
            #pragma unroll
            for (int i = 0; i < 8; ++i) v = fmaf(h1[i], wp[32 + i * 8 + o], v);
            h2[o] = fmaxf(v, 0.f);
        }
        #pragma unroll
        for (int o = 0; o < WD; ++o) {
            float v = wp[232 + o];
            #pragma unroll
            for (int i = 0; i < 8; ++i) v = fmaf(h2[i], wp[104 + i * WD + o], v);
            wgt[p * WSTR + k * WD + o] = fmaxf(v, 0.f);
        }
    }

    for (int e = tid; e < PTS * (D2 / 4); e += 256) {
        const int p = e / (D2 / 4), c4 = (e % (D2 / 4)) * 4;
        const float4 v = *(const float4*)(own_pm + ((size_t)mbase + p) * D2 + c4);
        float* dst = ownrow + p * OSTR + c4;
        dst[0] = v.x; dst[1] = v.y; dst[2] = v.z; dst[3] = v.w;
    }
    for (int e = tid; e < PTS * NBR * (D2 / 4); e += 256) {
        const int p  = e / (NBR * (D2 / 4));
        const int r  = e % (NBR * (D2 / 4));
        const int k  = r / (D2 / 4), c4 = (r % (D2 / 4)) * 4;
        const int j  = nb[p * NBR + k];
        const float4 v = *(const float4*)(nbr_pm + ((size_t)b * NPT + j) * D2 + c4);
        bf16* dst = feats + p * FSTR + k * D2 + c4;
        dst[0] = __float2bfloat16(v.x); dst[1] = __float2bfloat16(v.y);
        dst[2] = __float2bfloat16(v.z); dst[3] = __float2bfloat16(v.w);
    }
    __syncthreads();

    const int p  = tid % PTS;
    const int dg = tid / PTS;
    const float* wg = wgt + p * WSTR;
    bf16* aout = agg + ((size_t)blockIdx.x * PTS + p) * (DT * WD) + (size_t)dg * 8 * WD;

    if (dg * 8 < D2) {
        float sw[WD];
        #pragma unroll
        for (int w = 0; w < WD; ++w) {
            float s = 0.f;
            #pragma unroll
            for (int k = 0; k < NBR; ++k) s += wg[k * WD + w];
            sw[w] = s;
        }
        #pragma unroll
        for (int di = 0; di < 8; ++di) {
            const float f = ownrow[p * OSTR + dg * 8 + di];
            union { bf16 h[16]; uint4 q[2]; } pk;
            #pragma unroll
            for (int w = 0; w < WD; ++w) pk.h[w] = __float2bfloat16(f * sw[w]);
            *(uint4*)(aout + di * WD)     = pk.q[0];
            *(uint4*)(aout + di * WD + 8) = pk.q[1];
        }
    } else {
        const bf16* fb = feats + p * FSTR + (dg * 8 - D2);
        #pragma unroll
        for (int di = 0; di < 8; ++di) {
            float F[NBR];
            #pragma unroll
            for (int k = 0; k < NBR; ++k) F[k] = __bfloat162float(fb[k * D2 + di]);
            union { bf16 h[16]; uint4 q[2]; } pk;
            #pragma unroll
            for (int w = 0; w < WD; ++w) {
                float s = 0.f;
                #pragma unroll
                for (int k = 0; k < NBR; ++k) s = fmaf(F[k], wg[k * WD + w], s);
                pk.h[w] = __float2bfloat16(s);
            }
            *(uint4*)(aout + di * WD)     = pk.q[0];
            *(uint4*)(aout + di * WD + 8) = pk.q[1];
        }
    }
}

// ---------------------------------------------------------------------------
// MFMA GEMM (unchanged from round 3).
// ---------------------------------------------------------------------------
__global__ __launch_bounds__(256)
void gemm_mfma(const bf16* __restrict__ A, const bf16* __restrict__ Bhi,
               const bf16* __restrict__ Blo, const float* __restrict__ bias,
               float* __restrict__ out_t, float* __restrict__ out_pm,
               int m0, int K)
{
    __shared__ __align__(16) char smem[49152];
    bf16* lds = (bf16*)smem;

    const int tid  = threadIdx.x;
    const int w    = tid >> 6;
    const int lane = tid & 63;
    const int wr   = w >> 1, wc = w & 1;
    const int mb   = (int)blockIdx.x * 128;
    const int gK   = lane >> 4;
    const int rL   = lane & 15;

    f32x4 acc[4][4];
    #pragma unroll
    for (int i = 0; i < 4; ++i)
        #pragma unroll
        for (int j = 0; j < 4; ++j) acc[i][j] = (f32x4)0.f;

    auto stage = [&](int buf, int kt) {
        const int kb = kt * 32;
        const int bufo = buf * 12288;
        #pragma unroll
        for (int i = 0; i < 2; ++i) {
            const int sl = i * 256 + tid;
            const int row = sl >> 2, ch = sl & 3;
            const int sch = ch ^ (row & 3);
            const int wavebase = (i * 256 + w * 64) << 3;
            GLD16(A   + (size_t)(mb + row) * K + kb + (sch << 3), lds + bufo +        wavebase);
            GLD16(Bhi + (size_t)row        * K + kb + (sch << 3), lds + bufo + 4096 + wavebase);
            GLD16(Blo + (size_t)row        * K + kb + (sch << 3), lds + bufo + 8192 + wavebase);
        }
    };

    stage(0, 0);
    __syncthreads();

    const int nk = K / 32;
    for (int kt = 0; kt < nk; ++kt) {
        const int cur = kt & 1;
        if (kt + 1 < nk) stage(cur ^ 1, kt + 1);

        const bf16* la  = lds + cur * 12288;
        const bf16* lbh = la + 4096;
        const bf16* lbl = la + 8192;

        bf16x8 af[4], bh[4], bl[4];
        #pragma unroll
        for (int mf = 0; mf < 4; ++mf) {
            const int row = wr * 64 + mf * 16 + rL;
            af[mf] = *(const bf16x8*)(la + row * 32 + ((gK ^ (row & 3)) << 3));
        }
        #pragma unroll
        for (int nf = 0; nf < 4; ++nf) {
            const int col = wc * 64 + nf * 16 + rL;
            const int off = col * 32 + ((gK ^ (col & 3)) << 3);
            bh[nf] = *(const bf16x8*)(lbh + off);
            bl[nf] = *(const bf16x8*)(lbl + off);
        }
        #pragma unroll
        for (int mf = 0; mf < 4; ++mf)
            #pragma unroll
            for (int nf = 0; nf < 4; ++nf) {
                acc[mf][nf] = __builtin_amdgcn_mfma_f32_16x16x32_bf16(af[mf], bh[nf], acc[mf][nf], 0, 0, 0);
                acc[mf][nf] = __builtin_amdgcn_mfma_f32_16x16x32_bf16(af[mf], bl[nf], acc[mf][nf], 0, 0, 0);
            }
        __syncthreads();
    }

    float (*tile)[133] = (float(*)[133])smem;
    for (int half = 0; half < 2; ++half) {
        __syncthreads();
        if (wr == half) {
            #pragma unroll
            for (int mf = 0; mf < 4; ++mf)
                #pragma unroll
                for (int nf = 0; nf < 4; ++nf) {
                    const int col = wc * 64 + nf * 16 + rL;
                    const float bs = bias[col];
                    #pragma unroll
                    for (int qq = 0; qq < 4; ++qq) {
                        const int rrow = mf * 16 + gK * 4 + qq;
                        const float v = acc[mf][nf][qq] + bs;
                        tile[rrow][col] = v > 0.f ? v : 0.1f * v;
                    }
                }
        }
        __syncthreads();
        const int mrow = m0 + mb + half * 64;
        const int b = mrow >> 12, n0 = mrow & (NPT - 1);
        for (int e = tid; e < 64 * MIDD; e += 256) {
            const int o = e >> 6, i = e & 63;
            out_t[((size_t)b * MIDD + o) * NPT + n0 + i] = tile[i][o];
        }
        if (out_pm) {
            for (int e = tid; e < 64 * MIDD; e += 256) {
                const int i = e >> 7, o = e & 127;
                out_pm[(size_t)(mrow + i) * MIDD + o] = tile[i][o];
            }
        }
    }
}

// ---------------------------------------------------------------------------
extern "C" void kernel_launch(void* const* d_in, const int* in_sizes, int n_in,
                              void* d_out, int out_size, void* d_ws, size_t ws_size,
                              hipStream_t stream)
{
    (void)in_sizes; (void)n_in; (void)out_size;
    const float* pc1    = (const float*)d_in[0];
    const float* pc2    = (const float*)d_in[1];
    const float* feat1  = (const float*)d_in[2];
    const float* feat2  = (const float*)d_in[3];
    const float* wn1_w0 = (const float*)d_in[4];
    const float* wn1_b0 = (const float*)d_in[5];
    const float* wn1_w1 = (const float*)d_in[6];
    const float* wn1_b1 = (const float*)d_in[7];
    const float* wn1_w2 = (const float*)d_in[8];
    const float* wn1_b2 = (const float*)d_in[9];
    const float* lin1_w = (const float*)d_in[10];
    const float* lin1_b = (const float*)d_in[11];
    const float* wn2_w0 = (const float*)d_in[12];
    const float* wn2_b0 = (const float*)d_in[13];
    const float* wn2_w1 = (const float*)d_in[14];
    const float* wn2_b1 = (const float*)d_in[15];
    const float* wn2_w2 = (const float*)d_in[16];
    const float* wn2_b2 = (const float*)d_in[17];
    const float* lin2_w = (const float*)d_in[18];
    const float* lin2_b = (const float*)d_in[19];
    float* out = (float*)d_out;

    const int M  = BB * NPT;
    const int M2 = 2 * M;
    const int K1 = 2 * CDIM * WD;     // 2048
    const int K2 = 2 * MIDD * WD;     // 4096

    char* ws = (char*)d_ws;
    float* p1pm = (float*)ws;
    float* p2pm = p1pm + (size_t)M * CDIM;
    float* f1pm = p2pm + (size_t)M * CDIM;
    float* f2pm = f1pm + (size_t)M * MIDD;
    int* idx12  = (int*)(f2pm + (size_t)M * MIDD);
    int* idx21  = idx12 + (size_t)M * NBR;
    bf16* b1hi  = (bf16*)(idx21 + (size_t)M * NBR);
    bf16* b1lo  = b1hi + (size_t)MIDD * K1;
    bf16* b2hi  = b1lo + (size_t)MIDD * K1;
    bf16* b2lo  = b2hi + (size_t)MIDD * K2;
    bf16* aggbuf = b2lo + (size_t)MIDD * K2;
    const size_t used = (size_t)((char*)aggbuf - ws);
    const size_t avail = ws_size > used ? ws_size - used : 0;

    float* f1t = out;
    float* fft = out + 2 * (size_t)BB * MIDD * NPT;

    transpose_kernel<<<dim3(NPT / 32, CDIM / 32, BB), dim3(32, 8), 0, stream>>>(feat1, p1pm, CDIM);
    transpose_kernel<<<dim3(NPT / 32, CDIM / 32, BB), dim3(32, 8), 0, stream>>>(feat2, p2pm, CDIM);
    split_w_kernel<<<dim3(K1 / 32, MIDD / 32), dim3(32, 8), 0, stream>>>(lin1_w, b1hi, b1lo, K1);
    split_w_kernel<<<dim3(K2 / 32, MIDD / 32), dim3(32, 8), 0, stream>>>(lin2_w, b2hi, b2lo, K2);
    knn_kernel<<<dim3(NPT / KQ, BB, 2), 256, 0, stream>>>(pc1, pc2, idx12, idx21);

    auto chunk_rows = [&](int K) -> int {
        long rows = (long)(avail / ((size_t)K * sizeof(bf16)));
        int cm = (int)(rows > M2 ? M2 : rows) & ~127;
        if (cm < 128) cm = 128;
        return cm;
    };

    {   // cross 1 + cross 2 merged (K = 2048)
        const int CMr = chunk_rows(K1);
        for (int m0 = 0; m0 < M2; m0 += CMr) {
            const int cm = (M2 - m0 < CMr) ? (M2 - m0) : CMr;
            int done = 0;
            if (m0 < M) {
                const int c1 = (cm < M - m0) ? cm : (M - m0);
                agg_kernel<CDIM, 16><<<c1 / 16, 256, 0, stream>>>(
                    pc1, pc2, p1pm, p2pm, idx12,
                    wn1_w0, wn1_b0, wn1_w1, wn1_b1, wn1_w2, wn1_b2, aggbuf, m0);
                done = c1;
            }
            if (m0 + cm > M) {
                const int start2 = (m0 > M) ? m0 : M;
                const int c2 = m0 + cm - start2;
                agg_kernel<CDIM, 16><<<c2 / 16, 256, 0, stream>>>(
                    pc2, pc1, p2pm, p1pm, idx21,
                    wn1_w0, wn1_b0, wn1_w1, wn1_b1, wn1_w2, wn1_b2,
                    aggbuf + (size_t)done * K1, start2 - M);
            }
            gemm_mfma<<<cm / 128, 256, 0, stream>>>(aggbuf, b1hi, b1lo, lin1_b, f1t, f1pm, m0, K1);
        }
    }
    {   // cross 3 (K = 4096)
        const int CMr = chunk_rows(K2);
        for (int m0 = 0; m0 < M; m0 += CMr) {
            const int cm = (M - m0 < CMr) ? (M - m0) : CMr;
            agg_kernel<MIDD, 8><<<cm / 8, 256, 0, stream>>>(
                pc1, pc2, f1pm, f2pm, idx12,
                wn2_w0, wn2_b0, wn2_w1, wn2_b1, wn2_w2, wn2_b2, aggbuf, m0);
            gemm_mfma<<<cm / 128, 256, 0, stream>>>(aggbuf, b2hi, b2lo, lin2_b, fft, nullptr, m0, K2);
        }
    }
}

// Round 5
// 464.777 us; speedup vs baseline: 4.6927x; 1.3286x over previous
//
#include <hip/hip_runtime.h>
#include <hip/hip_bf16.h>
#include <cstddef>
#include <cstdint>

typedef __hip_bfloat16 bf16;
typedef __attribute__((ext_vector_type(8))) short bf16x8;   // 8 bf16 = 4 VGPRs
typedef __attribute__((ext_vector_type(4))) float f32x4;

#define NPT 4096   // points per cloud
#define BB  4      // batch
#define NBR 16     // neighbors (nsample)
#define WD  16     // weightnet output width
#define CDIM 64    // input feature channels
#define MIDD 128   // lin1/lin2 output channels

// async global->LDS, 16B per lane; LDS dest is wave-uniform base + lane*16
#define GLD16(g, l) __builtin_amdgcn_global_load_lds( \
    (const __attribute__((address_space(1))) unsigned int*)(const void*)(g), \
    (__attribute__((address_space(3))) unsigned int*)(void*)(l), 16, 0, 0)

// ---------------------------------------------------------------------------
// Transpose [B][C][N] -> [B][N][C], fp32 + bf16 copies (bf16 used for gathers;
// same __float2bfloat16 rounding the agg kernel previously applied).
// ---------------------------------------------------------------------------
__global__ __launch_bounds__(256)
void transpose_kernel(const float* __restrict__ in, float* __restrict__ out,
                      bf16* __restrict__ outb, int C)
{
    __shared__ float t[32][33];
    const int b = blockIdx.z;
    const int n0 = blockIdx.x * 32, c0 = blockIdx.y * 32;
    const int tx = threadIdx.x, ty = threadIdx.y;
    #pragma unroll
    for (int r = ty; r < 32; r += 8)
        t[r][tx] = in[((size_t)b * C + c0 + r) * NPT + n0 + tx];
    __syncthreads();
    #pragma unroll
    for (int r = ty; r < 32; r += 8) {
        const float v = t[tx][r];
        out [((size_t)b * NPT + n0 + r) * C + c0 + tx] = v;
        outb[((size_t)b * NPT + n0 + r) * C + c0 + tx] = __float2bfloat16(v);
    }
}

// ---------------------------------------------------------------------------
// Split lin weights [K][128] f32 into transposed bf16 hi/lo: [128][K] each.
// ---------------------------------------------------------------------------
__global__ __launch_bounds__(256)
void split_w_kernel(const float* __restrict__ w, bf16* __restrict__ hi,
                    bf16* __restrict__ lo, int K)
{
    __shared__ float t[32][33];
    const int k0 = blockIdx.x * 32, o0 = blockIdx.y * 32;
    const int tx = threadIdx.x, ty = threadIdx.y;
    #pragma unroll
    for (int r = ty; r < 32; r += 8)
        t[r][tx] = w[(size_t)(k0 + r) * MIDD + o0 + tx];
    __syncthreads();
    #pragma unroll
    for (int r = ty; r < 32; r += 8) {
        const float v = t[tx][r];
        const bf16 h = __float2bfloat16(v);
        const bf16 l2 = __float2bfloat16(v - __bfloat162float(h));
        hi[(size_t)(o0 + r) * K + k0 + tx] = h;
        lo[(size_t)(o0 + r) * K + k0 + tx] = l2;
    }
}

// ---------------------------------------------------------------------------
// KNN v3: two-pass threshold selection (unchanged from round 4).
// ---------------------------------------------------------------------------
#define KQ     16
#define KSEG   16
#define KCH    64
#define KSTAGE 1024
#define KRING  96

__global__ __launch_bounds__(256)
void knn_kernel(const float* __restrict__ pcA, const float* __restrict__ pcB,
                int* __restrict__ idxAB, int* __restrict__ idxBA)
{
    const float *qxyz, *cxyz; int* idx_out;
    if (blockIdx.z == 0) { qxyz = pcA; cxyz = pcB; idx_out = idxAB; }
    else                 { qxyz = pcB; cxyz = pcA; idx_out = idxBA; }

    __shared__ float4 cf[KSTAGE];
    __shared__ float  pubd[2][KSEG][KQ];
    __shared__ float  u16s[KQ];
    __shared__ int    rcnt[KQ];
    __shared__ float  ringd[KQ][KRING + 1];
    __shared__ int    ringi[KQ][KRING + 1];

    const int tid = threadIdx.x;
    const int q   = tid & (KQ - 1);
    const int s   = tid >> 4;
    const int b   = blockIdx.y;
    const int n   = blockIdx.x * KQ + q;

    const float* qp = qxyz + (size_t)b * 3 * NPT;
    const float qx = qp[n], qy = qp[NPT + n], qz = qp[2 * NPT + n];
    const float q2 = fmaf(qx, qx, fmaf(qy, qy, qz * qz));
    const float* c = cxyz + (size_t)b * 3 * NPT;

    if (tid < KQ) rcnt[tid] = 0;

    float b0 = 3.4e38f, b1 = 3.4e38f;
    for (int st = 0; st < NPT; st += KSTAGE) {
        __syncthreads();
        for (int j = tid; j < KSTAGE; j += 256) {
            const int g = st + j;
            const float x = c[g], y = c[NPT + g], z = c[2 * NPT + g];
            cf[j] = make_float4(x, y, z, fmaf(x, x, fmaf(y, y, z * z)));
        }
        __syncthreads();
        const int base = s * KCH;
        #pragma unroll 4
        for (int jj = 0; jj < KCH; ++jj) {
            const float4 pv = cf[base + jj];
            const float dot = fmaf(qx, pv.x, fmaf(qy, pv.y, qz * pv.z));
            const float d = q2 + pv.w - 2.f * dot;
            const float t = fmaxf(b0, d);
            b0 = fminf(b0, d);
            b1 = fminf(b1, t);
        }
    }
    pubd[0][s][q] = b0;
    pubd[1][s][q] = b1;
    __syncthreads();

    {
        float tv[32];
        #pragma unroll
        for (int j = 0; j < 32; ++j) tv[j] = pubd[j >> 4][j & 15][q];
        #pragma unroll
        for (int rep = 0; rep < 2; ++rep) {
            const int j = rep * 16 + s;
            const float vj = pubd[rep][s][q];
            int rank = 0;
            #pragma unroll
            for (int k = 0; k < 32; ++k)
                rank += (tv[k] < vj || (tv[k] == vj && k < j)) ? 1 : 0;
            if (rank == 15) u16s[q] = vj;
        }
    }
    __syncthreads();
    const float ugate = u16s[q];

    for (int st = 0; st < NPT; st += KSTAGE) {
        __syncthreads();
        for (int j = tid; j < KSTAGE; j += 256) {
            const int g = st + j;
            const float x = c[g], y = c[NPT + g], z = c[2 * NPT + g];
            cf[j] = make_float4(x, y, z, fmaf(x, x, fmaf(y, y, z * z)));
        }
        __syncthreads();
        const int base = s * KCH;
        #pragma unroll 4
        for (int jj = 0; jj < KCH; ++jj) {
            const float4 pv = cf[base + jj];
            const float dot = fmaf(qx, pv.x, fmaf(qy, pv.y, qz * pv.z));
            const float d = q2 + pv.w - 2.f * dot;
            if (d <= ugate) {
                const int slot = atomicAdd(&rcnt[q], 1);
                if (slot < KRING) { ringd[q][slot] = d; ringi[q][slot] = st + base + jj; }
            }
        }
    }
    __syncthreads();

    {
        const int cnt = min(rcnt[q], KRING);
        int* op = idx_out + ((size_t)b * NPT + n) * NBR;
        for (int e = s; e < cnt; e += KSEG) {
            const float de = ringd[q][e];
            const int   ie = ringi[q][e];
            int rank = 0;
            for (int k = 0; k < cnt; ++k) {
                const float dk = ringd[q][k];
                const int   ik = ringi[q][k];
                rank += (dk < de || (dk == de && ik < ie)) ? 1 : 0;
            }
            if (rank < NBR) op[rank] = ie;
        }
    }
}

// ---------------------------------------------------------------------------
// Weightnet + aggregation v2: vectorized LDS, k-outer register blocking.
//   agg[p][d][w] = sum_k pts[p][k][d] * wgt[p][k][w]; d<D2 own, d>=D2 gather.
// Thread map: p = tid & (PTS-1), dg = tid / PTS. dg < TPP/2 -> own half
// (4 d's each), else gather half (4 d's each, acc[4][16] in registers).
// Gather source is bf16 point-major (values identical to the old in-kernel
// conversion); FMA order over k unchanged -> bit-identical agg.
// ---------------------------------------------------------------------------
template<int D2, int PTS>
__global__ __launch_bounds__(256)
void agg_kernel(const float* __restrict__ qxyz, const float* __restrict__ cxyz,
                const float* __restrict__ own_pm, const bf16* __restrict__ nbr_b,
                const int* __restrict__ idx,
                const float* __restrict__ w0, const float* __restrict__ b0,
                const float* __restrict__ w1, const float* __restrict__ b1,
                const float* __restrict__ w2, const float* __restrict__ b2,
                bf16* __restrict__ agg, int m0)
{
    constexpr int TPP   = 256 / PTS;          // 32 (D2=64) or 64 (D2=128)
    constexpr int HALF  = TPP / 2;
    constexpr int WSTR  = 276;                // fp32; 16B-aligned, banks spread
    constexpr int OSTR  = D2 + 4;
    constexpr int FSTR  = NBR * D2 + 8;       // bf16; 16B-aligned, banks spread
    constexpr int CH    = (D2 * 2) / 16;      // uint4 chunks per gathered row
    constexpr int ROWCH = NBR * CH;           // chunks per point (128 / 256)

    __shared__ float wp[248];
    __shared__ int   nb[PTS * NBR];
    __shared__ float wgt[PTS * WSTR];
    __shared__ float ownrow[PTS * OSTR];
    __shared__ bf16  feats[PTS * FSTR];

    const int tid = threadIdx.x;
    const int mbase = m0 + (int)blockIdx.x * PTS;
    const int b = mbase >> 12;
    const int nbase = mbase & (NPT - 1);

    if (tid < 248) {
        float v;
        if      (tid <  24) v = w0[tid];
        else if (tid <  32) v = b0[tid - 24];
        else if (tid <  96) v = w1[tid - 32];
        else if (tid < 104) v = b1[tid - 96];
        else if (tid < 232) v = w2[tid - 104];
        else                v = b2[tid - 232];
        wp[tid] = v;
    }
    if (tid < PTS * NBR)
        nb[tid] = idx[(size_t)mbase * NBR + tid];
    if (tid < PTS * (D2 / 4)) {
        const int p = tid / (D2 / 4), c4 = (tid % (D2 / 4)) * 4;
        const float4 v = *(const float4*)(own_pm + ((size_t)mbase + p) * D2 + c4);
        float* dst = ownrow + p * OSTR + c4;
        dst[0] = v.x; dst[1] = v.y; dst[2] = v.z; dst[3] = v.w;
    }
    __syncthreads();

    // ---- gather loads: issue early (regs), LDS-write after weightnet ----
    uint4 rg[4]; int doff[4];
    #pragma unroll
    for (int i = 0; i < 4; ++i) {
        const int e = i * 256 + tid;              // PTS*ROWCH == 1024 exactly
        const int p = e / ROWCH, r = e % ROWCH;
        const int k = r / CH, cc = r % CH;
        const int j = nb[p * NBR + k];
        rg[i] = *(const uint4*)(nbr_b + ((size_t)b * NPT + j) * D2 + cc * 8);
        doff[i] = p * FSTR + k * D2 + cc * 8;
    }

    // ---- weightnet: one thread per (point, neighbor) ----
    if (tid < PTS * NBR) {
        const int p = tid / NBR, k = tid % NBR;
        const int n = nbase + p;
        const int j = nb[tid];
        const float* q = qxyz + (size_t)b * 3 * NPT;
        const float* c = cxyz + (size_t)b * 3 * NPT;
        const float dx = c[j]           - q[n];
        const float dy = c[NPT + j]     - q[NPT + n];
        const float dz = c[2 * NPT + j] - q[2 * NPT + n];
        float h1[8], h2[8];
        #pragma unroll
        for (int o = 0; o < 8; ++o) {
            float v = wp[24 + o];
            v = fmaf(dx, wp[o], v);
            v = fmaf(dy, wp[8 + o], v);
            v = fmaf(dz, wp[16 + o], v);
            h1[o] = fmaxf(v, 0.f);
        }
        #pragma unroll
        for (int o = 0; o < 8; ++o) {
            float v = wp[96 + o];
            #pragma unroll
            for (int i = 0; i < 8; ++i) v = fmaf(h1[i], wp[32 + i * 8 + o], v);
            h2[o] = fmaxf(v, 0.f);
        }
        #pragma unroll
        for (int o = 0; o < WD; ++o) {
            float v = wp[232 + o];
            #pragma unroll
            for (int i = 0; i < 8; ++i) v = fmaf(h2[i], wp[104 + i * WD + o], v);
            wgt[p * WSTR + k * WD + o] = fmaxf(v, 0.f);
        }
    }

    #pragma unroll
    for (int i = 0; i < 4; ++i)
        *(uint4*)(feats + doff[i]) = rg[i];
    __syncthreads();

    // ---- aggregation ----
    const int p  = tid & (PTS - 1);
    const int dg = tid / PTS;
    const float* wg = wgt + p * WSTR;
    bf16* aout = agg + ((size_t)((int)blockIdx.x * PTS + p)) * (2 * D2 * WD);

    if (dg < HALF) {
        const int d0 = dg * 4;
        float sw[16];
        #pragma unroll
        for (int w = 0; w < 16; ++w) sw[w] = 0.f;
        #pragma unroll
        for (int k = 0; k < NBR; ++k) {
            const float4 v0 = *(const float4*)(wg + k * WD);
            const float4 v1 = *(const float4*)(wg + k * WD + 4);
            const float4 v2 = *(const float4*)(wg + k * WD + 8);
            const float4 v3 = *(const float4*)(wg + k * WD + 12);
            sw[0]  += v0.x; sw[1]  += v0.y; sw[2]  += v0.z; sw[3]  += v0.w;
            sw[4]  += v1.x; sw[5]  += v1.y; sw[6]  += v1.z; sw[7]  += v1.w;
            sw[8]  += v2.x; sw[9]  += v2.y; sw[10] += v2.z; sw[11] += v2.w;
            sw[12] += v3.x; sw[13] += v3.y; sw[14] += v3.z; sw[15] += v3.w;
        }
        #pragma unroll
        for (int di = 0; di < 4; ++di) {
            const float f = ownrow[p * OSTR + d0 + di];
            union { bf16 h[16]; uint4 q[2]; } pk;
            #pragma unroll
            for (int w = 0; w < 16; ++w) pk.h[w] = __float2bfloat16(f * sw[w]);
            bf16* dst = aout + (d0 + di) * WD;
            *(uint4*)dst       = pk.q[0];
            *(uint4*)(dst + 8) = pk.q[1];
        }
    } else {
        const int d0 = (dg - HALF) * 4;
        const bf16* fb = feats + p * FSTR + d0;
        float acc[4][16];
        #pragma unroll
        for (int di = 0; di < 4; ++di)
            #pragma unroll
            for (int w = 0; w < 16; ++w) acc[di][w] = 0.f;
        #pragma unroll
        for (int k = 0; k < NBR; ++k) {
            union { uint2 u; bf16 h[4]; } uf;
            uf.u = *(const uint2*)(fb + k * D2);
            float F[4];
            #pragma unroll
            for (int j = 0; j < 4; ++j) F[j] = __bfloat162float(uf.h[j]);
            const float4 v0 = *(const float4*)(wg + k * WD);
            const float4 v1 = *(const float4*)(wg + k * WD + 4);
            const float4 v2 = *(const float4*)(wg + k * WD + 8);
            const float4 v3 = *(const float4*)(wg + k * WD + 12);
            float w16[16];
            w16[0]  = v0.x; w16[1]  = v0.y; w16[2]  = v0.z; w16[3]  = v0.w;
            w16[4]  = v1.x; w16[5]  = v1.y; w16[6]  = v1.z; w16[7]  = v1.w;
            w16[8]  = v2.x; w16[9]  = v2.y; w16[10] = v2.z; w16[11] = v2.w;
            w16[12] = v3.x; w16[13] = v3.y; w16[14] = v3.z; w16[15] = v3.w;
            #pragma unroll
            for (int di = 0; di < 4; ++di)
                #pragma unroll
                for (int w = 0; w < 16; ++w)
                    acc[di][w] = fmaf(F[di], w16[w], acc[di][w]);
        }
        #pragma unroll
        for (int di = 0; di < 4; ++di) {
            union { bf16 h[16]; uint4 q[2]; } pk;
            #pragma unroll
            for (int w = 0; w < 16; ++w) pk.h[w] = __float2bfloat16(acc[di][w]);
            bf16* dst = aout + (D2 + d0 + di) * WD;
            *(uint4*)dst       = pk.q[0];
            *(uint4*)(dst + 8) = pk.q[1];
        }
    }
}

// ---------------------------------------------------------------------------
// MFMA GEMM (round-3 structure; epilogue additionally emits bf16 point-major).
// ---------------------------------------------------------------------------
__global__ __launch_bounds__(256)
void gemm_mfma(const bf16* __restrict__ A, const bf16* __restrict__ Bhi,
               const bf16* __restrict__ Blo, const float* __restrict__ bias,
               float* __restrict__ out_t, float* __restrict__ out_pm,
               bf16* __restrict__ out_pmb, int m0, int K)
{
    __shared__ __align__(16) char smem[49152];
    bf16* lds = (bf16*)smem;

    const int tid  = threadIdx.x;
    const int w    = tid >> 6;
    const int lane = tid & 63;
    const int wr   = w >> 1, wc = w & 1;
    const int mb   = (int)blockIdx.x * 128;
    const int gK   = lane >> 4;
    const int rL   = lane & 15;

    f32x4 acc[4][4];
    #pragma unroll
    for (int i = 0; i < 4; ++i)
        #pragma unroll
        for (int j = 0; j < 4; ++j) acc[i][j] = (f32x4)0.f;

    auto stage = [&](int buf, int kt) {
        const int kb = kt * 32;
        const int bufo = buf * 12288;
        #pragma unroll
        for (int i = 0; i < 2; ++i) {
            const int sl = i * 256 + tid;
            const int row = sl >> 2, ch = sl & 3;
            const int sch = ch ^ (row & 3);
            const int wavebase = (i * 256 + w * 64) << 3;
            GLD16(A   + (size_t)(mb + row) * K + kb + (sch << 3), lds + bufo +        wavebase);
            GLD16(Bhi + (size_t)row        * K + kb + (sch << 3), lds + bufo + 4096 + wavebase);
            GLD16(Blo + (size_t)row        * K + kb + (sch << 3), lds + bufo + 8192 + wavebase);
        }
    };

    stage(0, 0);
    __syncthreads();

    const int nk = K / 32;
    for (int kt = 0; kt < nk; ++kt) {
        const int cur = kt & 1;
        if (kt + 1 < nk) stage(cur ^ 1, kt + 1);

        const bf16* la  = lds + cur * 12288;
        const bf16* lbh = la + 4096;
        const bf16* lbl = la + 8192;

        bf16x8 af[4], bh[4], bl[4];
        #pragma unroll
        for (int mf = 0; mf < 4; ++mf) {
            const int row = wr * 64 + mf * 16 + rL;
            af[mf] = *(const bf16x8*)(la + row * 32 + ((gK ^ (row & 3)) << 3));
        }
        #pragma unroll
        for (int nf = 0; nf < 4; ++nf) {
            const int col = wc * 64 + nf * 16 + rL;
            const int off = col * 32 + ((gK ^ (col & 3)) << 3);
            bh[nf] = *(const bf16x8*)(lbh + off);
            bl[nf] = *(const bf16x8*)(lbl + off);
        }
        #pragma unroll
        for (int mf = 0; mf < 4; ++mf)
            #pragma unroll
            for (int nf = 0; nf < 4; ++nf) {
                acc[mf][nf] = __builtin_amdgcn_mfma_f32_16x16x32_bf16(af[mf], bh[nf], acc[mf][nf], 0, 0, 0);
                acc[mf][nf] = __builtin_amdgcn_mfma_f32_16x16x32_bf16(af[mf], bl[nf], acc[mf][nf], 0, 0, 0);
            }
        __syncthreads();
    }

    float (*tile)[133] = (float(*)[133])smem;
    for (int half = 0; half < 2; ++half) {
        __syncthreads();
        if (wr == half) {
            #pragma unroll
            for (int mf = 0; mf < 4; ++mf)
                #pragma unroll
                for (int nf = 0; nf < 4; ++nf) {
                    const int col = wc * 64 + nf * 16 + rL;
                    const float bs = bias[col];
                    #pragma unroll
                    for (int qq = 0; qq < 4; ++qq) {
                        const int rrow = mf * 16 + gK * 4 + qq;
                        const float v = acc[mf][nf][qq] + bs;
                        tile[rrow][col] = v > 0.f ? v : 0.1f * v;
                    }
                }
        }
        __syncthreads();
        const int mrow = m0 + mb + half * 64;
        const int b = mrow >> 12, n0 = mrow & (NPT - 1);
        for (int e = tid; e < 64 * MIDD; e += 256) {
            const int o = e >> 6, i = e & 63;
            out_t[((size_t)b * MIDD + o) * NPT + n0 + i] = tile[i][o];
        }
        if (out_pm) {
            for (int e = tid; e < 64 * MIDD; e += 256) {
                const int i = e >> 7, o = e & 127;
                const float v = tile[i][o];
                out_pm [(size_t)(mrow + i) * MIDD + o] = v;
                out_pmb[(size_t)(mrow + i) * MIDD + o] = __float2bfloat16(v);
            }
        }
    }
}

// ---------------------------------------------------------------------------
extern "C" void kernel_launch(void* const* d_in, const int* in_sizes, int n_in,
                              void* d_out, int out_size, void* d_ws, size_t ws_size,
                              hipStream_t stream)
{
    (void)in_sizes; (void)n_in; (void)out_size;
    const float* pc1    = (const float*)d_in[0];
    const float* pc2    = (const float*)d_in[1];
    const float* feat1  = (const float*)d_in[2];
    const float* feat2  = (const float*)d_in[3];
    const float* wn1_w0 = (const float*)d_in[4];
    const float* wn1_b0 = (const float*)d_in[5];
    const float* wn1_w1 = (const float*)d_in[6];
    const float* wn1_b1 = (const float*)d_in[7];
    const float* wn1_w2 = (const float*)d_in[8];
    const float* wn1_b2 = (const float*)d_in[9];
    const float* lin1_w = (const float*)d_in[10];
    const float* lin1_b = (const float*)d_in[11];
    const float* wn2_w0 = (const float*)d_in[12];
    const float* wn2_b0 = (const float*)d_in[13];
    const float* wn2_w1 = (const float*)d_in[14];
    const float* wn2_b1 = (const float*)d_in[15];
    const float* wn2_w2 = (const float*)d_in[16];
    const float* wn2_b2 = (const float*)d_in[17];
    const float* lin2_w = (const float*)d_in[18];
    const float* lin2_b = (const float*)d_in[19];
    float* out = (float*)d_out;

    const int M  = BB * NPT;
    const int M2 = 2 * M;
    const int K1 = 2 * CDIM * WD;     // 2048
    const int K2 = 2 * MIDD * WD;     // 4096

    char* ws = (char*)d_ws;
    float* p1pm = (float*)ws;                          // [M][64] f32
    float* p2pm = p1pm + (size_t)M * CDIM;             // [M][64] f32
    float* fpm  = p2pm + (size_t)M * CDIM;             // [2M][128] f32 (f1|f2)
    bf16*  p1b  = (bf16*)(fpm + (size_t)M2 * MIDD);    // [M][64] bf16
    bf16*  p2b  = p1b + (size_t)M * CDIM;              // [M][64] bf16
    bf16*  fb   = p2b + (size_t)M * CDIM;              // [2M][128] bf16
    int* idx12  = (int*)(fb + (size_t)M2 * MIDD);
    int* idx21  = idx12 + (size_t)M * NBR;
    bf16* b1hi  = (bf16*)(idx21 + (size_t)M * NBR);
    bf16* b1lo  = b1hi + (size_t)MIDD * K1;
    bf16* b2hi  = b1lo + (size_t)MIDD * K1;
    bf16* b2lo  = b2hi + (size_t)MIDD * K2;
    bf16* aggbuf = b2lo + (size_t)MIDD * K2;
    const size_t used = (size_t)((char*)aggbuf - ws);
    const size_t avail = ws_size > used ? ws_size - used : 0;

    float* f1t = out;
    float* fft = out + 2 * (size_t)BB * MIDD * NPT;

    transpose_kernel<<<dim3(NPT / 32, CDIM / 32, BB), dim3(32, 8), 0, stream>>>(feat1, p1pm, p1b, CDIM);
    transpose_kernel<<<dim3(NPT / 32, CDIM / 32, BB), dim3(32, 8), 0, stream>>>(feat2, p2pm, p2b, CDIM);
    split_w_kernel<<<dim3(K1 / 32, MIDD / 32), dim3(32, 8), 0, stream>>>(lin1_w, b1hi, b1lo, K1);
    split_w_kernel<<<dim3(K2 / 32, MIDD / 32), dim3(32, 8), 0, stream>>>(lin2_w, b2hi, b2lo, K2);
    knn_kernel<<<dim3(NPT / KQ, BB, 2), 256, 0, stream>>>(pc1, pc2, idx12, idx21);

    auto chunk_rows = [&](int K) -> int {
        long rows = (long)(avail / ((size_t)K * sizeof(bf16)));
        int cm = (int)(rows > M2 ? M2 : rows) & ~127;
        if (cm < 128) cm = 128;
        return cm;
    };

    {   // cross 1 + cross 2 merged (K = 2048)
        const int CMr = chunk_rows(K1);
        for (int m0 = 0; m0 < M2; m0 += CMr) {
            const int cm = (M2 - m0 < CMr) ? (M2 - m0) : CMr;
            int done = 0;
            if (m0 < M) {
                const int c1 = (cm < M - m0) ? cm : (M - m0);
                agg_kernel<CDIM, 8><<<c1 / 8, 256, 0, stream>>>(
                    pc1, pc2, p1pm, p2b, idx12,
                    wn1_w0, wn1_b0, wn1_w1, wn1_b1, wn1_w2, wn1_b2, aggbuf, m0);
                done = c1;
            }
            if (m0 + cm > M) {
                const int start2 = (m0 > M) ? m0 : M;
                const int c2 = m0 + cm - start2;
                agg_kernel<CDIM, 8><<<c2 / 8, 256, 0, stream>>>(
                    pc2, pc1, p2pm, p1b, idx21,
                    wn1_w0, wn1_b0, wn1_w1, wn1_b1, wn1_w2, wn1_b2,
                    aggbuf + (size_t)done * K1, start2 - M);
            }
            gemm_mfma<<<cm / 128, 256, 0, stream>>>(aggbuf, b1hi, b1lo, lin1_b,
                                                    f1t, fpm, fb, m0, K1);
        }
    }
    {   // cross 3 (K = 4096): own = f1 (fp32), neighbors = f2 (bf16)
        const int CMr = chunk_rows(K2);
        for (int m0 = 0; m0 < M; m0 += CMr) {
            const int cm = (M - m0 < CMr) ? (M - m0) : CMr;
            agg_kernel<MIDD, 4><<<cm / 4, 256, 0, stream>>>(
                pc1, pc2, fpm, fb + (size_t)M * MIDD, idx12,
                wn2_w0, wn2_b0, wn2_w1, wn2_b1, wn2_w2, wn2_b2, aggbuf, m0);
            gemm_mfma<<<cm / 128, 256, 0, stream>>>(aggbuf, b2hi, b2lo, lin2_b,
                                                    fft, nullptr, nullptr, m0, K2);
        }
    }
}

// Round 6
// 457.527 us; speedup vs baseline: 4.7671x; 1.0158x over previous
//
#include <hip/hip_runtime.h>
#include <hip/hip_bf16.h>
#include <cstddef>
#include <cstdint>

typedef __hip_bfloat16 bf16;
typedef __attribute__((ext_vector_type(8))) short bf16x8;   // 8 bf16 = 4 VGPRs
typedef __attribute__((ext_vector_type(4))) float f32x4;

#define NPT 4096   // points per cloud
#define BB  4      // batch
#define NBR 16     // neighbors (nsample)
#define WD  16     // weightnet output width
#define CDIM 64    // input feature channels
#define MIDD 128   // lin1/lin2 output channels

// async global->LDS, 16B per lane; LDS dest is wave-uniform base + lane*16
#define GLD16(g, l) __builtin_amdgcn_global_load_lds( \
    (const __attribute__((address_space(1))) unsigned int*)(const void*)(g), \
    (__attribute__((address_space(3))) unsigned int*)(void*)(l), 16, 0, 0)

// ---------------------------------------------------------------------------
// Transpose [B][C][N] -> [B][N][C], fp32 + bf16 copies (bf16 used for gathers;
// same __float2bfloat16 rounding the agg kernel originally applied).
// ---------------------------------------------------------------------------
__global__ __launch_bounds__(256)
void transpose_kernel(const float* __restrict__ in, float* __restrict__ out,
                      bf16* __restrict__ outb, int C)
{
    __shared__ float t[32][33];
    const int b = blockIdx.z;
    const int n0 = blockIdx.x * 32, c0 = blockIdx.y * 32;
    const int tx = threadIdx.x, ty = threadIdx.y;
    #pragma unroll
    for (int r = ty; r < 32; r += 8)
        t[r][tx] = in[((size_t)b * C + c0 + r) * NPT + n0 + tx];
    __syncthreads();
    #pragma unroll
    for (int r = ty; r < 32; r += 8) {
        const float v = t[tx][r];
        out [((size_t)b * NPT + n0 + r) * C + c0 + tx] = v;
        outb[((size_t)b * NPT + n0 + r) * C + c0 + tx] = __float2bfloat16(v);
    }
}

// ---------------------------------------------------------------------------
// Split lin weights [K][128] f32 into transposed bf16 hi/lo: [128][K] each.
// ---------------------------------------------------------------------------
__global__ __launch_bounds__(256)
void split_w_kernel(const float* __restrict__ w, bf16* __restrict__ hi,
                    bf16* __restrict__ lo, int K)
{
    __shared__ float t[32][33];
    const int k0 = blockIdx.x * 32, o0 = blockIdx.y * 32;
    const int tx = threadIdx.x, ty = threadIdx.y;
    #pragma unroll
    for (int r = ty; r < 32; r += 8)
        t[r][tx] = w[(size_t)(k0 + r) * MIDD + o0 + tx];
    __syncthreads();
    #pragma unroll
    for (int r = ty; r < 32; r += 8) {
        const float v = t[tx][r];
        const bf16 h = __float2bfloat16(v);
        const bf16 l2 = __float2bfloat16(v - __bfloat162float(h));
        hi[(size_t)(o0 + r) * K + k0 + tx] = h;
        lo[(size_t)(o0 + r) * K + k0 + tx] = l2;
    }
}

// ---------------------------------------------------------------------------
// KNN v3: two-pass threshold selection (unchanged from round 4).
// ---------------------------------------------------------------------------
#define KQ     16
#define KSEG   16
#define KCH    64
#define KSTAGE 1024
#define KRING  96

__global__ __launch_bounds__(256)
void knn_kernel(const float* __restrict__ pcA, const float* __restrict__ pcB,
                int* __restrict__ idxAB, int* __restrict__ idxBA)
{
    const float *qxyz, *cxyz; int* idx_out;
    if (blockIdx.z == 0) { qxyz = pcA; cxyz = pcB; idx_out = idxAB; }
    else                 { qxyz = pcB; cxyz = pcA; idx_out = idxBA; }

    __shared__ float4 cf[KSTAGE];
    __shared__ float  pubd[2][KSEG][KQ];
    __shared__ float  u16s[KQ];
    __shared__ int    rcnt[KQ];
    __shared__ float  ringd[KQ][KRING + 1];
    __shared__ int    ringi[KQ][KRING + 1];

    const int tid = threadIdx.x;
    const int q   = tid & (KQ - 1);
    const int s   = tid >> 4;
    const int b   = blockIdx.y;
    const int n   = blockIdx.x * KQ + q;

    const float* qp = qxyz + (size_t)b * 3 * NPT;
    const float qx = qp[n], qy = qp[NPT + n], qz = qp[2 * NPT + n];
    const float q2 = fmaf(qx, qx, fmaf(qy, qy, qz * qz));
    const float* c = cxyz + (size_t)b * 3 * NPT;

    if (tid < KQ) rcnt[tid] = 0;

    float b0 = 3.4e38f, b1 = 3.4e38f;
    for (int st = 0; st < NPT; st += KSTAGE) {
        __syncthreads();
        for (int j = tid; j < KSTAGE; j += 256) {
            const int g = st + j;
            const float x = c[g], y = c[NPT + g], z = c[2 * NPT + g];
            cf[j] = make_float4(x, y, z, fmaf(x, x, fmaf(y, y, z * z)));
        }
        __syncthreads();
        const int base = s * KCH;
        #pragma unroll 4
        for (int jj = 0; jj < KCH; ++jj) {
            const float4 pv = cf[base + jj];
            const float dot = fmaf(qx, pv.x, fmaf(qy, pv.y, qz * pv.z));
            const float d = q2 + pv.w - 2.f * dot;
            const float t = fmaxf(b0, d);
            b0 = fminf(b0, d);
            b1 = fminf(b1, t);
        }
    }
    pubd[0][s][q] = b0;
    pubd[1][s][q] = b1;
    __syncthreads();

    {
        float tv[32];
        #pragma unroll
        for (int j = 0; j < 32; ++j) tv[j] = pubd[j >> 4][j & 15][q];
        #pragma unroll
        for (int rep = 0; rep < 2; ++rep) {
            const int j = rep * 16 + s;
            const float vj = pubd[rep][s][q];
            int rank = 0;
            #pragma unroll
            for (int k = 0; k < 32; ++k)
                rank += (tv[k] < vj || (tv[k] == vj && k < j)) ? 1 : 0;
            if (rank == 15) u16s[q] = vj;
        }
    }
    __syncthreads();
    const float ugate = u16s[q];

    for (int st = 0; st < NPT; st += KSTAGE) {
        __syncthreads();
        for (int j = tid; j < KSTAGE; j += 256) {
            const int g = st + j;
            const float x = c[g], y = c[NPT + g], z = c[2 * NPT + g];
            cf[j] = make_float4(x, y, z, fmaf(x, x, fmaf(y, y, z * z)));
        }
        __syncthreads();
        const int base = s * KCH;
        #pragma unroll 4
        for (int jj = 0; jj < KCH; ++jj) {
            const float4 pv = cf[base + jj];
            const float dot = fmaf(qx, pv.x, fmaf(qy, pv.y, qz * pv.z));
            const float d = q2 + pv.w - 2.f * dot;
            if (d <= ugate) {
                const int slot = atomicAdd(&rcnt[q], 1);
                if (slot < KRING) { ringd[q][slot] = d; ringi[q][slot] = st + base + jj; }
            }
        }
    }
    __syncthreads();

    {
        const int cnt = min(rcnt[q], KRING);
        int* op = idx_out + ((size_t)b * NPT + n) * NBR;
        for (int e = s; e < cnt; e += KSEG) {
            const float de = ringd[q][e];
            const int   ie = ringi[q][e];
            int rank = 0;
            for (int k = 0; k < cnt; ++k) {
                const float dk = ringd[q][k];
                const int   ik = ringi[q][k];
                rank += (dk < de || (dk == de && ik < ie)) ? 1 : 0;
            }
            if (rank < NBR) op[rank] = ie;
        }
    }
}

// ---------------------------------------------------------------------------
// Weightnet + aggregation v3: direct-to-register gathers, slim LDS.
//   agg[p][d][w] = sum_k pts[p][k][d] * wgt[p][k][w]; d<D2 own, d>=D2 gather.
// Thread map: p = tid & (PTS-1), dg = tid / PTS; dg < TPP/2 own (4 d's),
// else gather (4 d's, acc[4][16]). Gather feats are loaded straight from the
// bf16 point-major array into 16 uint2 registers (issued before weightnet so
// HBM/L2 latency hides under it); own rows read as one float4. Only wp/nb/wgt
// live in LDS (5.7-10.3 KB). Values and FMA order unchanged -> bit-identical.
// ---------------------------------------------------------------------------
template<int D2, int PTS>
__global__ __launch_bounds__(256)
void agg_kernel(const float* __restrict__ qxyz, const float* __restrict__ cxyz,
                const float* __restrict__ own_pm, const bf16* __restrict__ nbr_b,
                const int* __restrict__ idx,
                const float* __restrict__ w0, const float* __restrict__ b0,
                const float* __restrict__ w1, const float* __restrict__ b1,
                const float* __restrict__ w2, const float* __restrict__ b2,
                bf16* __restrict__ agg, int m0)
{
    constexpr int TPP   = 256 / PTS;          // 32 (D2=64) or 64 (D2=128)
    constexpr int HALF  = TPP / 2;
    constexpr int WSTR  = 276;                // fp32; 16B-aligned, banks spread

    __shared__ float wp[248];
    __shared__ int   nb[PTS * NBR];
    __shared__ float wgt[PTS * WSTR];

    const int tid = threadIdx.x;
    const int mbase = m0 + (int)blockIdx.x * PTS;
    const int b = mbase >> 12;
    const int nbase = mbase & (NPT - 1);

    if (tid < 248) {
        float v;
        if      (tid <  24) v = w0[tid];
        else if (tid <  32) v = b0[tid - 24];
        else if (tid <  96) v = w1[tid - 32];
        else if (tid < 104) v = b1[tid - 96];
        else if (tid < 232) v = w2[tid - 104];
        else                v = b2[tid - 232];
        wp[tid] = v;
    }
    if (tid < PTS * NBR)
        nb[tid] = idx[(size_t)mbase * NBR + tid];
    __syncthreads();

    const int p  = tid & (PTS - 1);
    const int dg = tid / PTS;

    // ---- direct prefetch into registers (latency hides under weightnet) ----
    uint2  F[NBR];        // gather half: f[k][d0..d0+3] bf16
    float4 ow;            // own half: own[d0..d0+3] fp32
    if (dg >= HALF) {
        const int d0 = (dg - HALF) * 4;
        const bf16* base = nbr_b + (size_t)b * NPT * D2 + d0;
        #pragma unroll
        for (int k = 0; k < NBR; ++k) {
            const int j = nb[p * NBR + k];
            F[k] = *(const uint2*)(base + (size_t)j * D2);
        }
    } else {
        ow = *(const float4*)(own_pm + ((size_t)mbase + p) * D2 + dg * 4);
    }

    // ---- weightnet: one thread per (point, neighbor); tid<PTS*NBR is a
    // subset of the own half, so gather prefetch stays in disjoint waves ----
    if (tid < PTS * NBR) {
        const int pp = tid / NBR, k = tid % NBR;
        const int n = nbase + pp;
        const int j = nb[tid];
        const float* q = qxyz + (size_t)b * 3 * NPT;
        const float* c = cxyz + (size_t)b * 3 * NPT;
        const float dx = c[j]           - q[n];
        const float dy = c[NPT + j]     - q[NPT + n];
        const float dz = c[2 * NPT + j] - q[2 * NPT + n];
        float h1[8], h2[8];
        #pragma unroll
        for (int o = 0; o < 8; ++o) {
            float v = wp[24 + o];
            v = fmaf(dx, wp[o], v);
            v = fmaf(dy, wp[8 + o], v);
            v = fmaf(dz, wp[16 + o], v);
            h1[o] = fmaxf(v, 0.f);
        }
        #pragma unroll
        for (int o = 0; o < 8; ++o) {
            float v = wp[96 + o];
            #pragma unroll
            for (int i = 0; i < 8; ++i) v = fmaf(h1[i], wp[32 + i * 8 + o], v);
            h2[o] = fmaxf(v, 0.f);
        }
        #pragma unroll
        for (int o = 0; o < WD; ++o) {
            float v = wp[232 + o];
            #pragma unroll
            for (int i = 0; i < 8; ++i) v = fmaf(h2[i], wp[104 + i * WD + o], v);
            wgt[pp * WSTR + k * WD + o] = fmaxf(v, 0.f);
        }
    }
    __syncthreads();

    // ---- aggregation ----
    const float* wg = wgt + p * WSTR;
    bf16* aout = agg + ((size_t)((int)blockIdx.x * PTS + p)) * (2 * D2 * WD);

    if (dg < HALF) {
        const int d0 = dg * 4;
        float sw[16];
        #pragma unroll
        for (int w = 0; w < 16; ++w) sw[w] = 0.f;
        #pragma unroll
        for (int k = 0; k < NBR; ++k) {
            const float4 v0 = *(const float4*)(wg + k * WD);
            const float4 v1 = *(const float4*)(wg + k * WD + 4);
            const float4 v2 = *(const float4*)(wg + k * WD + 8);
            const float4 v3 = *(const float4*)(wg + k * WD + 12);
            sw[0]  += v0.x; sw[1]  += v0.y; sw[2]  += v0.z; sw[3]  += v0.w;
            sw[4]  += v1.x; sw[5]  += v1.y; sw[6]  += v1.z; sw[7]  += v1.w;
            sw[8]  += v2.x; sw[9]  += v2.y; sw[10] += v2.z; sw[11] += v2.w;
            sw[12] += v3.x; sw[13] += v3.y; sw[14] += v3.z; sw[15] += v3.w;
        }
        const float od[4] = { ow.x, ow.y, ow.z, ow.w };
        #pragma unroll
        for (int di = 0; di < 4; ++di) {
            const float f = od[di];
            union { bf16 h[16]; uint4 q[2]; } pk;
            #pragma unroll
            for (int w = 0; w < 16; ++w) pk.h[w] = __float2bfloat16(f * sw[w]);
            bf16* dst = aout + (d0 + di) * WD;
            *(uint4*)dst       = pk.q[0];
            *(uint4*)(dst + 8) = pk.q[1];
        }
    } else {
        const int d0 = (dg - HALF) * 4;
        float acc[4][16];
        #pragma unroll
        for (int di = 0; di < 4; ++di)
            #pragma unroll
            for (int w = 0; w < 16; ++w) acc[di][w] = 0.f;
        #pragma unroll
        for (int k = 0; k < NBR; ++k) {
            union { uint2 u; bf16 h[4]; } uf;
            uf.u = F[k];
            float Fv[4];
            #pragma unroll
            for (int j = 0; j < 4; ++j) Fv[j] = __bfloat162float(uf.h[j]);
            const float4 v0 = *(const float4*)(wg + k * WD);
            const float4 v1 = *(const float4*)(wg + k * WD + 4);
            const float4 v2 = *(const float4*)(wg + k * WD + 8);
            const float4 v3 = *(const float4*)(wg + k * WD + 12);
            float w16[16];
            w16[0]  = v0.x; w16[1]  = v0.y; w16[2]  = v0.z; w16[3]  = v0.w;
            w16[4]  = v1.x; w16[5]  = v1.y; w16[6]  = v1.z; w16[7]  = v1.w;
            w16[8]  = v2.x; w16[9]  = v2.y; w16[10] = v2.z; w16[11] = v2.w;
            w16[12] = v3.x; w16[13] = v3.y; w16[14] = v3.z; w16[15] = v3.w;
            #pragma unroll
            for (int di = 0; di < 4; ++di)
                #pragma unroll
                for (int w = 0; w < 16; ++w)
                    acc[di][w] = fmaf(Fv[di], w16[w], acc[di][w]);
        }
        #pragma unroll
        for (int di = 0; di < 4; ++di) {
            union { bf16 h[16]; uint4 q[2]; } pk;
            #pragma unroll
            for (int w = 0; w < 16; ++w) pk.h[w] = __float2bfloat16(acc[di][w]);
            bf16* dst = aout + (D2 + d0 + di) * WD;
            *(uint4*)dst       = pk.q[0];
            *(uint4*)(dst + 8) = pk.q[1];
        }
    }
}

// ---------------------------------------------------------------------------
// MFMA GEMM (round-3 structure; epilogue also emits fp32+bf16 point-major).
// ---------------------------------------------------------------------------
__global__ __launch_bounds__(256)
void gemm_mfma(const bf16* __restrict__ A, const bf16* __restrict__ Bhi,
               const bf16* __restrict__ Blo, const float* __restrict__ bias,
               float* __restrict__ out_t, float* __restrict__ out_pm,
               bf16* __restrict__ out_pmb, int m0, int K)
{
    __shared__ __align__(16) char smem[49152];
    bf16* lds = (bf16*)smem;

    const int tid  = threadIdx.x;
    const int w    = tid >> 6;
    const int lane = tid & 63;
    const int wr   = w >> 1, wc = w & 1;
    const int mb   = (int)blockIdx.x * 128;
    const int gK   = lane >> 4;
    const int rL   = lane & 15;

    f32x4 acc[4][4];
    #pragma unroll
    for (int i = 0; i < 4; ++i)
        #pragma unroll
        for (int j = 0; j < 4; ++j) acc[i][j] = (f32x4)0.f;

    auto stage = [&](int buf, int kt) {
        const int kb = kt * 32;
        const int bufo = buf * 12288;
        #pragma unroll
        for (int i = 0; i < 2; ++i) {
            const int sl = i * 256 + tid;
            const int row = sl >> 2, ch = sl & 3;
            const int sch = ch ^ (row & 3);
            const int wavebase = (i * 256 + w * 64) << 3;
            GLD16(A   + (size_t)(mb + row) * K + kb + (sch << 3), lds + bufo +        wavebase);
            GLD16(Bhi + (size_t)row        * K + kb + (sch << 3), lds + bufo + 4096 + wavebase);
            GLD16(Blo + (size_t)row        * K + kb + (sch << 3), lds + bufo + 8192 + wavebase);
        }
    };

    stage(0, 0);
    __syncthreads();

    const int nk = K / 32;
    for (int kt = 0; kt < nk; ++kt) {
        const int cur = kt & 1;
        if (kt + 1 < nk) stage(cur ^ 1, kt + 1);

        const bf16* la  = lds + cur * 12288;
        const bf16* lbh = la + 4096;
        const bf16* lbl = la + 8192;

        bf16x8 af[4], bh[4], bl[4];
        #pragma unroll
        for (int mf = 0; mf < 4; ++mf) {
            const int row = wr * 64 + mf * 16 + rL;
            af[mf] = *(const bf16x8*)(la + row * 32 + ((gK ^ (row & 3)) << 3));
        }
        #pragma unroll
        for (int nf = 0; nf < 4; ++nf) {
            const int col = wc * 64 + nf * 16 + rL;
            const int off = col * 32 + ((gK ^ (col & 3)) << 3);
            bh[nf] = *(const bf16x8*)(lbh + off);
            bl[nf] = *(const bf16x8*)(lbl + off);
        }
        #pragma unroll
        for (int mf = 0; mf < 4; ++mf)
            #pragma unroll
            for (int nf = 0; nf < 4; ++nf) {
                acc[mf][nf] = __builtin_amdgcn_mfma_f32_16x16x32_bf16(af[mf], bh[nf], acc[mf][nf], 0, 0, 0);
                acc[mf][nf] = __builtin_amdgcn_mfma_f32_16x16x32_bf16(af[mf], bl[nf], acc[mf][nf], 0, 0, 0);
            }
        __syncthreads();
    }

    float (*tile)[133] = (float(*)[133])smem;
    for (int half = 0; half < 2; ++half) {
        __syncthreads();
        if (wr == half) {
            #pragma unroll
            for (int mf = 0; mf < 4; ++mf)
                #pragma unroll
                for (int nf = 0; nf < 4; ++nf) {
                    const int col = wc * 64 + nf * 16 + rL;
                    const float bs = bias[col];
                    #pragma unroll
                    for (int qq = 0; qq < 4; ++qq) {
                        const int rrow = mf * 16 + gK * 4 + qq;
                        const float v = acc[mf][nf][qq] + bs;
                        tile[rrow][col] = v > 0.f ? v : 0.1f * v;
                    }
                }
        }
        __syncthreads();
        const int mrow = m0 + mb + half * 64;
        const int b = mrow >> 12, n0 = mrow & (NPT - 1);
        for (int e = tid; e < 64 * MIDD; e += 256) {
            const int o = e >> 6, i = e & 63;
            out_t[((size_t)b * MIDD + o) * NPT + n0 + i] = tile[i][o];
        }
        if (out_pm) {
            for (int e = tid; e < 64 * MIDD; e += 256) {
                const int i = e >> 7, o = e & 127;
                const float v = tile[i][o];
                out_pm [(size_t)(mrow + i) * MIDD + o] = v;
                out_pmb[(size_t)(mrow + i) * MIDD + o] = __float2bfloat16(v);
            }
        }
    }
}

// ---------------------------------------------------------------------------
extern "C" void kernel_launch(void* const* d_in, const int* in_sizes, int n_in,
                              void* d_out, int out_size, void* d_ws, size_t ws_size,
                              hipStream_t stream)
{
    (void)in_sizes; (void)n_in; (void)out_size;
    const float* pc1    = (const float*)d_in[0];
    const float* pc2    = (const float*)d_in[1];
    const float* feat1  = (const float*)d_in[2];
    const float* feat2  = (const float*)d_in[3];
    const float* wn1_w0 = (const float*)d_in[4];
    const float* wn1_b0 = (const float*)d_in[5];
    const float* wn1_w1 = (const float*)d_in[6];
    const float* wn1_b1 = (const float*)d_in[7];
    const float* wn1_w2 = (const float*)d_in[8];
    const float* wn1_b2 = (const float*)d_in[9];
    const float* lin1_w = (const float*)d_in[10];
    const float* lin1_b = (const float*)d_in[11];
    const float* wn2_w0 = (const float*)d_in[12];
    const float* wn2_b0 = (const float*)d_in[13];
    const float* wn2_w1 = (const float*)d_in[14];
    const float* wn2_b1 = (const float*)d_in[15];
    const float* wn2_w2 = (const float*)d_in[16];
    const float* wn2_b2 = (const float*)d_in[17];
    const float* lin2_w = (const float*)d_in[18];
    const float* lin2_b = (const float*)d_in[19];
    float* out = (float*)d_out;

    const int M  = BB * NPT;
    const int M2 = 2 * M;
    const int K1 = 2 * CDIM * WD;     // 2048
    const int K2 = 2 * MIDD * WD;     // 4096

    char* ws = (char*)d_ws;
    float* p1pm = (float*)ws;                          // [M][64] f32
    float* p2pm = p1pm + (size_t)M * CDIM;             // [M][64] f32
    float* fpm  = p2pm + (size_t)M * CDIM;             // [2M][128] f32 (f1|f2)
    bf16*  p1b  = (bf16*)(fpm + (size_t)M2 * MIDD);    // [M][64] bf16
    bf16*  p2b  = p1b + (size_t)M * CDIM;              // [M][64] bf16
    bf16*  fb   = p2b + (size_t)M * CDIM;              // [2M][128] bf16
    int* idx12  = (int*)(fb + (size_t)M2 * MIDD);
    int* idx21  = idx12 + (size_t)M * NBR;
    bf16* b1hi  = (bf16*)(idx21 + (size_t)M * NBR);
    bf16* b1lo  = b1hi + (size_t)MIDD * K1;
    bf16* b2hi  = b1lo + (size_t)MIDD * K1;
    bf16* b2lo  = b2hi + (size_t)MIDD * K2;
    bf16* aggbuf = b2lo + (size_t)MIDD * K2;
    const size_t used = (size_t)((char*)aggbuf - ws);
    const size_t avail = ws_size > used ? ws_size - used : 0;

    float* f1t = out;
    float* fft = out + 2 * (size_t)BB * MIDD * NPT;

    transpose_kernel<<<dim3(NPT / 32, CDIM / 32, BB), dim3(32, 8), 0, stream>>>(feat1, p1pm, p1b, CDIM);
    transpose_kernel<<<dim3(NPT / 32, CDIM / 32, BB), dim3(32, 8), 0, stream>>>(feat2, p2pm, p2b, CDIM);
    split_w_kernel<<<dim3(K1 / 32, MIDD / 32), dim3(32, 8), 0, stream>>>(lin1_w, b1hi, b1lo, K1);
    split_w_kernel<<<dim3(K2 / 32, MIDD / 32), dim3(32, 8), 0, stream>>>(lin2_w, b2hi, b2lo, K2);
    knn_kernel<<<dim3(NPT / KQ, BB, 2), 256, 0, stream>>>(pc1, pc2, idx12, idx21);

    auto chunk_rows = [&](int K) -> int {
        long rows = (long)(avail / ((size_t)K * sizeof(bf16)));
        int cm = (int)(rows > M2 ? M2 : rows) & ~127;
        if (cm < 128) cm = 128;
        return cm;
    };

    {   // cross 1 + cross 2 merged (K = 2048)
        const int CMr = chunk_rows(K1);
        for (int m0 = 0; m0 < M2; m0 += CMr) {
            const int cm = (M2 - m0 < CMr) ? (M2 - m0) : CMr;
            int done = 0;
            if (m0 < M) {
                const int c1 = (cm < M - m0) ? cm : (M - m0);
                agg_kernel<CDIM, 8><<<c1 / 8, 256, 0, stream>>>(
                    pc1, pc2, p1pm, p2b, idx12,
                    wn1_w0, wn1_b0, wn1_w1, wn1_b1, wn1_w2, wn1_b2, aggbuf, m0);
                done = c1;
            }
            if (m0 + cm > M) {
                const int start2 = (m0 > M) ? m0 : M;
                const int c2 = m0 + cm - start2;
                agg_kernel<CDIM, 8><<<c2 / 8, 256, 0, stream>>>(
                    pc2, pc1, p2pm, p1b, idx21,
                    wn1_w0, wn1_b0, wn1_w1, wn1_b1, wn1_w2, wn1_b2,
                    aggbuf + (size_t)done * K1, start2 - M);
            }
            gemm_mfma<<<cm / 128, 256, 0, stream>>>(aggbuf, b1hi, b1lo, lin1_b,
                                                    f1t, fpm, fb, m0, K1);
        }
    }
    {   // cross 3 (K = 4096): own = f1 (fp32), neighbors = f2 (bf16)
        const int CMr = chunk_rows(K2);
        for (int m0 = 0; m0 < M; m0 += CMr) {
            const int cm = (M - m0 < CMr) ? (M - m0) : CMr;
            agg_kernel<MIDD, 4><<<cm / 4, 256, 0, stream>>>(
                pc1, pc2, fpm, fb + (size_t)M * MIDD, idx12,
                wn2_w0, wn2_b0, wn2_w1, wn2_b1, wn2_w2, wn2_b2, aggbuf, m0);
            gemm_mfma<<<cm / 128, 256, 0, stream>>>(aggbuf, b2hi, b2lo, lin2_b,
                                                    fft, nullptr, nullptr, m0, K2);
        }
    }
}

// Round 7
// 450.153 us; speedup vs baseline: 4.8452x; 1.0164x over previous
//
#include <hip/hip_runtime.h>
#include <hip/hip_bf16.h>
#include <cstddef>
#include <cstdint>

typedef __hip_bfloat16 bf16;
typedef __attribute__((ext_vector_type(8))) short bf16x8;   // 8 bf16 = 4 VGPRs
typedef __attribute__((ext_vector_type(4))) float f32x4;

#define NPT 4096   // points per cloud
#define BB  4      // batch
#define NBR 16     // neighbors (nsample)
#define WD  16     // weightnet output width
#define CDIM 64    // input feature channels
#define MIDD 128   // lin1/lin2 output channels

// async global->LDS, 16B per lane; LDS dest is wave-uniform base + lane*16
#define GLD16(g, l) __builtin_amdgcn_global_load_lds( \
    (const __attribute__((address_space(1))) unsigned int*)(const void*)(g), \
    (__attribute__((address_space(3))) unsigned int*)(void*)(l), 16, 0, 0)

// ---------------------------------------------------------------------------
// Fused prep: both feature transposes (fp32+bf16 copies) and both lin-weight
// hi/lo splits, partitioned by blockIdx.x. Same tile bodies as before.
//   id in [0,2048)     : transpose feat1/feat2 tiles
//   id in [2048,2304)  : split lin1 (K=2048)
//   id in [2304,2816)  : split lin2 (K=4096)
// ---------------------------------------------------------------------------
__global__ __launch_bounds__(256)
void prep_kernel(const float* __restrict__ feat1, const float* __restrict__ feat2,
                 float* __restrict__ p1pm, bf16* __restrict__ p1b,
                 float* __restrict__ p2pm, bf16* __restrict__ p2b,
                 const float* __restrict__ lin1_w, bf16* __restrict__ b1hi, bf16* __restrict__ b1lo,
                 const float* __restrict__ lin2_w, bf16* __restrict__ b2hi, bf16* __restrict__ b2lo)
{
    __shared__ float t[32][33];
    const int tx = threadIdx.x & 31, ty = threadIdx.x >> 5;
    const int id = blockIdx.x;
    if (id < 2048) {
        const int which = id >> 10;
        const int nt = id & 1023;
        const int n0 = (nt & 127) * 32;
        const int c0 = ((nt >> 7) & 1) * 32;
        const int b  = nt >> 8;
        const float* in = which ? feat2 : feat1;
        float* out  = which ? p2pm : p1pm;
        bf16*  outb = which ? p2b  : p1b;
        #pragma unroll
        for (int r = ty; r < 32; r += 8)
            t[r][tx] = in[((size_t)b * CDIM + c0 + r) * NPT + n0 + tx];
        __syncthreads();
        #pragma unroll
        for (int r = ty; r < 32; r += 8) {
            const float v = t[tx][r];
            out [((size_t)b * NPT + n0 + r) * CDIM + c0 + tx] = v;
            outb[((size_t)b * NPT + n0 + r) * CDIM + c0 + tx] = __float2bfloat16(v);
        }
    } else {
        const float* w; bf16 *hi, *lo; int K, k0, o0;
        if (id < 2304) {
            const int id2 = id - 2048;
            w = lin1_w; hi = b1hi; lo = b1lo; K = 2048;
            k0 = (id2 & 63) * 32; o0 = (id2 >> 6) * 32;
        } else {
            const int id2 = id - 2304;
            w = lin2_w; hi = b2hi; lo = b2lo; K = 4096;
            k0 = (id2 & 127) * 32; o0 = (id2 >> 7) * 32;
        }
        #pragma unroll
        for (int r = ty; r < 32; r += 8)
            t[r][tx] = w[(size_t)(k0 + r) * MIDD + o0 + tx];
        __syncthreads();
        #pragma unroll
        for (int r = ty; r < 32; r += 8) {
            const float v = t[tx][r];
            const bf16 h = __float2bfloat16(v);
            const bf16 l2 = __float2bfloat16(v - __bfloat162float(h));
            hi[(size_t)(o0 + r) * K + k0 + tx] = h;
            lo[(size_t)(o0 + r) * K + k0 + tx] = l2;
        }
    }
}

// ---------------------------------------------------------------------------
// KNN v4: two-pass threshold selection. Pass 1 staged through LDS (as v3).
// Pass 2 reads candidates DIRECTLY from global (float4 on each coordinate
// stream, L2-resident, 16-lane broadcast) — no restaging, no pass-2 barriers.
// The distance expression is the literal same fmaf chain in both passes, so
// survivor sets (and therefore outputs) are bit-identical to rounds 4-6.
// ---------------------------------------------------------------------------
#define KQ     16
#define KSEG   16
#define KCH    64
#define KSTAGE 1024
#define KRING  96

__global__ __launch_bounds__(256)
void knn_kernel(const float* __restrict__ pcA, const float* __restrict__ pcB,
                int* __restrict__ idxAB, int* __restrict__ idxBA)
{
    const float *qxyz, *cxyz; int* idx_out;
    if (blockIdx.z == 0) { qxyz = pcA; cxyz = pcB; idx_out = idxAB; }
    else                 { qxyz = pcB; cxyz = pcA; idx_out = idxBA; }

    __shared__ float4 cf[KSTAGE];
    __shared__ float  pubd[2][KSEG][KQ];
    __shared__ float  u16s[KQ];
    __shared__ int    rcnt[KQ];
    __shared__ float  ringd[KQ][KRING + 1];
    __shared__ int    ringi[KQ][KRING + 1];

    const int tid = threadIdx.x;
    const int q   = tid & (KQ - 1);
    const int s   = tid >> 4;
    const int b   = blockIdx.y;
    const int n   = blockIdx.x * KQ + q;

    const float* qp = qxyz + (size_t)b * 3 * NPT;
    const float qx = qp[n], qy = qp[NPT + n], qz = qp[2 * NPT + n];
    const float q2 = fmaf(qx, qx, fmaf(qy, qy, qz * qz));
    const float* c = cxyz + (size_t)b * 3 * NPT;

    if (tid < KQ) rcnt[tid] = 0;

    // ---- pass 1: two smallest distance values per (q,s), LDS-staged ----
    float b0 = 3.4e38f, b1 = 3.4e38f;
    for (int st = 0; st < NPT; st += KSTAGE) {
        __syncthreads();
        for (int j = tid; j < KSTAGE; j += 256) {
            const int g = st + j;
            const float x = c[g], y = c[NPT + g], z = c[2 * NPT + g];
            cf[j] = make_float4(x, y, z, fmaf(x, x, fmaf(y, y, z * z)));
        }
        __syncthreads();
        const int base = s * KCH;
        #pragma unroll 4
        for (int jj = 0; jj < KCH; ++jj) {
            const float4 pv = cf[base + jj];
            const float dot = fmaf(qx, pv.x, fmaf(qy, pv.y, qz * pv.z));
            const float d = q2 + pv.w - 2.f * dot;
            const float t = fmaxf(b0, d);
            b0 = fminf(b0, d);
            b1 = fminf(b1, t);
        }
    }
    pubd[0][s][q] = b0;
    pubd[1][s][q] = b1;
    __syncthreads();

    // ---- u16: 16th smallest of 32 published values (rank == 15) ----
    {
        float tv[32];
        #pragma unroll
        for (int j = 0; j < 32; ++j) tv[j] = pubd[j >> 4][j & 15][q];
        #pragma unroll
        for (int rep = 0; rep < 2; ++rep) {
            const int j = rep * 16 + s;
            const float vj = pubd[rep][s][q];
            int rank = 0;
            #pragma unroll
            for (int k = 0; k < 32; ++k)
                rank += (tv[k] < vj || (tv[k] == vj && k < j)) ? 1 : 0;
            if (rank == 15) u16s[q] = vj;
        }
    }
    __syncthreads();
    const float ugate = u16s[q];

    // ---- pass 2: direct global reads, collect d <= ugate into ring ----
    for (int ch = 0; ch < 4; ++ch) {
        const int base = ch * KSTAGE + s * KCH;
        #pragma unroll 2
        for (int jj = 0; jj < KCH; jj += 4) {
            const int j = base + jj;
            const float4 xs = *(const float4*)(c + j);
            const float4 ys = *(const float4*)(c + NPT + j);
            const float4 zs = *(const float4*)(c + 2 * NPT + j);
            const float xv[4] = { xs.x, xs.y, xs.z, xs.w };
            const float yv[4] = { ys.x, ys.y, ys.z, ys.w };
            const float zv[4] = { zs.x, zs.y, zs.z, zs.w };
            #pragma unroll
            for (int e = 0; e < 4; ++e) {
                const float p2 = fmaf(xv[e], xv[e], fmaf(yv[e], yv[e], zv[e] * zv[e]));
                const float dot = fmaf(qx, xv[e], fmaf(qy, yv[e], qz * zv[e]));
                const float d = q2 + p2 - 2.f * dot;
                if (d <= ugate) {
                    const int slot = atomicAdd(&rcnt[q], 1);
                    if (slot < KRING) { ringd[q][slot] = d; ringi[q][slot] = j + e; }
                }
            }
        }
    }
    __syncthreads();

    // ---- final: exact (d, idx) rank-select of top-16 from the ring ----
    {
        const int cnt = min(rcnt[q], KRING);
        int* op = idx_out + ((size_t)b * NPT + n) * NBR;
        for (int e = s; e < cnt; e += KSEG) {
            const float de = ringd[q][e];
            const int   ie = ringi[q][e];
            int rank = 0;
            for (int k = 0; k < cnt; ++k) {
                const float dk = ringd[q][k];
                const int   ik = ringi[q][k];
                rank += (dk < de || (dk == de && ik < ie)) ? 1 : 0;
            }
            if (rank < NBR) op[rank] = ie;
        }
    }
}

// ---------------------------------------------------------------------------
// Weightnet + aggregation v3 (unchanged from round 6).
// ---------------------------------------------------------------------------
template<int D2, int PTS>
__global__ __launch_bounds__(256)
void agg_kernel(const float* __restrict__ qxyz, const float* __restrict__ cxyz,
                const float* __restrict__ own_pm, const bf16* __restrict__ nbr_b,
                const int* __restrict__ idx,
                const float* __restrict__ w0, const float* __restrict__ b0,
                const float* __restrict__ w1, const float* __restrict__ b1,
                const float* __restrict__ w2, const float* __restrict__ b2,
                bf16* __restrict__ agg, int m0)
{
    constexpr int TPP   = 256 / PTS;
    constexpr int HALF  = TPP / 2;
    constexpr int WSTR  = 276;

    __shared__ float wp[248];
    __shared__ int   nb[PTS * NBR];
    __shared__ float wgt[PTS * WSTR];

    const int tid = threadIdx.x;
    const int mbase = m0 + (int)blockIdx.x * PTS;
    const int b = mbase >> 12;
    const int nbase = mbase & (NPT - 1);

    if (tid < 248) {
        float v;
        if      (tid <  24) v = w0[tid];
        else if (tid <  32) v = b0[tid - 24];
        else if (tid <  96) v = w1[tid - 32];
        else if (tid < 104) v = b1[tid - 96];
        else if (tid < 232) v = w2[tid - 104];
        else                v = b2[tid - 232];
        wp[tid] = v;
    }
    if (tid < PTS * NBR)
        nb[tid] = idx[(size_t)mbase * NBR + tid];
    __syncthreads();

    const int p  = tid & (PTS - 1);
    const int dg = tid / PTS;

    uint2  F[NBR];
    float4 ow;
    if (dg >= HALF) {
        const int d0 = (dg - HALF) * 4;
        const bf16* base = nbr_b + (size_t)b * NPT * D2 + d0;
        #pragma unroll
        for (int k = 0; k < NBR; ++k) {
            const int j = nb[p * NBR + k];
            F[k] = *(const uint2*)(base + (size_t)j * D2);
        }
    } else {
        ow = *(const float4*)(own_pm + ((size_t)mbase + p) * D2 + dg * 4);
    }

    if (tid < PTS * NBR) {
        const int pp = tid / NBR, k = tid % NBR;
        const int n = nbase + pp;
        const int j = nb[tid];
        const float* q = qxyz + (size_t)b * 3 * NPT;
        const float* c = cxyz + (size_t)b * 3 * NPT;
        const float dx = c[j]           - q[n];
        const float dy = c[NPT + j]     - q[NPT + n];
        const float dz = c[2 * NPT + j] - q[2 * NPT + n];
        float h1[8], h2[8];
        #pragma unroll
        for (int o = 0; o < 8; ++o) {
            float v = wp[24 + o];
            v = fmaf(dx, wp[o], v);
            v = fmaf(dy, wp[8 + o], v);
            v = fmaf(dz, wp[16 + o], v);
            h1[o] = fmaxf(v, 0.f);
        }
        #pragma unroll
        for (int o = 0; o < 8; ++o) {
            float v = wp[96 + o];
            #pragma unroll
            for (int i = 0; i < 8; ++i) v = fmaf(h1[i], wp[32 + i * 8 + o], v);
            h2[o] = fmaxf(v, 0.f);
        }
        #pragma unroll
        for (int o = 0; o < WD; ++o) {
            float v = wp[232 + o];
            #pragma unroll
            for (int i = 0; i < 8; ++i) v = fmaf(h2[i], wp[104 + i * WD + o], v);
            wgt[pp * WSTR + k * WD + o] = fmaxf(v, 0.f);
        }
    }
    __syncthreads();

    const float* wg = wgt + p * WSTR;
    bf16* aout = agg + ((size_t)((int)blockIdx.x * PTS + p)) * (2 * D2 * WD);

    if (dg < HALF) {
        const int d0 = dg * 4;
        float sw[16];
        #pragma unroll
        for (int w = 0; w < 16; ++w) sw[w] = 0.f;
        #pragma unroll
        for (int k = 0; k < NBR; ++k) {
            const float4 v0 = *(const float4*)(wg + k * WD);
            const float4 v1 = *(const float4*)(wg + k * WD + 4);
            const float4 v2 = *(const float4*)(wg + k * WD + 8);
            const float4 v3 = *(const float4*)(wg + k * WD + 12);
            sw[0]  += v0.x; sw[1]  += v0.y; sw[2]  += v0.z; sw[3]  += v0.w;
            sw[4]  += v1.x; sw[5]  += v1.y; sw[6]  += v1.z; sw[7]  += v1.w;
            sw[8]  += v2.x; sw[9]  += v2.y; sw[10] += v2.z; sw[11] += v2.w;
            sw[12] += v3.x; sw[13] += v3.y; sw[14] += v3.z; sw[15] += v3.w;
        }
        const float od[4] = { ow.x, ow.y, ow.z, ow.w };
        #pragma unroll
        for (int di = 0; di < 4; ++di) {
            const float f = od[di];
            union { bf16 h[16]; uint4 q[2]; } pk;
            #pragma unroll
            for (int w = 0; w < 16; ++w) pk.h[w] = __float2bfloat16(f * sw[w]);
            bf16* dst = aout + (d0 + di) * WD;
            *(uint4*)dst       = pk.q[0];
            *(uint4*)(dst + 8) = pk.q[1];
        }
    } else {
        const int d0 = (dg - HALF) * 4;
        float acc[4][16];
        #pragma unroll
        for (int di = 0; di < 4; ++di)
            #pragma unroll
            for (int w = 0; w < 16; ++w) acc[di][w] = 0.f;
        #pragma unroll
        for (int k = 0; k < NBR; ++k) {
            union { uint2 u; bf16 h[4]; } uf;
            uf.u = F[k];
            float Fv[4];
            #pragma unroll
            for (int j = 0; j < 4; ++j) Fv[j] = __bfloat162float(uf.h[j]);
            const float4 v0 = *(const float4*)(wg + k * WD);
            const float4 v1 = *(const float4*)(wg + k * WD + 4);
            const float4 v2 = *(const float4*)(wg + k * WD + 8);
            const float4 v3 = *(const float4*)(wg + k * WD + 12);
            float w16[16];
            w16[0]  = v0.x; w16[1]  = v0.y; w16[2]  = v0.z; w16[3]  = v0.w;
            w16[4]  = v1.x; w16[5]  = v1.y; w16[6]  = v1.z; w16[7]  = v1.w;
            w16[8]  = v2.x; w16[9]  = v2.y; w16[10] = v2.z; w16[11] = v2.w;
            w16[12] = v3.x; w16[13] = v3.y; w16[14] = v3.z; w16[15] = v3.w;
            #pragma unroll
            for (int di = 0; di < 4; ++di)
                #pragma unroll
                for (int w = 0; w < 16; ++w)
                    acc[di][w] = fmaf(Fv[di], w16[w], acc[di][w]);
        }
        #pragma unroll
        for (int di = 0; di < 4; ++di) {
            union { bf16 h[16]; uint4 q[2]; } pk;
            #pragma unroll
            for (int w = 0; w < 16; ++w) pk.h[w] = __float2bfloat16(acc[di][w]);
            bf16* dst = aout + (D2 + d0 + di) * WD;
            *(uint4*)dst       = pk.q[0];
            *(uint4*)(dst + 8) = pk.q[1];
        }
    }
}

// ---------------------------------------------------------------------------
// MFMA GEMM v2: BM=64 tile (grid 2x denser -> all CUs busy on cross 3).
// Block 64x128, BK=32, 4 waves (2x2, wave tile 32x64), fp32 acc, hi+lo B.
// 40KB LDS double buffer; same chunk-XOR swizzle (matched involution).
// ---------------------------------------------------------------------------
__global__ __launch_bounds__(256)
void gemm_mfma(const bf16* __restrict__ A, const bf16* __restrict__ Bhi,
               const bf16* __restrict__ Blo, const float* __restrict__ bias,
               float* __restrict__ out_t, float* __restrict__ out_pm,
               bf16* __restrict__ out_pmb, int m0, int K)
{
    __shared__ __align__(16) char smem[40960];   // 2 x (A 4KB + Bhi 8KB + Blo 8KB)
    bf16* lds = (bf16*)smem;

    const int tid  = threadIdx.x;
    const int w    = tid >> 6;
    const int lane = tid & 63;
    const int wr   = w >> 1, wc = w & 1;
    const int mb   = (int)blockIdx.x * 64;
    const int gK   = lane >> 4;
    const int rL   = lane & 15;

    f32x4 acc[2][4];
    #pragma unroll
    for (int i = 0; i < 2; ++i)
        #pragma unroll
        for (int j = 0; j < 4; ++j) acc[i][j] = (f32x4)0.f;

    auto stage = [&](int buf, int kt) {
        const int kb = kt * 32;
        const int bufo = buf * 10240;
        {   // A tile 64x32: one round
            const int row = tid >> 2, ch = tid & 3;
            const int sch = ch ^ (row & 3);
            GLD16(A + (size_t)(mb + row) * K + kb + (sch << 3),
                  lds + bufo + ((w * 64) << 3));
        }
        #pragma unroll
        for (int i = 0; i < 2; ++i) {   // Bhi / Blo tiles 128x32: two rounds each
            const int s2 = i * 256 + tid;
            const int row = s2 >> 2, ch = s2 & 3;
            const int sch = ch ^ (row & 3);
            const int wb = (i * 256 + w * 64) << 3;
            GLD16(Bhi + (size_t)row * K + kb + (sch << 3), lds + bufo + 2048 + wb);
            GLD16(Blo + (size_t)row * K + kb + (sch << 3), lds + bufo + 6144 + wb);
        }
    };

    stage(0, 0);
    __syncthreads();

    const int nk = K / 32;
    for (int kt = 0; kt < nk; ++kt) {
        const int cur = kt & 1;
        if (kt + 1 < nk) stage(cur ^ 1, kt + 1);

        const bf16* la  = lds + cur * 10240;
        const bf16* lbh = la + 2048;
        const bf16* lbl = la + 6144;

        bf16x8 af[2], bh[4], bl[4];
        #pragma unroll
        for (int mf = 0; mf < 2; ++mf) {
            const int row = wr * 32 + mf * 16 + rL;
            af[mf] = *(const bf16x8*)(la + row * 32 + ((gK ^ (row & 3)) << 3));
        }
        #pragma unroll
        for (int nf = 0; nf < 4; ++nf) {
            const int col = wc * 64 + nf * 16 + rL;
            const int off = col * 32 + ((gK ^ (col & 3)) << 3);
            bh[nf] = *(const bf16x8*)(lbh + off);
            bl[nf] = *(const bf16x8*)(lbl + off);
        }
        #pragma unroll
        for (int mf = 0; mf < 2; ++mf)
            #pragma unroll
            for (int nf = 0; nf < 4; ++nf) {
                acc[mf][nf] = __builtin_amdgcn_mfma_f32_16x16x32_bf16(af[mf], bh[nf], acc[mf][nf], 0, 0, 0);
                acc[mf][nf] = __builtin_amdgcn_mfma_f32_16x16x32_bf16(af[mf], bl[nf], acc[mf][nf], 0, 0, 0);
            }
        __syncthreads();
    }

    // epilogue: bias + leaky into 64x128 LDS tile (stride 133: conflict-free)
    float (*tile)[133] = (float(*)[133])smem;
    #pragma unroll
    for (int mf = 0; mf < 2; ++mf)
        #pragma unroll
        for (int nf = 0; nf < 4; ++nf) {
            const int col = wc * 64 + nf * 16 + rL;
            const float bs = bias[col];
            #pragma unroll
            for (int qq = 0; qq < 4; ++qq) {
                const int rrow = wr * 32 + mf * 16 + gK * 4 + qq;
                const float v = acc[mf][nf][qq] + bs;
                tile[rrow][col] = v > 0.f ? v : 0.1f * v;
            }
        }
    __syncthreads();

    const int mrow = m0 + mb;
    const int b = mrow >> 12, n0 = mrow & (NPT - 1);
    for (int e = tid; e < 64 * MIDD; e += 256) {
        const int o = e >> 6, i = e & 63;
        out_t[((size_t)b * MIDD + o) * NPT + n0 + i] = tile[i][o];
    }
    if (out_pm) {
        for (int e = tid; e < 64 * MIDD; e += 256) {
            const int i = e >> 7, o = e & 127;
            const float v = tile[i][o];
            out_pm [(size_t)(mrow + i) * MIDD + o] = v;
            out_pmb[(size_t)(mrow + i) * MIDD + o] = __float2bfloat16(v);
        }
    }
}

// ---------------------------------------------------------------------------
extern "C" void kernel_launch(void* const* d_in, const int* in_sizes, int n_in,
                              void* d_out, int out_size, void* d_ws, size_t ws_size,
                              hipStream_t stream)
{
    (void)in_sizes; (void)n_in; (void)out_size;
    const float* pc1    = (const float*)d_in[0];
    const float* pc2    = (const float*)d_in[1];
    const float* feat1  = (const float*)d_in[2];
    const float* feat2  = (const float*)d_in[3];
    const float* wn1_w0 = (const float*)d_in[4];
    const float* wn1_b0 = (const float*)d_in[5];
    const float* wn1_w1 = (const float*)d_in[6];
    const float* wn1_b1 = (const float*)d_in[7];
    const float* wn1_w2 = (const float*)d_in[8];
    const float* wn1_b2 = (const float*)d_in[9];
    const float* lin1_w = (const float*)d_in[10];
    const float* lin1_b = (const float*)d_in[11];
    const float* wn2_w0 = (const float*)d_in[12];
    const float* wn2_b0 = (const float*)d_in[13];
    const float* wn2_w1 = (const float*)d_in[14];
    const float* wn2_b1 = (const float*)d_in[15];
    const float* wn2_w2 = (const float*)d_in[16];
    const float* wn2_b2 = (const float*)d_in[17];
    const float* lin2_w = (const float*)d_in[18];
    const float* lin2_b = (const float*)d_in[19];
    float* out = (float*)d_out;

    const int M  = BB * NPT;
    const int M2 = 2 * M;
    const int K1 = 2 * CDIM * WD;     // 2048
    const int K2 = 2 * MIDD * WD;     // 4096

    char* ws = (char*)d_ws;
    float* p1pm = (float*)ws;                          // [M][64] f32
    float* p2pm = p1pm + (size_t)M * CDIM;             // [M][64] f32
    float* fpm  = p2pm + (size_t)M * CDIM;             // [2M][128] f32 (f1|f2)
    bf16*  p1b  = (bf16*)(fpm + (size_t)M2 * MIDD);    // [M][64] bf16
    bf16*  p2b  = p1b + (size_t)M * CDIM;              // [M][64] bf16
    bf16*  fb   = p2b + (size_t)M * CDIM;              // [2M][128] bf16
    int* idx12  = (int*)(fb + (size_t)M2 * MIDD);
    int* idx21  = idx12 + (size_t)M * NBR;
    bf16* b1hi  = (bf16*)(idx21 + (size_t)M * NBR);
    bf16* b1lo  = b1hi + (size_t)MIDD * K1;
    bf16* b2hi  = b1lo + (size_t)MIDD * K1;
    bf16* b2lo  = b2hi + (size_t)MIDD * K2;
    bf16* aggbuf = b2lo + (size_t)MIDD * K2;
    const size_t used = (size_t)((char*)aggbuf - ws);
    const size_t avail = ws_size > used ? ws_size - used : 0;

    float* f1t = out;
    float* fft = out + 2 * (size_t)BB * MIDD * NPT;

    prep_kernel<<<2816, 256, 0, stream>>>(feat1, feat2, p1pm, p1b, p2pm, p2b,
                                          lin1_w, b1hi, b1lo, lin2_w, b2hi, b2lo);
    knn_kernel<<<dim3(NPT / KQ, BB, 2), 256, 0, stream>>>(pc1, pc2, idx12, idx21);

    auto chunk_rows = [&](int K) -> int {
        long rows = (long)(avail / ((size_t)K * sizeof(bf16)));
        int cm = (int)(rows > M2 ? M2 : rows) & ~127;
        if (cm < 128) cm = 128;
        return cm;
    };

    {   // cross 1 + cross 2 merged (K = 2048)
        const int CMr = chunk_rows(K1);
        for (int m0 = 0; m0 < M2; m0 += CMr) {
            const int cm = (M2 - m0 < CMr) ? (M2 - m0) : CMr;
            int done = 0;
            if (m0 < M) {
                const int c1 = (cm < M - m0) ? cm : (M - m0);
                agg_kernel<CDIM, 8><<<c1 / 8, 256, 0, stream>>>(
                    pc1, pc2, p1pm, p2b, idx12,
                    wn1_w0, wn1_b0, wn1_w1, wn1_b1, wn1_w2, wn1_b2, aggbuf, m0);
                done = c1;
            }
            if (m0 + cm > M) {
                const int start2 = (m0 > M) ? m0 : M;
                const int c2 = m0 + cm - start2;
                agg_kernel<CDIM, 8><<<c2 / 8, 256, 0, stream>>>(
                    pc2, pc1, p2pm, p1b, idx21,
                    wn1_w0, wn1_b0, wn1_w1, wn1_b1, wn1_w2, wn1_b2,
                    aggbuf + (size_t)done * K1, start2 - M);
            }
            gemm_mfma<<<cm / 64, 256, 0, stream>>>(aggbuf, b1hi, b1lo, lin1_b,
                                                   f1t, fpm, fb, m0, K1);
        }
    }
    {   // cross 3 (K = 4096): own = f1 (fp32), neighbors = f2 (bf16)
        const int CMr = chunk_rows(K2);
        for (int m0 = 0; m0 < M; m0 += CMr) {
            const int cm = (M - m0 < CMr) ? (M - m0) : CMr;
            agg_kernel<MIDD, 4><<<cm / 4, 256, 0, stream>>>(
                pc1, pc2, fpm, fb + (size_t)M * MIDD, idx12,
                wn2_w0, wn2_b0, wn2_w1, wn2_b1, wn2_w2, wn2_b2, aggbuf, m0);
            gemm_mfma<<<cm / 64, 256, 0, stream>>>(aggbuf, b2hi, b2lo, lin2_b,
                                                   fft, nullptr, nullptr, m0, K2);
        }
    }
}

// Round 8
// 435.607 us; speedup vs baseline: 5.0070x; 1.0334x over previous
//
#include <hip/hip_runtime.h>
#include <hip/hip_bf16.h>
#include <cstddef>
#include <cstdint>

typedef __hip_bfloat16 bf16;
typedef __attribute__((ext_vector_type(8))) short bf16x8;   // 8 bf16 = 4 VGPRs
typedef __attribute__((ext_vector_type(4))) float f32x4;

#define NPT 4096   // points per cloud
#define BB  4      // batch
#define NBR 16     // neighbors (nsample)
#define WD  16     // weightnet output width
#define CDIM 64    // input feature channels
#define MIDD 128   // lin1/lin2 output channels

// async global->LDS, 16B per lane; LDS dest is wave-uniform base + lane*16
#define GLD16(g, l) __builtin_amdgcn_global_load_lds( \
    (const __attribute__((address_space(1))) unsigned int*)(const void*)(g), \
    (__attribute__((address_space(3))) unsigned int*)(void*)(l), 16, 0, 0)

// ---------------------------------------------------------------------------
// Fused prep: feature transposes (fp32+bf16) + lin-weight hi/lo splits.
// ---------------------------------------------------------------------------
__global__ __launch_bounds__(256)
void prep_kernel(const float* __restrict__ feat1, const float* __restrict__ feat2,
                 float* __restrict__ p1pm, bf16* __restrict__ p1b,
                 float* __restrict__ p2pm, bf16* __restrict__ p2b,
                 const float* __restrict__ lin1_w, bf16* __restrict__ b1hi, bf16* __restrict__ b1lo,
                 const float* __restrict__ lin2_w, bf16* __restrict__ b2hi, bf16* __restrict__ b2lo)
{
    __shared__ float t[32][33];
    const int tx = threadIdx.x & 31, ty = threadIdx.x >> 5;
    const int id = blockIdx.x;
    if (id < 2048) {
        const int which = id >> 10;
        const int nt = id & 1023;
        const int n0 = (nt & 127) * 32;
        const int c0 = ((nt >> 7) & 1) * 32;
        const int b  = nt >> 8;
        const float* in = which ? feat2 : feat1;
        float* out  = which ? p2pm : p1pm;
        bf16*  outb = which ? p2b  : p1b;
        #pragma unroll
        for (int r = ty; r < 32; r += 8)
            t[r][tx] = in[((size_t)b * CDIM + c0 + r) * NPT + n0 + tx];
        __syncthreads();
        #pragma unroll
        for (int r = ty; r < 32; r += 8) {
            const float v = t[tx][r];
            out [((size_t)b * NPT + n0 + r) * CDIM + c0 + tx] = v;
            outb[((size_t)b * NPT + n0 + r) * CDIM + c0 + tx] = __float2bfloat16(v);
        }
    } else {
        const float* w; bf16 *hi, *lo; int K, k0, o0;
        if (id < 2304) {
            const int id2 = id - 2048;
            w = lin1_w; hi = b1hi; lo = b1lo; K = 2048;
            k0 = (id2 & 63) * 32; o0 = (id2 >> 6) * 32;
        } else {
            const int id2 = id - 2304;
            w = lin2_w; hi = b2hi; lo = b2lo; K = 4096;
            k0 = (id2 & 127) * 32; o0 = (id2 >> 7) * 32;
        }
        #pragma unroll
        for (int r = ty; r < 32; r += 8)
            t[r][tx] = w[(size_t)(k0 + r) * MIDD + o0 + tx];
        __syncthreads();
        #pragma unroll
        for (int r = ty; r < 32; r += 8) {
            const float v = t[tx][r];
            const bf16 h = __float2bfloat16(v);
            const bf16 l2 = __float2bfloat16(v - __bfloat162float(h));
            hi[(size_t)(o0 + r) * K + k0 + tx] = h;
            lo[(size_t)(o0 + r) * K + k0 + tx] = l2;
        }
    }
}

// ---------------------------------------------------------------------------
// KNN v5: two-pass threshold selection with segment skipping.
//  - cf[] skewed (+1 float4 per 64) -> pass-1 reads conflict-free.
//  - pass 1: two smallest VALUES per (q,s) (same min/max/min chain as v4 ->
//    ugate bit-identical).
//  - classify: segment can contain a survivor iff its minimum b0 <= ugate.
//    Flagged (q,seg) pairs go to a block-wide worklist.
//  - pass 2: cooperative rescan of flagged segments only (16 units in
//    flight x 16 threads/unit, load-balanced across the block). Same fmaf
//    distance chain as v4 -> identical survivor set -> identical output.
// ---------------------------------------------------------------------------
#define KQ     16
#define KSEG   16
#define KCH    64
#define KSTAGE 1024
#define KRING  96

__global__ __launch_bounds__(256)
void knn_kernel(const float* __restrict__ pcA, const float* __restrict__ pcB,
                int* __restrict__ idxAB, int* __restrict__ idxBA)
{
    const float *qxyz, *cxyz; int* idx_out;
    if (blockIdx.z == 0) { qxyz = pcA; cxyz = pcB; idx_out = idxAB; }
    else                 { qxyz = pcB; cxyz = pcA; idx_out = idxBA; }

    __shared__ float4 cf[KSTAGE + KSTAGE / KCH];   // skewed
    __shared__ float  pubd[2][KSEG][KQ];
    __shared__ float4 qc[KQ];                      // qx,qy,qz,q2 per query
    __shared__ float  u16s[KQ];
    __shared__ int    rcnt[KQ];
    __shared__ int    wtot;
    __shared__ int    wl[256];                     // packed (q<<4)|seg
    __shared__ float  ringd[KQ][KRING + 1];
    __shared__ int    ringi[KQ][KRING + 1];

    const int tid = threadIdx.x;
    const int q   = tid & (KQ - 1);
    const int s   = tid >> 4;
    const int b   = blockIdx.y;
    const int n   = blockIdx.x * KQ + q;

    const float* qp = qxyz + (size_t)b * 3 * NPT;
    const float qx = qp[n], qy = qp[NPT + n], qz = qp[2 * NPT + n];
    const float q2 = fmaf(qx, qx, fmaf(qy, qy, qz * qz));
    const float* c = cxyz + (size_t)b * 3 * NPT;

    if (tid < KQ) rcnt[tid] = 0;
    if (tid == 0) wtot = 0;
    if (s == 0) qc[q] = make_float4(qx, qy, qz, q2);

    // ---- pass 1: two smallest distance values per (q,s) ----
    float b0 = 3.4e38f, b1 = 3.4e38f;
    for (int st = 0; st < NPT; st += KSTAGE) {
        __syncthreads();
        {   // vectorized staging: 4 candidates per thread
            const int j4 = tid * 4;
            const int g = st + j4;
            const float4 xs = *(const float4*)(c + g);
            const float4 ys = *(const float4*)(c + NPT + g);
            const float4 zs = *(const float4*)(c + 2 * NPT + g);
            const float xv[4] = { xs.x, xs.y, xs.z, xs.w };
            const float yv[4] = { ys.x, ys.y, ys.z, ys.w };
            const float zv[4] = { zs.x, zs.y, zs.z, zs.w };
            #pragma unroll
            for (int e = 0; e < 4; ++e) {
                const int j = j4 + e;
                cf[j + (j >> 6)] = make_float4(xv[e], yv[e], zv[e],
                    fmaf(xv[e], xv[e], fmaf(yv[e], yv[e], zv[e] * zv[e])));
            }
        }
        __syncthreads();
        const int base = s * (KCH + 1);   // skewed segment base
        #pragma unroll 4
        for (int jj = 0; jj < KCH; ++jj) {
            const float4 pv = cf[base + jj];
            const float dot = fmaf(qx, pv.x, fmaf(qy, pv.y, qz * pv.z));
            const float d = q2 + pv.w - 2.f * dot;
            const float t = fmaxf(b0, d);
            b0 = fminf(b0, d);
            b1 = fminf(b1, t);
        }
    }
    pubd[0][s][q] = b0;
    pubd[1][s][q] = b1;
    __syncthreads();

    // ---- u16: 16th smallest of 32 published values (rank == 15) ----
    {
        float tv[32];
        #pragma unroll
        for (int j = 0; j < 32; ++j) tv[j] = pubd[j >> 4][j & 15][q];
        #pragma unroll
        for (int rep = 0; rep < 2; ++rep) {
            const int j = rep * 16 + s;
            const float vj = pubd[rep][s][q];
            int rank = 0;
            #pragma unroll
            for (int k = 0; k < 32; ++k)
                rank += (tv[k] < vj || (tv[k] == vj && k < j)) ? 1 : 0;
            if (rank == 15) u16s[q] = vj;
        }
    }
    __syncthreads();

    // ---- classify: flag segments whose minimum can be <= gate ----
    if (b0 <= u16s[q]) {
        const int u = atomicAdd(&wtot, 1);
        wl[u] = (q << 4) | s;
    }
    __syncthreads();

    // ---- pass 2: cooperative rescan of flagged segments only ----
    {
        const int W = wtot;
        const int lu = tid & 15;                   // lane within unit
        for (int u = tid >> 4; u < W; u += 16) {
            const int qq  = wl[u] >> 4;
            const int seg = wl[u] & 15;
            const float4 qv = qc[qq];
            const float gate = u16s[qq];
            #pragma unroll
            for (int ch = 0; ch < 4; ++ch) {
                const int j = ch * KSTAGE + seg * KCH + lu * 4;
                const float4 xs = *(const float4*)(c + j);
                const float4 ys = *(const float4*)(c + NPT + j);
                const float4 zs = *(const float4*)(c + 2 * NPT + j);
                const float xv[4] = { xs.x, xs.y, xs.z, xs.w };
                const float yv[4] = { ys.x, ys.y, ys.z, ys.w };
                const float zv[4] = { zs.x, zs.y, zs.z, zs.w };
                #pragma unroll
                for (int e = 0; e < 4; ++e) {
                    const float p2 = fmaf(xv[e], xv[e], fmaf(yv[e], yv[e], zv[e] * zv[e]));
                    const float dot = fmaf(qv.x, xv[e], fmaf(qv.y, yv[e], qv.z * zv[e]));
                    const float d = qv.w + p2 - 2.f * dot;
                    if (d <= gate) {
                        const int slot = atomicAdd(&rcnt[qq], 1);
                        if (slot < KRING) { ringd[qq][slot] = d; ringi[qq][slot] = j + e; }
                    }
                }
            }
        }
    }
    __syncthreads();

    // ---- final: exact (d, idx) rank-select of top-16 from the ring ----
    {
        const int cnt = min(rcnt[q], KRING);
        int* op = idx_out + ((size_t)b * NPT + n) * NBR;
        for (int e = s; e < cnt; e += KSEG) {
            const float de = ringd[q][e];
            const int   ie = ringi[q][e];
            int rank = 0;
            for (int k = 0; k < cnt; ++k) {
                const float dk = ringd[q][k];
                const int   ik = ringi[q][k];
                rank += (dk < de || (dk == de && ik < ie)) ? 1 : 0;
            }
            if (rank < NBR) op[rank] = ie;
        }
    }
}

// ---------------------------------------------------------------------------
// Weightnet + aggregation v3 (round-6 body), merged: rows >= Msplit use the
// B-parameter set (cross 2). Blocks never straddle Msplit (M % PTS == 0).
// ---------------------------------------------------------------------------
template<int D2, int PTS>
__global__ __launch_bounds__(256)
void agg_kernel(const float* __restrict__ qA, const float* __restrict__ cA,
                const float* __restrict__ ownA, const bf16* __restrict__ nbrA,
                const int* __restrict__ idxA,
                const float* __restrict__ qB, const float* __restrict__ cB,
                const float* __restrict__ ownB, const bf16* __restrict__ nbrB,
                const int* __restrict__ idxB, int Msplit,
                const float* __restrict__ w0, const float* __restrict__ b0,
                const float* __restrict__ w1, const float* __restrict__ b1,
                const float* __restrict__ w2, const float* __restrict__ b2,
                bf16* __restrict__ agg, int m0)
{
    constexpr int TPP   = 256 / PTS;
    constexpr int HALF  = TPP / 2;
    constexpr int WSTR  = 276;

    __shared__ float wp[248];
    __shared__ int   nb[PTS * NBR];
    __shared__ float wgt[PTS * WSTR];

    const int tid = threadIdx.x;
    const int mbase = m0 + (int)blockIdx.x * PTS;
    const bool second = mbase >= Msplit;
    const int mrow = second ? mbase - Msplit : mbase;
    const float* qxyz   = second ? qB   : qA;
    const float* cxyz   = second ? cB   : cA;
    const float* own_pm = second ? ownB : ownA;
    const bf16*  nbr_b  = second ? nbrB : nbrA;
    const int*   idx    = second ? idxB : idxA;
    const int b = mrow >> 12;
    const int nbase = mrow & (NPT - 1);

    if (tid < 248) {
        float v;
        if      (tid <  24) v = w0[tid];
        else if (tid <  32) v = b0[tid - 24];
        else if (tid <  96) v = w1[tid - 32];
        else if (tid < 104) v = b1[tid - 96];
        else if (tid < 232) v = w2[tid - 104];
        else                v = b2[tid - 232];
        wp[tid] = v;
    }
    if (tid < PTS * NBR)
        nb[tid] = idx[(size_t)mrow * NBR + tid];
    __syncthreads();

    const int p  = tid & (PTS - 1);
    const int dg = tid / PTS;

    uint2  F[NBR];
    float4 ow;
    if (dg >= HALF) {
        const int d0 = (dg - HALF) * 4;
        const bf16* base = nbr_b + (size_t)b * NPT * D2 + d0;
        #pragma unroll
        for (int k = 0; k < NBR; ++k) {
            const int j = nb[p * NBR + k];
            F[k] = *(const uint2*)(base + (size_t)j * D2);
        }
    } else {
        ow = *(const float4*)(own_pm + ((size_t)mrow + p) * D2 + dg * 4);
    }

    if (tid < PTS * NBR) {
        const int pp = tid / NBR, k = tid % NBR;
        const int n = nbase + pp;
        const int j = nb[tid];
        const float* q = qxyz + (size_t)b * 3 * NPT;
        const float* c = cxyz + (size_t)b * 3 * NPT;
        const float dx = c[j]           - q[n];
        const float dy = c[NPT + j]     - q[NPT + n];
        const float dz = c[2 * NPT + j] - q[2 * NPT + n];
        float h1[8], h2[8];
        #pragma unroll
        for (int o = 0; o < 8; ++o) {
            float v = wp[24 + o];
            v = fmaf(dx, wp[o], v);
            v = fmaf(dy, wp[8 + o], v);
            v = fmaf(dz, wp[16 + o], v);
            h1[o] = fmaxf(v, 0.f);
        }
        #pragma unroll
        for (int o = 0; o < 8; ++o) {
            float v = wp[96 + o];
            #pragma unroll
            for (int i = 0; i < 8; ++i) v = fmaf(h1[i], wp[32 + i * 8 + o], v);
            h2[o] = fmaxf(v, 0.f);
        }
        #pragma unroll
        for (int o = 0; o < WD; ++o) {
            float v = wp[232 + o];
            #pragma unroll
            for (int i = 0; i < 8; ++i) v = fmaf(h2[i], wp[104 + i * WD + o], v);
            wgt[pp * WSTR + k * WD + o] = fmaxf(v, 0.f);
        }
    }
    __syncthreads();

    const float* wg = wgt + p * WSTR;
    bf16* aout = agg + ((size_t)((int)blockIdx.x * PTS + p)) * (2 * D2 * WD);

    if (dg < HALF) {
        const int d0 = dg * 4;
        float sw[16];
        #pragma unroll
        for (int w = 0; w < 16; ++w) sw[w] = 0.f;
        #pragma unroll
        for (int k = 0; k < NBR; ++k) {
            const float4 v0 = *(const float4*)(wg + k * WD);
            const float4 v1 = *(const float4*)(wg + k * WD + 4);
            const float4 v2 = *(const float4*)(wg + k * WD + 8);
            const float4 v3 = *(const float4*)(wg + k * WD + 12);
            sw[0]  += v0.x; sw[1]  += v0.y; sw[2]  += v0.z; sw[3]  += v0.w;
            sw[4]  += v1.x; sw[5]  += v1.y; sw[6]  += v1.z; sw[7]  += v1.w;
            sw[8]  += v2.x; sw[9]  += v2.y; sw[10] += v2.z; sw[11] += v2.w;
            sw[12] += v3.x; sw[13] += v3.y; sw[14] += v3.z; sw[15] += v3.w;
        }
        const float od[4] = { ow.x, ow.y, ow.z, ow.w };
        #pragma unroll
        for (int di = 0; di < 4; ++di) {
            const float f = od[di];
            union { bf16 h[16]; uint4 q[2]; } pk;
            #pragma unroll
            for (int w = 0; w < 16; ++w) pk.h[w] = __float2bfloat16(f * sw[w]);
            bf16* dst = aout + (d0 + di) * WD;
            *(uint4*)dst       = pk.q[0];
            *(uint4*)(dst + 8) = pk.q[1];
        }
    } else {
        const int d0 = (dg - HALF) * 4;
        float acc[4][16];
        #pragma unroll
        for (int di = 0; di < 4; ++di)
            #pragma unroll
            for (int w = 0; w < 16; ++w) acc[di][w] = 0.f;
        #pragma unroll
        for (int k = 0; k < NBR; ++k) {
            union { uint2 u; bf16 h[4]; } uf;
            uf.u = F[k];
            float Fv[4];
            #pragma unroll
            for (int j = 0; j < 4; ++j) Fv[j] = __bfloat162float(uf.h[j]);
            const float4 v0 = *(const float4*)(wg + k * WD);
            const float4 v1 = *(const float4*)(wg + k * WD + 4);
            const float4 v2 = *(const float4*)(wg + k * WD + 8);
            const float4 v3 = *(const float4*)(wg + k * WD + 12);
            float w16[16];
            w16[0]  = v0.x; w16[1]  = v0.y; w16[2]  = v0.z; w16[3]  = v0.w;
            w16[4]  = v1.x; w16[5]  = v1.y; w16[6]  = v1.z; w16[7]  = v1.w;
            w16[8]  = v2.x; w16[9]  = v2.y; w16[10] = v2.z; w16[11] = v2.w;
            w16[12] = v3.x; w16[13] = v3.y; w16[14] = v3.z; w16[15] = v3.w;
            #pragma unroll
            for (int di = 0; di < 4; ++di)
                #pragma unroll
                for (int w = 0; w < 16; ++w)
                    acc[di][w] = fmaf(Fv[di], w16[w], acc[di][w]);
        }
        #pragma unroll
        for (int di = 0; di < 4; ++di) {
            union { bf16 h[16]; uint4 q[2]; } pk;
            #pragma unroll
            for (int w = 0; w < 16; ++w) pk.h[w] = __float2bfloat16(acc[di][w]);
            bf16* dst = aout + (D2 + d0 + di) * WD;
            *(uint4*)dst       = pk.q[0];
            *(uint4*)(dst + 8) = pk.q[1];
        }
    }
}

// ---------------------------------------------------------------------------
// MFMA GEMM (round-7 BM=64 structure, unchanged).
// ---------------------------------------------------------------------------
__global__ __launch_bounds__(256)
void gemm_mfma(const bf16* __restrict__ A, const bf16* __restrict__ Bhi,
               const bf16* __restrict__ Blo, const float* __restrict__ bias,
               float* __restrict__ out_t, float* __restrict__ out_pm,
               bf16* __restrict__ out_pmb, int m0, int K)
{
    __shared__ __align__(16) char smem[40960];
    bf16* lds = (bf16*)smem;

    const int tid  = threadIdx.x;
    const int w    = tid >> 6;
    const int lane = tid & 63;
    const int wr   = w >> 1, wc = w & 1;
    const int mb   = (int)blockIdx.x * 64;
    const int gK   = lane >> 4;
    const int rL   = lane & 15;

    f32x4 acc[2][4];
    #pragma unroll
    for (int i = 0; i < 2; ++i)
        #pragma unroll
        for (int j = 0; j < 4; ++j) acc[i][j] = (f32x4)0.f;

    auto stage = [&](int buf, int kt) {
        const int kb = kt * 32;
        const int bufo = buf * 10240;
        {
            const int row = tid >> 2, ch = tid & 3;
            const int sch = ch ^ (row & 3);
            GLD16(A + (size_t)(mb + row) * K + kb + (sch << 3),
                  lds + bufo + ((w * 64) << 3));
        }
        #pragma unroll
        for (int i = 0; i < 2; ++i) {
            const int s2 = i * 256 + tid;
            const int row = s2 >> 2, ch = s2 & 3;
            const int sch = ch ^ (row & 3);
            const int wb = (i * 256 + w * 64) << 3;
            GLD16(Bhi + (size_t)row * K + kb + (sch << 3), lds + bufo + 2048 + wb);
            GLD16(Blo + (size_t)row * K + kb + (sch << 3), lds + bufo + 6144 + wb);
        }
    };

    stage(0, 0);
    __syncthreads();

    const int nk = K / 32;
    for (int kt = 0; kt < nk; ++kt) {
        const int cur = kt & 1;
        if (kt + 1 < nk) stage(cur ^ 1, kt + 1);

        const bf16* la  = lds + cur * 10240;
        const bf16* lbh = la + 2048;
        const bf16* lbl = la + 6144;

        bf16x8 af[2], bh[4], bl[4];
        #pragma unroll
        for (int mf = 0; mf < 2; ++mf) {
            const int row = wr * 32 + mf * 16 + rL;
            af[mf] = *(const bf16x8*)(la + row * 32 + ((gK ^ (row & 3)) << 3));
        }
        #pragma unroll
        for (int nf = 0; nf < 4; ++nf) {
            const int col = wc * 64 + nf * 16 + rL;
            const int off = col * 32 + ((gK ^ (col & 3)) << 3);
            bh[nf] = *(const bf16x8*)(lbh + off);
            bl[nf] = *(const bf16x8*)(lbl + off);
        }
        #pragma unroll
        for (int mf = 0; mf < 2; ++mf)
            #pragma unroll
            for (int nf = 0; nf < 4; ++nf) {
                acc[mf][nf] = __builtin_amdgcn_mfma_f32_16x16x32_bf16(af[mf], bh[nf], acc[mf][nf], 0, 0, 0);
                acc[mf][nf] = __builtin_amdgcn_mfma_f32_16x16x32_bf16(af[mf], bl[nf], acc[mf][nf], 0, 0, 0);
            }
        __syncthreads();
    }

    float (*tile)[133] = (float(*)[133])smem;
    #pragma unroll
    for (int mf = 0; mf < 2; ++mf)
        #pragma unroll
        for (int nf = 0; nf < 4; ++nf) {
            const int col = wc * 64 + nf * 16 + rL;
            const float bs = bias[col];
            #pragma unroll
            for (int qq = 0; qq < 4; ++qq) {
                const int rrow = wr * 32 + mf * 16 + gK * 4 + qq;
                const float v = acc[mf][nf][qq] + bs;
                tile[rrow][col] = v > 0.f ? v : 0.1f * v;
            }
        }
    __syncthreads();

    const int mrow = m0 + mb;
    const int b = mrow >> 12, n0 = mrow & (NPT - 1);
    for (int e = tid; e < 64 * MIDD; e += 256) {
        const int o = e >> 6, i = e & 63;
        out_t[((size_t)b * MIDD + o) * NPT + n0 + i] = tile[i][o];
    }
    if (out_pm) {
        for (int e = tid; e < 64 * MIDD; e += 256) {
            const int i = e >> 7, o = e & 127;
            const float v = tile[i][o];
            out_pm [(size_t)(mrow + i) * MIDD + o] = v;
            out_pmb[(size_t)(mrow + i) * MIDD + o] = __float2bfloat16(v);
        }
    }
}

// ---------------------------------------------------------------------------
extern "C" void kernel_launch(void* const* d_in, const int* in_sizes, int n_in,
                              void* d_out, int out_size, void* d_ws, size_t ws_size,
                              hipStream_t stream)
{
    (void)in_sizes; (void)n_in; (void)out_size;
    const float* pc1    = (const float*)d_in[0];
    const float* pc2    = (const float*)d_in[1];
    const float* feat1  = (const float*)d_in[2];
    const float* feat2  = (const float*)d_in[3];
    const float* wn1_w0 = (const float*)d_in[4];
    const float* wn1_b0 = (const float*)d_in[5];
    const float* wn1_w1 = (const float*)d_in[6];
    const float* wn1_b1 = (const float*)d_in[7];
    const float* wn1_w2 = (const float*)d_in[8];
    const float* wn1_b2 = (const float*)d_in[9];
    const float* lin1_w = (const float*)d_in[10];
    const float* lin1_b = (const float*)d_in[11];
    const float* wn2_w0 = (const float*)d_in[12];
    const float* wn2_b0 = (const float*)d_in[13];
    const float* wn2_w1 = (const float*)d_in[14];
    const float* wn2_b1 = (const float*)d_in[15];
    const float* wn2_w2 = (const float*)d_in[16];
    const float* wn2_b2 = (const float*)d_in[17];
    const float* lin2_w = (const float*)d_in[18];
    const float* lin2_b = (const float*)d_in[19];
    float* out = (float*)d_out;

    const int M  = BB * NPT;
    const int M2 = 2 * M;
    const int K1 = 2 * CDIM * WD;     // 2048
    const int K2 = 2 * MIDD * WD;     // 4096

    char* ws = (char*)d_ws;
    float* p1pm = (float*)ws;                          // [M][64] f32
    float* p2pm = p1pm + (size_t)M * CDIM;             // [M][64] f32
    float* fpm  = p2pm + (size_t)M * CDIM;             // [2M][128] f32 (f1|f2)
    bf16*  p1b  = (bf16*)(fpm + (size_t)M2 * MIDD);    // [M][64] bf16
    bf16*  p2b  = p1b + (size_t)M * CDIM;              // [M][64] bf16
    bf16*  fb   = p2b + (size_t)M * CDIM;              // [2M][128] bf16
    int* idx12  = (int*)(fb + (size_t)M2 * MIDD);
    int* idx21  = idx12 + (size_t)M * NBR;
    bf16* b1hi  = (bf16*)(idx21 + (size_t)M * NBR);
    bf16* b1lo  = b1hi + (size_t)MIDD * K1;
    bf16* b2hi  = b1lo + (size_t)MIDD * K1;
    bf16* b2lo  = b2hi + (size_t)MIDD * K2;
    bf16* aggbuf = b2lo + (size_t)MIDD * K2;
    const size_t used = (size_t)((char*)aggbuf - ws);
    const size_t avail = ws_size > used ? ws_size - used : 0;

    float* f1t = out;
    float* fft = out + 2 * (size_t)BB * MIDD * NPT;

    prep_kernel<<<2816, 256, 0, stream>>>(feat1, feat2, p1pm, p1b, p2pm, p2b,
                                          lin1_w, b1hi, b1lo, lin2_w, b2hi, b2lo);
    knn_kernel<<<dim3(NPT / KQ, BB, 2), 256, 0, stream>>>(pc1, pc2, idx12, idx21);

    auto chunk_rows = [&](int K) -> int {
        long rows = (long)(avail / ((size_t)K * sizeof(bf16)));
        int cm = (int)(rows > M2 ? M2 : rows) & ~127;
        if (cm < 128) cm = 128;
        return cm;
    };

    {   // cross 1 + cross 2 merged (K = 2048), single agg launch per chunk
        const int CMr = chunk_rows(K1);
        for (int m0 = 0; m0 < M2; m0 += CMr) {
            const int cm = (M2 - m0 < CMr) ? (M2 - m0) : CMr;
            agg_kernel<CDIM, 8><<<cm / 8, 256, 0, stream>>>(
                pc1, pc2, p1pm, p2b, idx12,
                pc2, pc1, p2pm, p1b, idx21, M,
                wn1_w0, wn1_b0, wn1_w1, wn1_b1, wn1_w2, wn1_b2, aggbuf, m0);
            gemm_mfma<<<cm / 64, 256, 0, stream>>>(aggbuf, b1hi, b1lo, lin1_b,
                                                   f1t, fpm, fb, m0, K1);
        }
    }
    {   // cross 3 (K = 4096): own = f1 (fp32), neighbors = f2 (bf16)
        const int CMr = chunk_rows(K2);
        for (int m0 = 0; m0 < M; m0 += CMr) {
            const int cm = (M - m0 < CMr) ? (M - m0) : CMr;
            agg_kernel<MIDD, 4><<<cm / 4, 256, 0, stream>>>(
                pc1, pc2, fpm, fb + (size_t)M * MIDD, idx12,
                nullptr, nullptr, nullptr, nullptr, nullptr, M2,
                wn2_w0, wn2_b0, wn2_w1, wn2_b1, wn2_w2, wn2_b2, aggbuf, m0);
            gemm_mfma<<<cm / 64, 256, 0, stream>>>(aggbuf, b2hi, b2lo, lin2_b,
                                                   fft, nullptr, nullptr, m0, K2);
        }
    }
}